// Round 11
// baseline (232.739 us; speedup 1.0000x reference)
//
#include <hip/hip_runtime.h>
#include <hip/hip_bf16.h>
#include <math.h>

// ---------------- problem constants ----------------
#define HW    3136        // 56*56
#define PADA  4624        // 68*68 padded plane (fp32 NCHW)
#define NT    49

// ---------------- workspace regions (float offsets) — proven extent ----------------
// R0: part0,part1 (bf16, dead after combine) -> fmap_att [4][256][3136] AT REGION BASE
// R1: attb [4][49][3136]
// R2: xpad fp32 [4][256][68][68]
// R3: k1 -> c2wb bf16 (after w2-gemm consumed k1)
// R4: xcat bf16 -> part2,part3 (bf16) -> attT bf16 (lower half); x2 fp32 (upper half)
// R5: c1wb bf16
// R6: stats
// R7: xpadT bf16 [4][68][68][256]
// R8: wbf bf16 [128][12544]
#define R0 0u
#define R1 3211264u
#define R2 6422528u
#define R3 11157504u
#define R4 12763136u
#define R5 15974400u
#define R6 17580032u
#define R7 17580544u
#define R8 19948032u

typedef __attribute__((ext_vector_type(8))) short bf16x8;
typedef __attribute__((ext_vector_type(8))) short short8v;
typedef __attribute__((ext_vector_type(4))) float f32x4;

__device__ __forceinline__ void gll16(const void* g, void* l) {
    __builtin_amdgcn_global_load_lds((const __attribute__((address_space(1))) void*)g,
                                     (__attribute__((address_space(3))) void*)l, 16, 0, 0);
}

__device__ __forceinline__ float bf2f(short u) {
    return __uint_as_float(((unsigned)(unsigned short)u) << 16);
}

// ---------------- tiled NCHW fp32 -> NHWC bf16 transpose (validated) ----------------
__global__ __launch_bounds__(256) void k_t2nhwc(const float* __restrict__ src,
        __hip_bfloat16* __restrict__ dst, int kstride, int c_off)
{
    __shared__ float t[64][65];
    const int tid = threadIdx.x;
    const int p0 = blockIdx.x * 64;
    const int c0 = blockIdx.y * 64;
    const int b  = blockIdx.z;
    const int pl = tid & 63, cr = tid >> 6;
    #pragma unroll
    for (int i = 0; i < 16; ++i) {
        const int c = c0 + i*4 + cr;
        t[i*4+cr][pl] = src[((size_t)(b*256 + c)) * HW + p0 + pl];
    }
    __syncthreads();
    const int cl = tid & 63, pr = tid >> 6;
    #pragma unroll
    for (int i = 0; i < 16; ++i) {
        const int p = p0 + i*4 + pr;
        dst[((size_t)(b*HW + p)) * kstride + c_off + c0 + cl] = __float2bfloat16(t[cl][i*4+pr]);
    }
}

// ---------------- fused bilinear-upsample + transpose: dec [4][256][28][28] -> xcat dec-half ----------------
__global__ __launch_bounds__(256) void k_t2up(const float* __restrict__ dec,
        __hip_bfloat16* __restrict__ dst, int kstride, int c_off)
{
    __shared__ float t[64][65];
    const int tid = threadIdx.x;
    const int p0 = blockIdx.x * 64;
    const int c0 = blockIdx.y * 64;
    const int b  = blockIdx.z;
    const int pl = tid & 63, cr = tid >> 6;

    const int p = p0 + pl;
    const int h = p / 56;
    const int w = p - h * 56;
    int ih0; float fh;
    if (h & 1) { ih0 = h >> 1;       fh = 0.25f; }
    else       { ih0 = (h >> 1) - 1; fh = 0.75f; }
    int ih1 = min(ih0 + 1, 27); ih0 = max(ih0, 0);
    int iw0; float fw;
    if (w & 1) { iw0 = w >> 1;       fw = 0.25f; }
    else       { iw0 = (w >> 1) - 1; fw = 0.75f; }
    int iw1 = min(iw0 + 1, 27); iw0 = max(iw0, 0);
    const int o00 = ih0*28 + iw0, o01 = ih0*28 + iw1;
    const int o10 = ih1*28 + iw0, o11 = ih1*28 + iw1;
    const float w00 = (1.f-fh)*(1.f-fw), w01 = (1.f-fh)*fw;
    const float w10 = fh*(1.f-fw),       w11 = fh*fw;

    #pragma unroll
    for (int i = 0; i < 16; ++i) {
        const int c = c0 + i*4 + cr;
        const float* s = dec + (size_t)(b*256 + c) * 784;
        t[i*4+cr][pl] = w00*s[o00] + w01*s[o01] + w10*s[o10] + w11*s[o11];
    }
    __syncthreads();
    const int cl = tid & 63, pr = tid >> 6;
    #pragma unroll
    for (int i = 0; i < 16; ++i) {
        const int pp = p0 + i*4 + pr;
        dst[((size_t)(b*HW + pp)) * kstride + c_off + c0 + cl] = __float2bfloat16(t[cl][i*4+pr]);
    }
}

// ---------------- fp32 -> bf16 straight convert ----------------
__global__ void k_cvt(const float* __restrict__ s, __hip_bfloat16* __restrict__ d)
{
    int j = blockIdx.x * 256 + threadIdx.x;
    d[j] = __float2bfloat16(s[j]);
}

// ---------------- w1 [128][256][49] -> Wbf [oc][k=t*256+c] bf16, LDS transpose (validated) ----------------
__global__ __launch_bounds__(256) void k_w1bf2(const float* __restrict__ w1,
        __hip_bfloat16* __restrict__ wt)
{
    __shared__ float t[NT * 257];
    const int tid = threadIdx.x;
    const int oc  = blockIdx.x;             // 128 blocks
    const float* src = w1 + (size_t)oc * 12544;
    #pragma unroll
    for (int i = 0; i < 49; ++i) {
        const int idx = i * 256 + tid;
        const int c  = idx / 49;
        const int tt = idx - c * 49;
        t[tt * 257 + c] = src[idx];
    }
    __syncthreads();
    __hip_bfloat16* dst = wt + (size_t)oc * 12544;
    #pragma unroll
    for (int i = 0; i < 49; ++i)
        dst[i * 256 + tid] = __float2bfloat16(t[i * 257 + tid]);
}

// ---------------- fp32 8x8 FMA microtile (w2 gemm only) ----------------
__device__ __forceinline__ void tile_fma(const float (*As)[128], const float (*Bs)[128],
                                         float acc[8][8], int tx, int ty)
{
    #pragma unroll
    for (int kk = 0; kk < 16; ++kk) {
        const float4 a0 = *(const float4*)&As[kk][ty*8];
        const float4 a1 = *(const float4*)&As[kk][ty*8+4];
        const float4 b0 = *(const float4*)&Bs[kk][tx*8];
        const float4 b1 = *(const float4*)&Bs[kk][tx*8+4];
        const float av[8] = {a0.x,a0.y,a0.z,a0.w,a1.x,a1.y,a1.z,a1.w};
        const float bv[8] = {b0.x,b0.y,b0.z,b0.w,b1.x,b1.y,b1.z,b1.w};
        #pragma unroll
        for (int e = 0; e < 8; ++e)
            #pragma unroll
            for (int f = 0; f < 8; ++f)
                acc[e][f] = fmaf(av[e], bv[f], acc[e][f]);
    }
}

// ---------------- fp32 1x1 GEMM (w2 only: M=49, K=128) — validated ----------------
__global__ __launch_bounds__(256, 2) void k_gemm1x1(
    const float* __restrict__ W, const float* __restrict__ bias,
    const float* __restrict__ X0, int M, int K, float* __restrict__ Y)
{
    __shared__ float As[16][128];
    __shared__ float Bs[16][128];
    const int tid = threadIdx.x;
    const int tx = tid & 15, ty = tid >> 4;
    const int n0 = blockIdx.y * 128;

    const int amA = tid >> 2;
    const int kqA = tid & 3;
    const bool av0 = amA < M;
    const bool av1 = (amA + 64) < M;
    const size_t aoff0 = (size_t)amA * K + kqA * 4;
    const size_t aoff1 = (size_t)(amA + 64) * K + kqA * 4;

    const int colB = tid & 127;
    const int kkb  = tid >> 7;
    const int nB = n0 + colB;
    const int bB = nB / HW;
    const int pB = nB - bB * HW;
    const size_t u0 = (size_t)bB * K * HW + pB;

    float acc[8][8] = {};

    for (int k0 = 0; k0 < K; k0 += 16) {
        float4 va = av0 ? *(const float4*)(W + aoff0 + k0) : make_float4(0.f,0.f,0.f,0.f);
        float4 vb = av1 ? *(const float4*)(W + aoff1 + k0) : make_float4(0.f,0.f,0.f,0.f);
        As[kqA*4+0][amA] = va.x; As[kqA*4+1][amA] = va.y;
        As[kqA*4+2][amA] = va.z; As[kqA*4+3][amA] = va.w;
        As[kqA*4+0][amA+64] = vb.x; As[kqA*4+1][amA+64] = vb.y;
        As[kqA*4+2][amA+64] = vb.z; As[kqA*4+3][amA+64] = vb.w;
        #pragma unroll
        for (int e = 0; e < 8; ++e) {
            const int kk = e*2 + kkb;
            Bs[kk][colB] = X0[u0 + (size_t)(k0 + kk) * HW];
        }
        __syncthreads();
        tile_fma(As, Bs, acc, tx, ty);
        __syncthreads();
    }

    const int nE = n0 + tx*8;
    const int bE0 = nE / HW;
    const int pE0 = nE - bE0 * HW;
    #pragma unroll
    for (int e = 0; e < 8; ++e) {
        const int m = ty*8 + e;
        if (m < M) {
            const float bsv = bias[m];
            int b = bE0, p = pE0;
            #pragma unroll
            for (int f = 0; f < 8; ++f) {
                Y[((size_t)b * M + m) * HW + p] = acc[e][f] + bsv;
                if (++p == HW) { p = 0; ++b; }
            }
        }
    }
}

// ---------------- c1 MFMA GEMM: epilogue writes xpad (fp32) + xpadT (bf16) — validated ----------------
__global__ __launch_bounds__(256, 2) void k_gemmc1(
    const __hip_bfloat16* __restrict__ A, const __hip_bfloat16* __restrict__ B0,
    const float* __restrict__ bias, float* __restrict__ Xpad,
    __hip_bfloat16* __restrict__ XpadT)
{
    __shared__ __hip_bfloat16 As[8192];
    __shared__ __hip_bfloat16 Bs[8192];
    const int tid  = threadIdx.x;
    const int w    = tid >> 6;
    const int lane = tid & 63;
    const int n0   = blockIdx.x * 128;
    const int m0   = blockIdx.y * 128;

    unsigned aoffs[4], boffs[4];
    void *adst[4], *bdst[4];
    #pragma unroll
    for (int j = 0; j < 4; ++j) {
        const int slot = (w*4 + j)*64 + lane;
        const int row  = slot >> 3;
        const int q    = slot & 7;
        const int lc   = q ^ (row & 7);
        aoffs[j] = (unsigned)(m0 + row) * 512u + (unsigned)lc * 8u;
        adst[j]  = (void*)&As[(w*4 + j) * 512];
        boffs[j] = (unsigned)(n0 + row) * 512u + (unsigned)lc * 8u;
        bdst[j]  = (void*)&Bs[(w*4 + j) * 512];
    }

    const int l15 = lane & 15, lg = lane >> 4;
    const int m_w0 = (w & 1) * 64;
    const int n_w0 = (w >> 1) * 64;
    int rowA[4], rowB[4], chunkoff[2];
    #pragma unroll
    for (int i = 0; i < 4; ++i) {
        rowA[i] = (m_w0 + i*16 + l15) * 128;
        rowB[i] = (n_w0 + i*16 + l15) * 128;
    }
    #pragma unroll
    for (int ks = 0; ks < 2; ++ks)
        chunkoff[ks] = ((4*ks + lg) ^ (lane & 7)) * 16;

    f32x4 acc[4][4];
    #pragma unroll
    for (int i = 0; i < 4; ++i)
        #pragma unroll
        for (int j = 0; j < 4; ++j)
            acc[i][j] = (f32x4){0.f, 0.f, 0.f, 0.f};

    for (int k0 = 0; k0 < 512; k0 += 64) {
        #pragma unroll
        for (int j = 0; j < 4; ++j) gll16(A + aoffs[j] + k0, adst[j]);
        #pragma unroll
        for (int j = 0; j < 4; ++j) gll16(B0 + boffs[j] + k0, bdst[j]);
        __syncthreads();
        #pragma unroll
        for (int ks = 0; ks < 2; ++ks) {
            const int co = chunkoff[ks];
            bf16x8 av[4], bv[4];
            #pragma unroll
            for (int i = 0; i < 4; ++i)
                av[i] = *(const bf16x8*)((const char*)As + rowA[i] + co);
            #pragma unroll
            for (int i = 0; i < 4; ++i)
                bv[i] = *(const bf16x8*)((const char*)Bs + rowB[i] + co);
            #pragma unroll
            for (int i = 0; i < 4; ++i)
                #pragma unroll
                for (int j = 0; j < 4; ++j)
                    acc[i][j] = __builtin_amdgcn_mfma_f32_16x16x32_bf16(av[i], bv[j], acc[i][j], 0, 0, 0);
        }
        __syncthreads();
    }

    #pragma unroll
    for (int j = 0; j < 4; ++j) {
        const int n = n0 + n_w0 + j*16 + l15;
        const int b = n / HW;
        const int p = n - b * HW;
        const int h = p / 56;
        const int ww = p - h * 56;
        #pragma unroll
        for (int i = 0; i < 4; ++i) {
            const int m = m0 + m_w0 + i*16 + lg*4;
            const float4 bs4 = *(const float4*)&bias[m];
            float v0 = fmaxf(acc[i][j][0] + bs4.x, 0.f);
            float v1 = fmaxf(acc[i][j][1] + bs4.y, 0.f);
            float v2 = fmaxf(acc[i][j][2] + bs4.z, 0.f);
            float v3 = fmaxf(acc[i][j][3] + bs4.w, 0.f);
            float* dp = Xpad + ((size_t)(b*256 + m)) * PADA + (h + 6) * 68 + (ww + 6);
            dp[0]      = v0;
            dp[PADA]   = v1;
            dp[2*PADA] = v2;
            dp[3*PADA] = v3;
            ushort4 pk;
            pk.x = __bfloat16_as_ushort(__float2bfloat16(v0));
            pk.y = __bfloat16_as_ushort(__float2bfloat16(v1));
            pk.z = __bfloat16_as_ushort(__float2bfloat16(v2));
            pk.w = __bfloat16_as_ushort(__float2bfloat16(v3));
            *(ushort4*)(XpadT + ((size_t)((b*68 + h + 6)*68 + ww + 6)) * 256 + m) = pk;
        }
    }
}

// ---------------- c2 MFMA GEMM (validated) ----------------
__global__ __launch_bounds__(256, 2) void k_gemmc2(
    const __hip_bfloat16* __restrict__ A, const __hip_bfloat16* __restrict__ XT,
    const __hip_bfloat16* __restrict__ AT, const float* __restrict__ bias,
    float* __restrict__ Y)
{
    __shared__ __hip_bfloat16 As[8192];
    __shared__ __hip_bfloat16 Bs[8192];
    const int tid  = threadIdx.x;
    const int w    = tid >> 6;
    const int lane = tid & 63;
    const int n0   = blockIdx.x * 128;

    unsigned aoffs[4], boffs0[4], boffs1[4];
    void *adst[4], *bdst[4];
    #pragma unroll
    for (int j = 0; j < 4; ++j) {
        const int slot = (w*4 + j)*64 + lane;
        const int row  = slot >> 3;
        const int q    = slot & 7;
        const int lc   = q ^ (row & 7);
        aoffs[j] = (unsigned)row * 512u + (unsigned)lc * 8u;
        adst[j]  = (void*)&As[(w*4 + j) * 512];
        const int n = n0 + row;
        const int b = n / HW;
        const int p = n - b * HW;
        const int h = p / 56;
        const int ww = p - h * 56;
        boffs0[j] = ((unsigned)(b*68 + h + 6)*68 + (unsigned)(ww + 6))*256u + (unsigned)lc * 8u;
        boffs1[j] = (unsigned)n * 256u + (unsigned)lc * 8u;
        bdst[j]  = (void*)&Bs[(w*4 + j) * 512];
    }

    const int l15 = lane & 15, lg = lane >> 4;
    const int m_w0 = (w & 1) * 64;
    const int n_w0 = (w >> 1) * 64;
    int rowA[4], rowB[4], chunkoff[2];
    #pragma unroll
    for (int i = 0; i < 4; ++i) {
        rowA[i] = (m_w0 + i*16 + l15) * 128;
        rowB[i] = (n_w0 + i*16 + l15) * 128;
    }
    #pragma unroll
    for (int ks = 0; ks < 2; ++ks)
        chunkoff[ks] = ((4*ks + lg) ^ (lane & 7)) * 16;

    f32x4 acc[4][4];
    #pragma unroll
    for (int i = 0; i < 4; ++i)
        #pragma unroll
        for (int j = 0; j < 4; ++j)
            acc[i][j] = (f32x4){0.f, 0.f, 0.f, 0.f};

    for (int k0 = 0; k0 < 512; k0 += 64) {
        #pragma unroll
        for (int j = 0; j < 4; ++j) gll16(A + aoffs[j] + k0, adst[j]);
        if (k0 < 256) {
            #pragma unroll
            for (int j = 0; j < 4; ++j) gll16(XT + boffs0[j] + k0, bdst[j]);
        } else {
            #pragma unroll
            for (int j = 0; j < 4; ++j) gll16(AT + boffs1[j] + (k0 - 256), bdst[j]);
        }
        __syncthreads();
        #pragma unroll
        for (int ks = 0; ks < 2; ++ks) {
            const int co = chunkoff[ks];
            bf16x8 av[4], bv[4];
            #pragma unroll
            for (int i = 0; i < 4; ++i)
                av[i] = *(const bf16x8*)((const char*)As + rowA[i] + co);
            #pragma unroll
            for (int i = 0; i < 4; ++i)
                bv[i] = *(const bf16x8*)((const char*)Bs + rowB[i] + co);
            #pragma unroll
            for (int i = 0; i < 4; ++i)
                #pragma unroll
                for (int j = 0; j < 4; ++j)
                    acc[i][j] = __builtin_amdgcn_mfma_f32_16x16x32_bf16(av[i], bv[j], acc[i][j], 0, 0, 0);
        }
        __syncthreads();
    }

    #pragma unroll
    for (int j = 0; j < 4; ++j) {
        const int n = n0 + n_w0 + j*16 + l15;
        const int b = n / HW;
        const int p = n - b * HW;
        #pragma unroll
        for (int i = 0; i < 4; ++i) {
            const int m = m_w0 + i*16 + lg*4;
            const float4 bs4 = *(const float4*)&bias[m];
            float* dst = Y + ((size_t)(b*128 + m) * HW + p);
            dst[0]    = acc[i][j][0] + bs4.x;
            dst[HW]   = acc[i][j][1] + bs4.y;
            dst[2*HW] = acc[i][j][2] + bs4.z;
            dst[3*HW] = acc[i][j][3] + bs4.w;
        }
    }
}

// ---------------- dilated 7x7 conv: bf16 MFMA implicit GEMM, K-split x4, bf16 partials ----------------
__global__ __launch_bounds__(256, 2) void k_convmfma(
    const __hip_bfloat16* __restrict__ Wbf, const __hip_bfloat16* __restrict__ XT,
    __hip_bfloat16* __restrict__ o0, __hip_bfloat16* __restrict__ o1,
    __hip_bfloat16* __restrict__ o2, __hip_bfloat16* __restrict__ o3)
{
    __shared__ __hip_bfloat16 As[8192];
    __shared__ __hip_bfloat16 Bs[8192];
    const int tid  = threadIdx.x;
    const int w    = tid >> 6;
    const int lane = tid & 63;
    const int n0   = blockIdx.x * 128;
    const int s    = blockIdx.y;                 // 0..3
    const int t_start = s * 49;                  // 4 x 49 = 196 K-tiles
    __hip_bfloat16* __restrict__ out = (s==0)?o0:(s==1)?o1:(s==2)?o2:o3;

    unsigned aoffs[4], boffs[4];
    void *adst[4], *bdst[4];
    #pragma unroll
    for (int j = 0; j < 4; ++j) {
        const int slot = (w*4 + j)*64 + lane;
        const int row  = slot >> 3;
        const int q    = slot & 7;
        const int lc   = q ^ (row & 7);
        aoffs[j] = (unsigned)row * 12544u + (unsigned)lc * 8u;
        adst[j]  = (void*)&As[(w*4 + j) * 512];
        const int n = n0 + row;
        const int b = n / HW;
        const int p = n - b * HW;
        const int h = p / 56;
        const int ww = p - h * 56;
        boffs[j] = ((unsigned)(b*68 + h)*68 + (unsigned)ww)*256u + (unsigned)lc * 8u;
        bdst[j]  = (void*)&Bs[(w*4 + j) * 512];
    }

    const int l15 = lane & 15, lg = lane >> 4;
    const int m_w0 = (w & 1) * 64;
    const int n_w0 = (w >> 1) * 64;
    int rowA[4], rowB[4], chunkoff[2];
    #pragma unroll
    for (int i = 0; i < 4; ++i) {
        rowA[i] = (m_w0 + i*16 + l15) * 128;
        rowB[i] = (n_w0 + i*16 + l15) * 128;
    }
    #pragma unroll
    for (int ks = 0; ks < 2; ++ks)
        chunkoff[ks] = ((4*ks + lg) ^ (lane & 7)) * 16;

    f32x4 acc[4][4];
    #pragma unroll
    for (int i = 0; i < 4; ++i)
        #pragma unroll
        for (int j = 0; j < 4; ++j)
            acc[i][j] = (f32x4){0.f, 0.f, 0.f, 0.f};

    for (int it = 0; it < 49; ++it) {
        const int kt = t_start + it;
        const int k0 = kt << 6;
        const int t  = k0 >> 8;
        const int c0 = k0 & 255;
        const int ti = (t * 37) >> 8;
        const int tj = t - ti * 7;
        const unsigned aof = (unsigned)k0;
        const unsigned bof = (unsigned)(ti*68 + tj) * 512u + (unsigned)c0;

        #pragma unroll
        for (int j = 0; j < 4; ++j) gll16(Wbf + aoffs[j] + aof, adst[j]);
        #pragma unroll
        for (int j = 0; j < 4; ++j) gll16(XT + boffs[j] + bof, bdst[j]);

        __syncthreads();

        #pragma unroll
        for (int ks = 0; ks < 2; ++ks) {
            const int co = chunkoff[ks];
            bf16x8 av[4], bv[4];
            #pragma unroll
            for (int i = 0; i < 4; ++i)
                av[i] = *(const bf16x8*)((const char*)As + rowA[i] + co);
            #pragma unroll
            for (int i = 0; i < 4; ++i)
                bv[i] = *(const bf16x8*)((const char*)Bs + rowB[i] + co);
            #pragma unroll
            for (int i = 0; i < 4; ++i)
                #pragma unroll
                for (int j = 0; j < 4; ++j)
                    acc[i][j] = __builtin_amdgcn_mfma_f32_16x16x32_bf16(av[i], bv[j], acc[i][j], 0, 0, 0);
        }
        __syncthreads();
    }

    #pragma unroll
    for (int j = 0; j < 4; ++j) {
        const int n = n0 + n_w0 + j*16 + l15;
        const int b = n / HW;
        const int p = n - b * HW;
        #pragma unroll
        for (int i = 0; i < 4; ++i) {
            const int m = m_w0 + i*16 + lg*4;
            __hip_bfloat16* dst = out + ((size_t)(b*128 + m) * HW + p);
            dst[0]      = __float2bfloat16(acc[i][j][0]);
            dst[HW]     = __float2bfloat16(acc[i][j][1]);
            dst[2*HW]   = __float2bfloat16(acc[i][j][2]);
            dst[3*HW]   = __float2bfloat16(acc[i][j][3]);
        }
    }
}

// ---------------- combine 4 bf16 partials + bias + relu -> k1 (short8-vectorized) ----------------
__global__ __launch_bounds__(256) void k_combine4(
    const short8v* __restrict__ p0, const short8v* __restrict__ p1,
    const short8v* __restrict__ p2, const short8v* __restrict__ p3,
    const float* __restrict__ bias, float* __restrict__ Y)
{
    const int j = blockIdx.x * 256 + threadIdx.x;    // over 200,704 (= 1,605,632/8)
    short8v a = p0[j], b = p1[j], c = p2[j], d = p3[j];
    const int oc = ((j * 8) / HW) & 127;             // 3136 % 8 == 0: no oc straddle
    const float bv = bias[oc];
    float o[8];
    #pragma unroll
    for (int e = 0; e < 8; ++e) {
        float v = bf2f(a[e]) + bf2f(b[e]) + bf2f(c[e]) + bf2f(d[e]) + bv;
        o[e] = fmaxf(v, 0.f);
    }
    float4* dst = (float4*)(Y + (size_t)j * 8);
    dst[0] = *(float4*)&o[0];
    dst[1] = *(float4*)&o[4];
}

// ---------------- BN batch stats (validated) ----------------
__global__ __launch_bounds__(256) void k_bnstats(const float* __restrict__ X, int nch,
                                                 float* __restrict__ meanOut,
                                                 float* __restrict__ rstdOut)
{
    const int ch  = blockIdx.x;
    const int tid = threadIdx.x;
    float s1 = 0.f, s2 = 0.f;
    for (int b = 0; b < 4; ++b) {
        const float* base = X + ((size_t)b * nch + ch) * HW;
        for (int p = tid; p < HW; p += 256) { float v = base[p]; s1 += v; s2 += v * v; }
    }
    for (int off = 32; off > 0; off >>= 1) {
        s1 += __shfl_down(s1, off);
        s2 += __shfl_down(s2, off);
    }
    __shared__ float r1[4], r2[4];
    const int lane = tid & 63, wv = tid >> 6;
    if (lane == 0) { r1[wv] = s1; r2[wv] = s2; }
    __syncthreads();
    if (tid == 0) {
        float a = r1[0] + r1[1] + r1[2] + r1[3];
        float q = r2[0] + r2[1] + r2[2] + r2[3];
        float mean = a * (1.f / 12544.f);
        float var  = q * (1.f / 12544.f) - mean * mean;
        meanOut[ch] = mean;
        rstdOut[ch] = rsqrtf(var + 1e-5f);
    }
}

// ---------------- fused BN + relu + softmax over 49 channels (validated) ----------------
__global__ __launch_bounds__(256) void k_bnsoftmax(float* __restrict__ X,
        const float* __restrict__ mean, const float* __restrict__ rstd,
        const float* __restrict__ gam,  const float* __restrict__ bet)
{
    const int gidx = blockIdx.x * 256 + threadIdx.x;
    const int b = gidx / HW;
    const int p = gidx - b * HW;
    float* base = X + (size_t)b * NT * HW + p;
    float vals[NT];
    float m = -1e30f;
    #pragma unroll
    for (int t = 0; t < NT; ++t) {
        float v = base[(size_t)t * HW];
        v = (v - mean[t]) * rstd[t] * gam[t] + bet[t];
        v = fmaxf(v, 0.f);
        vals[t] = v;
        m = fmaxf(m, v);
    }
    float s = 0.f;
    #pragma unroll
    for (int t = 0; t < NT; ++t) { float e = __expf(vals[t] - m); vals[t] = e; s += e; }
    const float inv = 1.f / s;
    #pragma unroll
    for (int t = 0; t < NT; ++t) base[(size_t)t * HW] = vals[t] * inv;
}

// ---------------- attention apply v2: register-blocked, LDS-free (validated) ----------------
__global__ __launch_bounds__(256) void k_attapply2(const float* __restrict__ Xpad,
        const float* __restrict__ att, float* __restrict__ Y)
{
    const int tid  = threadIdx.x;
    const int wv   = tid >> 6;
    const int lane = tid & 63;
    const int wq   = lane & 15;          // active < 14
    const int rs   = lane >> 4;
    const int rq   = blockIdx.x;         // 0..13
    const int cg   = blockIdx.y;         // 0..63
    const int b    = blockIdx.z;         // 0..3
    const int c    = cg * 4 + wv;
    const int h    = rq * 4 + rs;
    const int w0   = min(wq, 13) * 4;

    const float* xbase = Xpad + ((size_t)(b*256 + c) * 68 + h) * 68 + w0;
    const float* abase = att + (size_t)b * NT * HW + h * 56 + w0;
    float4 acc = {0.f, 0.f, 0.f, 0.f};
    #pragma unroll
    for (int ti = 0; ti < 7; ++ti) {
        const float* xr = xbase + ti * 136;          // row h + 2*ti
        float xf[16];
        *(float4*)&xf[0]  = *(const float4*)(xr);
        *(float4*)&xf[4]  = *(const float4*)(xr + 4);
        *(float4*)&xf[8]  = *(const float4*)(xr + 8);
        *(float4*)&xf[12] = *(const float4*)(xr + 12);
        #pragma unroll
        for (int tj = 0; tj < 7; ++tj) {
            const float4 a4 = *(const float4*)(abase + (size_t)(ti*7 + tj) * HW);
            acc.x = fmaf(xf[2*tj + 0], a4.x, acc.x);
            acc.y = fmaf(xf[2*tj + 1], a4.y, acc.y);
            acc.z = fmaf(xf[2*tj + 2], a4.z, acc.z);
            acc.w = fmaf(xf[2*tj + 3], a4.w, acc.w);
        }
    }
    if (wq < 14)
        *(float4*)(Y + (size_t)(b*256 + c) * HW + h * 56 + w0) = acc;
}

// ---------------- fused final BN + relu -> dec_out, + sigmoid(c3) -> side (validated) ----------------
__global__ __launch_bounds__(256) void k_bnside(const float* __restrict__ X,
        const float* __restrict__ mean, const float* __restrict__ rstd,
        const float* __restrict__ gam,  const float* __restrict__ bet,
        const float* __restrict__ w3,   const float* __restrict__ b3,
        float* __restrict__ dec_out,    float* __restrict__ side)
{
    __shared__ float ms[128], rs[128], gs[128], bs[128], w3s[128];
    const int tid = threadIdx.x;
    if (tid < 128) {
        ms[tid] = mean[tid]; rs[tid] = rstd[tid];
        gs[tid] = gam[tid];  bs[tid] = bet[tid];
        w3s[tid] = w3[tid];
    }
    __syncthreads();
    const int gidx = blockIdx.x * 256 + tid;    // exactly 12544
    const int b = gidx / HW;
    const int p = gidx - b * HW;
    const size_t u = (size_t)b * 128 * HW + p;
    float acc = b3[0];
    #pragma unroll 8
    for (int c = 0; c < 128; ++c) {
        const size_t a = u + (size_t)c * HW;
        float v = (X[a] - ms[c]) * rs[c] * gs[c] + bs[c];
        v = fmaxf(v, 0.f);
        dec_out[a] = v;
        acc = fmaf(v, w3s[c], acc);
    }
    side[gidx] = 1.f / (1.f + __expf(-acc));
}

// ---------------- launcher ----------------
extern "C" void kernel_launch(void* const* d_in, const int* in_sizes, int n_in,
                              void* d_out, int out_size, void* d_ws, size_t ws_size,
                              hipStream_t stream)
{
    const float* en  = (const float*)d_in[0];
    const float* dec = (const float*)d_in[1];
    const float* w1  = (const float*)d_in[2];
    const float* b1  = (const float*)d_in[3];
    const float* w2  = (const float*)d_in[4];
    const float* b2  = (const float*)d_in[5];
    const float* bng = (const float*)d_in[6];
    const float* bnb = (const float*)d_in[7];
    const float* c1w = (const float*)d_in[8];
    const float* c1b = (const float*)d_in[9];
    const float* c2w = (const float*)d_in[10];
    const float* c2b = (const float*)d_in[11];
    const float* bfg = (const float*)d_in[12];
    const float* bfb = (const float*)d_in[13];
    const float* c3w = (const float*)d_in[14];
    const float* c3b = (const float*)d_in[15];

    float* ws = (float*)d_ws;                   // 20,750,848 floats (proven extent)
    __hip_bfloat16* part0 = (__hip_bfloat16*)(ws + R0);             // dead after combine4
    __hip_bfloat16* part1 = (__hip_bfloat16*)(ws + R0 + 802816u);   // dead after combine4
    float* fmap_att = ws + R0;                  // FIX: region BASE — needs all 3,211,264 floats
    float* attb     = ws + R1;
    float* xpad     = ws + R2;
    float* k1       = ws + R3;
    __hip_bfloat16* c2wb = (__hip_bfloat16*)(ws + R3);              // overlays k1 AFTER w2-gemm
    __hip_bfloat16* xcat = (__hip_bfloat16*)(ws + R4);              // dead before part2/3 written
    __hip_bfloat16* part2 = (__hip_bfloat16*)(ws + R4);
    __hip_bfloat16* part3 = (__hip_bfloat16*)(ws + R4 + 802816u);
    __hip_bfloat16* attT  = (__hip_bfloat16*)(ws + R4);             // part2/3 dead after combine
    float* x2       = ws + R4 + 1605632u;
    __hip_bfloat16* c1wb = (__hip_bfloat16*)(ws + R5);
    float* stats    = ws + R6;
    __hip_bfloat16* xpadT = (__hip_bfloat16*)(ws + R7);
    __hip_bfloat16* wbf   = (__hip_bfloat16*)(ws + R8);

    float* dec_out = (float*)d_out;
    float* side    = (float*)d_out + 1605632u;

    // 0. zero padded buffers (borders must be 0 every call; interiors overwritten by gemmc1)
    hipMemsetAsync(xpad,  0, (size_t)4 * 256 * PADA * sizeof(float), stream);
    hipMemsetAsync(xpadT, 0, (size_t)4 * PADA * 256 * sizeof(__hip_bfloat16), stream);
    // 1. en -> xcat[:, 0:256]; dec -(fused bilinear)-> xcat[:, 256:512]
    k_t2nhwc<<<dim3(49, 4, 4), dim3(256), 0, stream>>>(en, xcat, 512, 0);
    k_t2up<<<dim3(49, 4, 4), dim3(256), 0, stream>>>(dec, xcat, 512, 256);
    // 2. c1 weight -> bf16
    k_cvt<<<dim3(512), dim3(256), 0, stream>>>(c1w, c1wb);
    // 3. relu(c1 x xcat) via MFMA -> xpad (fp32) + xpadT (bf16)
    k_gemmc1<<<dim3(98, 2), dim3(256), 0, stream>>>(c1wb, xcat, c1b, xpad, xpadT);
    // 4. w1 -> bf16 [oc][t*256+c]
    k_w1bf2<<<dim3(128), dim3(256), 0, stream>>>(w1, wbf);
    // 5. big dilated conv (K-split x4, bf16 partials)
    k_convmfma<<<dim3(98, 4), dim3(256), 0, stream>>>(wbf, xpadT, part0, part1, part2, part3);
    // 6. combine -> k1
    k_combine4<<<dim3(784), dim3(256), 0, stream>>>((const short8v*)part0, (const short8v*)part1,
                                                    (const short8v*)part2, (const short8v*)part3, b1, k1);
    // 7. attention logits = w2 * k1 + b2 (fp32)
    k_gemm1x1<<<dim3(1, 98), dim3(256), 0, stream>>>(w2, b2, k1, 49, 128, attb);
    // 8-9. BN stats + BN/relu/softmax
    k_bnstats<<<dim3(49), dim3(256), 0, stream>>>(attb, 49, stats + 0, stats + 64);
    k_bnsoftmax<<<dim3(49), dim3(256), 0, stream>>>(attb, stats + 0, stats + 64, bng, bnb);
    // 10. local attention gather -> fmap_att (parts dead; fmap_att at R0 base, no overlap with attb)
    k_attapply2<<<dim3(14, 64, 4), dim3(256), 0, stream>>>(xpad, attb, fmap_att);
    // 11. fmap_att -> attT NHWC bf16
    k_t2nhwc<<<dim3(49, 4, 4), dim3(256), 0, stream>>>(fmap_att, attT, 256, 0);
    // 12. c2 weight -> bf16 (k1 dead after step 7)
    k_cvt<<<dim3(256), dim3(256), 0, stream>>>(c2w, c2wb);
    // 13. x2 = c2 x [xpadT(center) ; attT] via MFMA
    k_gemmc2<<<dim3(98), dim3(256), 0, stream>>>(c2wb, xpadT, attT, c2b, x2);
    // 14. BN stats over x2
    k_bnstats<<<dim3(128), dim3(256), 0, stream>>>(x2, 128, stats + 128, stats + 256);
    // 15. fused BN/relu -> dec_out + sigmoid side
    k_bnside<<<dim3(49), dim3(256), 0, stream>>>(x2, stats + 128, stats + 256, bfg, bfb,
                                                 c3w, c3b, dec_out, side);
}

// Round 12
// 226.749 us; speedup vs baseline: 1.0264x; 1.0264x over previous
//
#include <hip/hip_runtime.h>
#include <hip/hip_bf16.h>
#include <math.h>

// ---------------- problem constants ----------------
#define HW    3136        // 56*56
#define PADA  4624        // 68*68 padded plane (fp32 NCHW)
#define NT    49

// ---------------- workspace regions (float offsets) — proven extent ----------------
// R0: part0..part3 (bf16, 4x802816, dead after combine) -> fmap_att [4][256][3136] at base
// R1: attb [4][49][3136]
// R2: xpad fp32 [4][256][68][68]
// R3: k1 -> c2wb bf16 (after w2-gemm consumed k1)
// R4: xcat bf16 -> part4 (bf16, base) -> attT bf16 (base); x2 fp32 (upper half)
// R5: c1wb bf16
// R6: stats
// R7: xpadT bf16 [4][68][68][256]
// R8: wbf bf16 [128][12544]
#define R0 0u
#define R1 3211264u
#define R2 6422528u
#define R3 11157504u
#define R4 12763136u
#define R5 15974400u
#define R6 17580032u
#define R7 17580544u
#define R8 19948032u

typedef __attribute__((ext_vector_type(8))) short bf16x8;
typedef __attribute__((ext_vector_type(8))) short short8v;
typedef __attribute__((ext_vector_type(4))) float f32x4;

__device__ __forceinline__ void gll16(const void* g, void* l) {
    __builtin_amdgcn_global_load_lds((const __attribute__((address_space(1))) void*)g,
                                     (__attribute__((address_space(3))) void*)l, 16, 0, 0);
}

__device__ __forceinline__ float bf2f(short u) {
    return __uint_as_float(((unsigned)(unsigned short)u) << 16);
}

// ---------------- tiled NCHW fp32 -> NHWC bf16 transpose (validated) ----------------
__global__ __launch_bounds__(256) void k_t2nhwc(const float* __restrict__ src,
        __hip_bfloat16* __restrict__ dst, int kstride, int c_off)
{
    __shared__ float t[64][65];
    const int tid = threadIdx.x;
    const int p0 = blockIdx.x * 64;
    const int c0 = blockIdx.y * 64;
    const int b  = blockIdx.z;
    const int pl = tid & 63, cr = tid >> 6;
    #pragma unroll
    for (int i = 0; i < 16; ++i) {
        const int c = c0 + i*4 + cr;
        t[i*4+cr][pl] = src[((size_t)(b*256 + c)) * HW + p0 + pl];
    }
    __syncthreads();
    const int cl = tid & 63, pr = tid >> 6;
    #pragma unroll
    for (int i = 0; i < 16; ++i) {
        const int p = p0 + i*4 + pr;
        dst[((size_t)(b*HW + p)) * kstride + c_off + c0 + cl] = __float2bfloat16(t[cl][i*4+pr]);
    }
}

// ---------------- fused bilinear-upsample + transpose (validated R11) ----------------
__global__ __launch_bounds__(256) void k_t2up(const float* __restrict__ dec,
        __hip_bfloat16* __restrict__ dst, int kstride, int c_off)
{
    __shared__ float t[64][65];
    const int tid = threadIdx.x;
    const int p0 = blockIdx.x * 64;
    const int c0 = blockIdx.y * 64;
    const int b  = blockIdx.z;
    const int pl = tid & 63, cr = tid >> 6;

    const int p = p0 + pl;
    const int h = p / 56;
    const int w = p - h * 56;
    int ih0; float fh;
    if (h & 1) { ih0 = h >> 1;       fh = 0.25f; }
    else       { ih0 = (h >> 1) - 1; fh = 0.75f; }
    int ih1 = min(ih0 + 1, 27); ih0 = max(ih0, 0);
    int iw0; float fw;
    if (w & 1) { iw0 = w >> 1;       fw = 0.25f; }
    else       { iw0 = (w >> 1) - 1; fw = 0.75f; }
    int iw1 = min(iw0 + 1, 27); iw0 = max(iw0, 0);
    const int o00 = ih0*28 + iw0, o01 = ih0*28 + iw1;
    const int o10 = ih1*28 + iw0, o11 = ih1*28 + iw1;
    const float w00 = (1.f-fh)*(1.f-fw), w01 = (1.f-fh)*fw;
    const float w10 = fh*(1.f-fw),       w11 = fh*fw;

    #pragma unroll
    for (int i = 0; i < 16; ++i) {
        const int c = c0 + i*4 + cr;
        const float* s = dec + (size_t)(b*256 + c) * 784;
        t[i*4+cr][pl] = w00*s[o00] + w01*s[o01] + w10*s[o10] + w11*s[o11];
    }
    __syncthreads();
    const int cl = tid & 63, pr = tid >> 6;
    #pragma unroll
    for (int i = 0; i < 16; ++i) {
        const int pp = p0 + i*4 + pr;
        dst[((size_t)(b*HW + pp)) * kstride + c_off + c0 + cl] = __float2bfloat16(t[cl][i*4+pr]);
    }
}

// ---------------- fp32 -> bf16 straight convert ----------------
__global__ void k_cvt(const float* __restrict__ s, __hip_bfloat16* __restrict__ d)
{
    int j = blockIdx.x * 256 + threadIdx.x;
    d[j] = __float2bfloat16(s[j]);
}

// ---------------- w1 [128][256][49] -> Wbf [oc][k=t*256+c] bf16, LDS transpose (validated) ----------------
__global__ __launch_bounds__(256) void k_w1bf2(const float* __restrict__ w1,
        __hip_bfloat16* __restrict__ wt)
{
    __shared__ float t[NT * 257];
    const int tid = threadIdx.x;
    const int oc  = blockIdx.x;             // 128 blocks
    const float* src = w1 + (size_t)oc * 12544;
    #pragma unroll
    for (int i = 0; i < 49; ++i) {
        const int idx = i * 256 + tid;
        const int c  = idx / 49;
        const int tt = idx - c * 49;
        t[tt * 257 + c] = src[idx];
    }
    __syncthreads();
    __hip_bfloat16* dst = wt + (size_t)oc * 12544;
    #pragma unroll
    for (int i = 0; i < 49; ++i)
        dst[i * 256 + tid] = __float2bfloat16(t[i * 257 + tid]);
}

// ---------------- fp32 8x8 FMA microtile (w2 gemm only) ----------------
__device__ __forceinline__ void tile_fma(const float (*As)[128], const float (*Bs)[128],
                                         float acc[8][8], int tx, int ty)
{
    #pragma unroll
    for (int kk = 0; kk < 16; ++kk) {
        const float4 a0 = *(const float4*)&As[kk][ty*8];
        const float4 a1 = *(const float4*)&As[kk][ty*8+4];
        const float4 b0 = *(const float4*)&Bs[kk][tx*8];
        const float4 b1 = *(const float4*)&Bs[kk][tx*8+4];
        const float av[8] = {a0.x,a0.y,a0.z,a0.w,a1.x,a1.y,a1.z,a1.w};
        const float bv[8] = {b0.x,b0.y,b0.z,b0.w,b1.x,b1.y,b1.z,b1.w};
        #pragma unroll
        for (int e = 0; e < 8; ++e)
            #pragma unroll
            for (int f = 0; f < 8; ++f)
                acc[e][f] = fmaf(av[e], bv[f], acc[e][f]);
    }
}

// ---------------- fp32 1x1 GEMM (w2 only: M=49, K=128) — validated ----------------
__global__ __launch_bounds__(256, 2) void k_gemm1x1(
    const float* __restrict__ W, const float* __restrict__ bias,
    const float* __restrict__ X0, int M, int K, float* __restrict__ Y)
{
    __shared__ float As[16][128];
    __shared__ float Bs[16][128];
    const int tid = threadIdx.x;
    const int tx = tid & 15, ty = tid >> 4;
    const int n0 = blockIdx.y * 128;

    const int amA = tid >> 2;
    const int kqA = tid & 3;
    const bool av0 = amA < M;
    const bool av1 = (amA + 64) < M;
    const size_t aoff0 = (size_t)amA * K + kqA * 4;
    const size_t aoff1 = (size_t)(amA + 64) * K + kqA * 4;

    const int colB = tid & 127;
    const int kkb  = tid >> 7;
    const int nB = n0 + colB;
    const int bB = nB / HW;
    const int pB = nB - bB * HW;
    const size_t u0 = (size_t)bB * K * HW + pB;

    float acc[8][8] = {};

    for (int k0 = 0; k0 < K; k0 += 16) {
        float4 va = av0 ? *(const float4*)(W + aoff0 + k0) : make_float4(0.f,0.f,0.f,0.f);
        float4 vb = av1 ? *(const float4*)(W + aoff1 + k0) : make_float4(0.f,0.f,0.f,0.f);
        As[kqA*4+0][amA] = va.x; As[kqA*4+1][amA] = va.y;
        As[kqA*4+2][amA] = va.z; As[kqA*4+3][amA] = va.w;
        As[kqA*4+0][amA+64] = vb.x; As[kqA*4+1][amA+64] = vb.y;
        As[kqA*4+2][amA+64] = vb.z; As[kqA*4+3][amA+64] = vb.w;
        #pragma unroll
        for (int e = 0; e < 8; ++e) {
            const int kk = e*2 + kkb;
            Bs[kk][colB] = X0[u0 + (size_t)(k0 + kk) * HW];
        }
        __syncthreads();
        tile_fma(As, Bs, acc, tx, ty);
        __syncthreads();
    }

    const int nE = n0 + tx*8;
    const int bE0 = nE / HW;
    const int pE0 = nE - bE0 * HW;
    #pragma unroll
    for (int e = 0; e < 8; ++e) {
        const int m = ty*8 + e;
        if (m < M) {
            const float bsv = bias[m];
            int b = bE0, p = pE0;
            #pragma unroll
            for (int f = 0; f < 8; ++f) {
                Y[((size_t)b * M + m) * HW + p] = acc[e][f] + bsv;
                if (++p == HW) { p = 0; ++b; }
            }
        }
    }
}

// ---------------- c1 MFMA GEMM: epilogue writes xpad (fp32) + xpadT (bf16) — validated ----------------
__global__ __launch_bounds__(256, 2) void k_gemmc1(
    const __hip_bfloat16* __restrict__ A, const __hip_bfloat16* __restrict__ B0,
    const float* __restrict__ bias, float* __restrict__ Xpad,
    __hip_bfloat16* __restrict__ XpadT)
{
    __shared__ __hip_bfloat16 As[8192];
    __shared__ __hip_bfloat16 Bs[8192];
    const int tid  = threadIdx.x;
    const int w    = tid >> 6;
    const int lane = tid & 63;
    const int n0   = blockIdx.x * 128;
    const int m0   = blockIdx.y * 128;

    unsigned aoffs[4], boffs[4];
    void *adst[4], *bdst[4];
    #pragma unroll
    for (int j = 0; j < 4; ++j) {
        const int slot = (w*4 + j)*64 + lane;
        const int row  = slot >> 3;
        const int q    = slot & 7;
        const int lc   = q ^ (row & 7);
        aoffs[j] = (unsigned)(m0 + row) * 512u + (unsigned)lc * 8u;
        adst[j]  = (void*)&As[(w*4 + j) * 512];
        boffs[j] = (unsigned)(n0 + row) * 512u + (unsigned)lc * 8u;
        bdst[j]  = (void*)&Bs[(w*4 + j) * 512];
    }

    const int l15 = lane & 15, lg = lane >> 4;
    const int m_w0 = (w & 1) * 64;
    const int n_w0 = (w >> 1) * 64;
    int rowA[4], rowB[4], chunkoff[2];
    #pragma unroll
    for (int i = 0; i < 4; ++i) {
        rowA[i] = (m_w0 + i*16 + l15) * 128;
        rowB[i] = (n_w0 + i*16 + l15) * 128;
    }
    #pragma unroll
    for (int ks = 0; ks < 2; ++ks)
        chunkoff[ks] = ((4*ks + lg) ^ (lane & 7)) * 16;

    f32x4 acc[4][4];
    #pragma unroll
    for (int i = 0; i < 4; ++i)
        #pragma unroll
        for (int j = 0; j < 4; ++j)
            acc[i][j] = (f32x4){0.f, 0.f, 0.f, 0.f};

    for (int k0 = 0; k0 < 512; k0 += 64) {
        #pragma unroll
        for (int j = 0; j < 4; ++j) gll16(A + aoffs[j] + k0, adst[j]);
        #pragma unroll
        for (int j = 0; j < 4; ++j) gll16(B0 + boffs[j] + k0, bdst[j]);
        __syncthreads();
        #pragma unroll
        for (int ks = 0; ks < 2; ++ks) {
            const int co = chunkoff[ks];
            bf16x8 av[4], bv[4];
            #pragma unroll
            for (int i = 0; i < 4; ++i)
                av[i] = *(const bf16x8*)((const char*)As + rowA[i] + co);
            #pragma unroll
            for (int i = 0; i < 4; ++i)
                bv[i] = *(const bf16x8*)((const char*)Bs + rowB[i] + co);
            #pragma unroll
            for (int i = 0; i < 4; ++i)
                #pragma unroll
                for (int j = 0; j < 4; ++j)
                    acc[i][j] = __builtin_amdgcn_mfma_f32_16x16x32_bf16(av[i], bv[j], acc[i][j], 0, 0, 0);
        }
        __syncthreads();
    }

    #pragma unroll
    for (int j = 0; j < 4; ++j) {
        const int n = n0 + n_w0 + j*16 + l15;
        const int b = n / HW;
        const int p = n - b * HW;
        const int h = p / 56;
        const int ww = p - h * 56;
        #pragma unroll
        for (int i = 0; i < 4; ++i) {
            const int m = m0 + m_w0 + i*16 + lg*4;
            const float4 bs4 = *(const float4*)&bias[m];
            float v0 = fmaxf(acc[i][j][0] + bs4.x, 0.f);
            float v1 = fmaxf(acc[i][j][1] + bs4.y, 0.f);
            float v2 = fmaxf(acc[i][j][2] + bs4.z, 0.f);
            float v3 = fmaxf(acc[i][j][3] + bs4.w, 0.f);
            float* dp = Xpad + ((size_t)(b*256 + m)) * PADA + (h + 6) * 68 + (ww + 6);
            dp[0]      = v0;
            dp[PADA]   = v1;
            dp[2*PADA] = v2;
            dp[3*PADA] = v3;
            ushort4 pk;
            pk.x = __bfloat16_as_ushort(__float2bfloat16(v0));
            pk.y = __bfloat16_as_ushort(__float2bfloat16(v1));
            pk.z = __bfloat16_as_ushort(__float2bfloat16(v2));
            pk.w = __bfloat16_as_ushort(__float2bfloat16(v3));
            *(ushort4*)(XpadT + ((size_t)((b*68 + h + 6)*68 + ww + 6)) * 256 + m) = pk;
        }
    }
}

// ---------------- c2 MFMA GEMM (validated) ----------------
__global__ __launch_bounds__(256, 2) void k_gemmc2(
    const __hip_bfloat16* __restrict__ A, const __hip_bfloat16* __restrict__ XT,
    const __hip_bfloat16* __restrict__ AT, const float* __restrict__ bias,
    float* __restrict__ Y)
{
    __shared__ __hip_bfloat16 As[8192];
    __shared__ __hip_bfloat16 Bs[8192];
    const int tid  = threadIdx.x;
    const int w    = tid >> 6;
    const int lane = tid & 63;
    const int n0   = blockIdx.x * 128;

    unsigned aoffs[4], boffs0[4], boffs1[4];
    void *adst[4], *bdst[4];
    #pragma unroll
    for (int j = 0; j < 4; ++j) {
        const int slot = (w*4 + j)*64 + lane;
        const int row  = slot >> 3;
        const int q    = slot & 7;
        const int lc   = q ^ (row & 7);
        aoffs[j] = (unsigned)row * 512u + (unsigned)lc * 8u;
        adst[j]  = (void*)&As[(w*4 + j) * 512];
        const int n = n0 + row;
        const int b = n / HW;
        const int p = n - b * HW;
        const int h = p / 56;
        const int ww = p - h * 56;
        boffs0[j] = ((unsigned)(b*68 + h + 6)*68 + (unsigned)(ww + 6))*256u + (unsigned)lc * 8u;
        boffs1[j] = (unsigned)n * 256u + (unsigned)lc * 8u;
        bdst[j]  = (void*)&Bs[(w*4 + j) * 512];
    }

    const int l15 = lane & 15, lg = lane >> 4;
    const int m_w0 = (w & 1) * 64;
    const int n_w0 = (w >> 1) * 64;
    int rowA[4], rowB[4], chunkoff[2];
    #pragma unroll
    for (int i = 0; i < 4; ++i) {
        rowA[i] = (m_w0 + i*16 + l15) * 128;
        rowB[i] = (n_w0 + i*16 + l15) * 128;
    }
    #pragma unroll
    for (int ks = 0; ks < 2; ++ks)
        chunkoff[ks] = ((4*ks + lg) ^ (lane & 7)) * 16;

    f32x4 acc[4][4];
    #pragma unroll
    for (int i = 0; i < 4; ++i)
        #pragma unroll
        for (int j = 0; j < 4; ++j)
            acc[i][j] = (f32x4){0.f, 0.f, 0.f, 0.f};

    for (int k0 = 0; k0 < 512; k0 += 64) {
        #pragma unroll
        for (int j = 0; j < 4; ++j) gll16(A + aoffs[j] + k0, adst[j]);
        if (k0 < 256) {
            #pragma unroll
            for (int j = 0; j < 4; ++j) gll16(XT + boffs0[j] + k0, bdst[j]);
        } else {
            #pragma unroll
            for (int j = 0; j < 4; ++j) gll16(AT + boffs1[j] + (k0 - 256), bdst[j]);
        }
        __syncthreads();
        #pragma unroll
        for (int ks = 0; ks < 2; ++ks) {
            const int co = chunkoff[ks];
            bf16x8 av[4], bv[4];
            #pragma unroll
            for (int i = 0; i < 4; ++i)
                av[i] = *(const bf16x8*)((const char*)As + rowA[i] + co);
            #pragma unroll
            for (int i = 0; i < 4; ++i)
                bv[i] = *(const bf16x8*)((const char*)Bs + rowB[i] + co);
            #pragma unroll
            for (int i = 0; i < 4; ++i)
                #pragma unroll
                for (int j = 0; j < 4; ++j)
                    acc[i][j] = __builtin_amdgcn_mfma_f32_16x16x32_bf16(av[i], bv[j], acc[i][j], 0, 0, 0);
        }
        __syncthreads();
    }

    #pragma unroll
    for (int j = 0; j < 4; ++j) {
        const int n = n0 + n_w0 + j*16 + l15;
        const int b = n / HW;
        const int p = n - b * HW;
        #pragma unroll
        for (int i = 0; i < 4; ++i) {
            const int m = m_w0 + i*16 + lg*4;
            const float4 bs4 = *(const float4*)&bias[m];
            float* dst = Y + ((size_t)(b*128 + m) * HW + p);
            dst[0]    = acc[i][j][0] + bs4.x;
            dst[HW]   = acc[i][j][1] + bs4.y;
            dst[2*HW] = acc[i][j][2] + bs4.z;
            dst[3*HW] = acc[i][j][3] + bs4.w;
        }
    }
}

// ---------------- dilated 7x7 conv: bf16 MFMA implicit GEMM, K-split x5, bf16 partials ----------------
__global__ __launch_bounds__(256, 2) void k_convmfma(
    const __hip_bfloat16* __restrict__ Wbf, const __hip_bfloat16* __restrict__ XT,
    __hip_bfloat16* __restrict__ o0, __hip_bfloat16* __restrict__ o1,
    __hip_bfloat16* __restrict__ o2, __hip_bfloat16* __restrict__ o3,
    __hip_bfloat16* __restrict__ o4)
{
    __shared__ __hip_bfloat16 As[8192];
    __shared__ __hip_bfloat16 Bs[8192];
    const int tid  = threadIdx.x;
    const int w    = tid >> 6;
    const int lane = tid & 63;
    const int n0   = blockIdx.x * 128;
    const int s    = blockIdx.y;                 // 0..4
    const int t_start = (s < 4) ? s * 40 : 158;  // tiles: 40,40,40,38,38 (196 total)
    const int cnt     = (s < 3) ? 40 : 38;
    __hip_bfloat16* __restrict__ out = (s==0)?o0:(s==1)?o1:(s==2)?o2:(s==3)?o3:o4;

    unsigned aoffs[4], boffs[4];
    void *adst[4], *bdst[4];
    #pragma unroll
    for (int j = 0; j < 4; ++j) {
        const int slot = (w*4 + j)*64 + lane;
        const int row  = slot >> 3;
        const int q    = slot & 7;
        const int lc   = q ^ (row & 7);
        aoffs[j] = (unsigned)row * 12544u + (unsigned)lc * 8u;
        adst[j]  = (void*)&As[(w*4 + j) * 512];
        const int n = n0 + row;
        const int b = n / HW;
        const int p = n - b * HW;
        const int h = p / 56;
        const int ww = p - h * 56;
        boffs[j] = ((unsigned)(b*68 + h)*68 + (unsigned)ww)*256u + (unsigned)lc * 8u;
        bdst[j]  = (void*)&Bs[(w*4 + j) * 512];
    }

    const int l15 = lane & 15, lg = lane >> 4;
    const int m_w0 = (w & 1) * 64;
    const int n_w0 = (w >> 1) * 64;
    int rowA[4], rowB[4], chunkoff[2];
    #pragma unroll
    for (int i = 0; i < 4; ++i) {
        rowA[i] = (m_w0 + i*16 + l15) * 128;
        rowB[i] = (n_w0 + i*16 + l15) * 128;
    }
    #pragma unroll
    for (int ks = 0; ks < 2; ++ks)
        chunkoff[ks] = ((4*ks + lg) ^ (lane & 7)) * 16;

    f32x4 acc[4][4];
    #pragma unroll
    for (int i = 0; i < 4; ++i)
        #pragma unroll
        for (int j = 0; j < 4; ++j)
            acc[i][j] = (f32x4){0.f, 0.f, 0.f, 0.f};

    for (int it = 0; it < cnt; ++it) {
        const int kt = t_start + it;
        const int k0 = kt << 6;
        const int t  = k0 >> 8;
        const int c0 = k0 & 255;
        const int ti = (t * 37) >> 8;
        const int tj = t - ti * 7;
        const unsigned aof = (unsigned)k0;
        const unsigned bof = (unsigned)(ti*68 + tj) * 512u + (unsigned)c0;

        #pragma unroll
        for (int j = 0; j < 4; ++j) gll16(Wbf + aoffs[j] + aof, adst[j]);
        #pragma unroll
        for (int j = 0; j < 4; ++j) gll16(XT + boffs[j] + bof, bdst[j]);

        __syncthreads();

        #pragma unroll
        for (int ks = 0; ks < 2; ++ks) {
            const int co = chunkoff[ks];
            bf16x8 av[4], bv[4];
            #pragma unroll
            for (int i = 0; i < 4; ++i)
                av[i] = *(const bf16x8*)((const char*)As + rowA[i] + co);
            #pragma unroll
            for (int i = 0; i < 4; ++i)
                bv[i] = *(const bf16x8*)((const char*)Bs + rowB[i] + co);
            #pragma unroll
            for (int i = 0; i < 4; ++i)
                #pragma unroll
                for (int j = 0; j < 4; ++j)
                    acc[i][j] = __builtin_amdgcn_mfma_f32_16x16x32_bf16(av[i], bv[j], acc[i][j], 0, 0, 0);
        }
        __syncthreads();
    }

    #pragma unroll
    for (int j = 0; j < 4; ++j) {
        const int n = n0 + n_w0 + j*16 + l15;
        const int b = n / HW;
        const int p = n - b * HW;
        #pragma unroll
        for (int i = 0; i < 4; ++i) {
            const int m = m_w0 + i*16 + lg*4;
            __hip_bfloat16* dst = out + ((size_t)(b*128 + m) * HW + p);
            dst[0]      = __float2bfloat16(acc[i][j][0]);
            dst[HW]     = __float2bfloat16(acc[i][j][1]);
            dst[2*HW]   = __float2bfloat16(acc[i][j][2]);
            dst[3*HW]   = __float2bfloat16(acc[i][j][3]);
        }
    }
}

// ---------------- combine 5 bf16 partials + bias + relu -> k1 (short8-vectorized) ----------------
__global__ __launch_bounds__(256) void k_combine5(
    const short8v* __restrict__ p0, const short8v* __restrict__ p1,
    const short8v* __restrict__ p2, const short8v* __restrict__ p3,
    const short8v* __restrict__ p4,
    const float* __restrict__ bias, float* __restrict__ Y)
{
    const int j = blockIdx.x * 256 + threadIdx.x;    // over 200,704 (= 1,605,632/8)
    short8v a = p0[j], b = p1[j], c = p2[j], d = p3[j], e5 = p4[j];
    const int oc = ((j * 8) / HW) & 127;             // 3136 % 8 == 0: no oc straddle
    const float bv = bias[oc];
    float o[8];
    #pragma unroll
    for (int e = 0; e < 8; ++e) {
        float v = bf2f(a[e]) + bf2f(b[e]) + bf2f(c[e]) + bf2f(d[e]) + bf2f(e5[e]) + bv;
        o[e] = fmaxf(v, 0.f);
    }
    float4* dst = (float4*)(Y + (size_t)j * 8);
    dst[0] = *(float4*)&o[0];
    dst[1] = *(float4*)&o[4];
}

// ---------------- BN batch stats (validated) ----------------
__global__ __launch_bounds__(256) void k_bnstats(const float* __restrict__ X, int nch,
                                                 float* __restrict__ meanOut,
                                                 float* __restrict__ rstdOut)
{
    const int ch  = blockIdx.x;
    const int tid = threadIdx.x;
    float s1 = 0.f, s2 = 0.f;
    for (int b = 0; b < 4; ++b) {
        const float* base = X + ((size_t)b * nch + ch) * HW;
        for (int p = tid; p < HW; p += 256) { float v = base[p]; s1 += v; s2 += v * v; }
    }
    for (int off = 32; off > 0; off >>= 1) {
        s1 += __shfl_down(s1, off);
        s2 += __shfl_down(s2, off);
    }
    __shared__ float r1[4], r2[4];
    const int lane = tid & 63, wv = tid >> 6;
    if (lane == 0) { r1[wv] = s1; r2[wv] = s2; }
    __syncthreads();
    if (tid == 0) {
        float a = r1[0] + r1[1] + r1[2] + r1[3];
        float q = r2[0] + r2[1] + r2[2] + r2[3];
        float mean = a * (1.f / 12544.f);
        float var  = q * (1.f / 12544.f) - mean * mean;
        meanOut[ch] = mean;
        rstdOut[ch] = rsqrtf(var + 1e-5f);
    }
}

// ---------------- fused BN + relu + softmax over 49 channels (validated) ----------------
__global__ __launch_bounds__(256) void k_bnsoftmax(float* __restrict__ X,
        const float* __restrict__ mean, const float* __restrict__ rstd,
        const float* __restrict__ gam,  const float* __restrict__ bet)
{
    const int gidx = blockIdx.x * 256 + threadIdx.x;
    const int b = gidx / HW;
    const int p = gidx - b * HW;
    float* base = X + (size_t)b * NT * HW + p;
    float vals[NT];
    float m = -1e30f;
    #pragma unroll
    for (int t = 0; t < NT; ++t) {
        float v = base[(size_t)t * HW];
        v = (v - mean[t]) * rstd[t] * gam[t] + bet[t];
        v = fmaxf(v, 0.f);
        vals[t] = v;
        m = fmaxf(m, v);
    }
    float s = 0.f;
    #pragma unroll
    for (int t = 0; t < NT; ++t) { float e = __expf(vals[t] - m); vals[t] = e; s += e; }
    const float inv = 1.f / s;
    #pragma unroll
    for (int t = 0; t < NT; ++t) base[(size_t)t * HW] = vals[t] * inv;
}

// ---------------- attention apply v2: register-blocked, LDS-free (validated) ----------------
__global__ __launch_bounds__(256) void k_attapply2(const float* __restrict__ Xpad,
        const float* __restrict__ att, float* __restrict__ Y)
{
    const int tid  = threadIdx.x;
    const int wv   = tid >> 6;
    const int lane = tid & 63;
    const int wq   = lane & 15;          // active < 14
    const int rs   = lane >> 4;
    const int rq   = blockIdx.x;         // 0..13
    const int cg   = blockIdx.y;         // 0..63
    const int b    = blockIdx.z;         // 0..3
    const int c    = cg * 4 + wv;
    const int h    = rq * 4 + rs;
    const int w0   = min(wq, 13) * 4;

    const float* xbase = Xpad + ((size_t)(b*256 + c) * 68 + h) * 68 + w0;
    const float* abase = att + (size_t)b * NT * HW + h * 56 + w0;
    float4 acc = {0.f, 0.f, 0.f, 0.f};
    #pragma unroll
    for (int ti = 0; ti < 7; ++ti) {
        const float* xr = xbase + ti * 136;          // row h + 2*ti
        float xf[16];
        *(float4*)&xf[0]  = *(const float4*)(xr);
        *(float4*)&xf[4]  = *(const float4*)(xr + 4);
        *(float4*)&xf[8]  = *(const float4*)(xr + 8);
        *(float4*)&xf[12] = *(const float4*)(xr + 12);
        #pragma unroll
        for (int tj = 0; tj < 7; ++tj) {
            const float4 a4 = *(const float4*)(abase + (size_t)(ti*7 + tj) * HW);
            acc.x = fmaf(xf[2*tj + 0], a4.x, acc.x);
            acc.y = fmaf(xf[2*tj + 1], a4.y, acc.y);
            acc.z = fmaf(xf[2*tj + 2], a4.z, acc.z);
            acc.w = fmaf(xf[2*tj + 3], a4.w, acc.w);
        }
    }
    if (wq < 14)
        *(float4*)(Y + (size_t)(b*256 + c) * HW + h * 56 + w0) = acc;
}

// ---------------- fused final BN + relu -> dec_out, + sigmoid(c3) -> side (validated) ----------------
__global__ __launch_bounds__(256) void k_bnside(const float* __restrict__ X,
        const float* __restrict__ mean, const float* __restrict__ rstd,
        const float* __restrict__ gam,  const float* __restrict__ bet,
        const float* __restrict__ w3,   const float* __restrict__ b3,
        float* __restrict__ dec_out,    float* __restrict__ side)
{
    __shared__ float ms[128], rs[128], gs[128], bs[128], w3s[128];
    const int tid = threadIdx.x;
    if (tid < 128) {
        ms[tid] = mean[tid]; rs[tid] = rstd[tid];
        gs[tid] = gam[tid];  bs[tid] = bet[tid];
        w3s[tid] = w3[tid];
    }
    __syncthreads();
    const int gidx = blockIdx.x * 256 + tid;    // exactly 12544
    const int b = gidx / HW;
    const int p = gidx - b * HW;
    const size_t u = (size_t)b * 128 * HW + p;
    float acc = b3[0];
    #pragma unroll 8
    for (int c = 0; c < 128; ++c) {
        const size_t a = u + (size_t)c * HW;
        float v = (X[a] - ms[c]) * rs[c] * gs[c] + bs[c];
        v = fmaxf(v, 0.f);
        dec_out[a] = v;
        acc = fmaf(v, w3s[c], acc);
    }
    side[gidx] = 1.f / (1.f + __expf(-acc));
}

// ---------------- launcher ----------------
extern "C" void kernel_launch(void* const* d_in, const int* in_sizes, int n_in,
                              void* d_out, int out_size, void* d_ws, size_t ws_size,
                              hipStream_t stream)
{
    const float* en  = (const float*)d_in[0];
    const float* dec = (const float*)d_in[1];
    const float* w1  = (const float*)d_in[2];
    const float* b1  = (const float*)d_in[3];
    const float* w2  = (const float*)d_in[4];
    const float* b2  = (const float*)d_in[5];
    const float* bng = (const float*)d_in[6];
    const float* bnb = (const float*)d_in[7];
    const float* c1w = (const float*)d_in[8];
    const float* c1b = (const float*)d_in[9];
    const float* c2w = (const float*)d_in[10];
    const float* c2b = (const float*)d_in[11];
    const float* bfg = (const float*)d_in[12];
    const float* bfb = (const float*)d_in[13];
    const float* c3w = (const float*)d_in[14];
    const float* c3b = (const float*)d_in[15];

    float* ws = (float*)d_ws;                   // 20,750,848 floats (proven extent)
    __hip_bfloat16* part0 = (__hip_bfloat16*)(ws + R0);             // dead after combine5
    __hip_bfloat16* part1 = (__hip_bfloat16*)(ws + R0 +  802816u);
    __hip_bfloat16* part2 = (__hip_bfloat16*)(ws + R0 + 1605632u);
    __hip_bfloat16* part3 = (__hip_bfloat16*)(ws + R0 + 2408448u);
    float* fmap_att = ws + R0;                  // region base after combine (parts dead)
    float* attb     = ws + R1;
    float* xpad     = ws + R2;
    float* k1       = ws + R3;
    __hip_bfloat16* c2wb = (__hip_bfloat16*)(ws + R3);              // overlays k1 AFTER w2-gemm
    __hip_bfloat16* xcat = (__hip_bfloat16*)(ws + R4);              // dead before part4 written
    __hip_bfloat16* part4 = (__hip_bfloat16*)(ws + R4);
    __hip_bfloat16* attT  = (__hip_bfloat16*)(ws + R4);             // part4 dead after combine
    float* x2       = ws + R4 + 1605632u;                           // upper half of R4
    __hip_bfloat16* c1wb = (__hip_bfloat16*)(ws + R5);
    float* stats    = ws + R6;
    __hip_bfloat16* xpadT = (__hip_bfloat16*)(ws + R7);
    __hip_bfloat16* wbf   = (__hip_bfloat16*)(ws + R8);

    float* dec_out = (float*)d_out;
    float* side    = (float*)d_out + 1605632u;

    // 0. zero padded buffers (borders must be 0 every call; interiors overwritten by gemmc1)
    hipMemsetAsync(xpad,  0, (size_t)4 * 256 * PADA * sizeof(float), stream);
    hipMemsetAsync(xpadT, 0, (size_t)4 * PADA * 256 * sizeof(__hip_bfloat16), stream);
    // 1. en -> xcat[:, 0:256]; dec -(fused bilinear)-> xcat[:, 256:512]
    k_t2nhwc<<<dim3(49, 4, 4), dim3(256), 0, stream>>>(en, xcat, 512, 0);
    k_t2up<<<dim3(49, 4, 4), dim3(256), 0, stream>>>(dec, xcat, 512, 256);
    // 2. c1 weight -> bf16
    k_cvt<<<dim3(512), dim3(256), 0, stream>>>(c1w, c1wb);
    // 3. relu(c1 x xcat) via MFMA -> xpad (fp32) + xpadT (bf16)
    k_gemmc1<<<dim3(98, 2), dim3(256), 0, stream>>>(c1wb, xcat, c1b, xpad, xpadT);
    // 4. w1 -> bf16 [oc][t*256+c]
    k_w1bf2<<<dim3(128), dim3(256), 0, stream>>>(w1, wbf);
    // 5. big dilated conv (K-split x5 for load balance, bf16 partials)
    k_convmfma<<<dim3(98, 5), dim3(256), 0, stream>>>(wbf, xpadT, part0, part1, part2, part3, part4);
    // 6. combine -> k1
    k_combine5<<<dim3(784), dim3(256), 0, stream>>>((const short8v*)part0, (const short8v*)part1,
                                                    (const short8v*)part2, (const short8v*)part3,
                                                    (const short8v*)part4, b1, k1);
    // 7. attention logits = w2 * k1 + b2 (fp32)
    k_gemm1x1<<<dim3(1, 98), dim3(256), 0, stream>>>(w2, b2, k1, 49, 128, attb);
    // 8-9. BN stats + BN/relu/softmax
    k_bnstats<<<dim3(49), dim3(256), 0, stream>>>(attb, 49, stats + 0, stats + 64);
    k_bnsoftmax<<<dim3(49), dim3(256), 0, stream>>>(attb, stats + 0, stats + 64, bng, bnb);
    // 10. local attention gather -> fmap_att (parts dead; fmap_att at R0 base)
    k_attapply2<<<dim3(14, 64, 4), dim3(256), 0, stream>>>(xpad, attb, fmap_att);
    // 11. fmap_att -> attT NHWC bf16 (part4/xcat slot, dead)
    k_t2nhwc<<<dim3(49, 4, 4), dim3(256), 0, stream>>>(fmap_att, attT, 256, 0);
    // 12. c2 weight -> bf16 (k1 dead after step 7)
    k_cvt<<<dim3(256), dim3(256), 0, stream>>>(c2w, c2wb);
    // 13. x2 = c2 x [xpadT(center) ; attT] via MFMA
    k_gemmc2<<<dim3(98), dim3(256), 0, stream>>>(c2wb, xpadT, attT, c2b, x2);
    // 14. BN stats over x2
    k_bnstats<<<dim3(128), dim3(256), 0, stream>>>(x2, 128, stats + 128, stats + 256);
    // 15. fused BN/relu -> dec_out + sigmoid side
    k_bnside<<<dim3(49), dim3(256), 0, stream>>>(x2, stats + 128, stats + 256, bfg, bfb,
                                                 c3w, c3b, dec_out, side);
}

// Round 13
// 203.325 us; speedup vs baseline: 1.1447x; 1.1152x over previous
//
#include <hip/hip_runtime.h>
#include <hip/hip_bf16.h>
#include <math.h>

// ---------------- problem constants ----------------
#define HW    3136        // 56*56
#define PADA  4624        // 68*68 padded plane (fp32 NCHW)
#define NT    49
#define NBLK  98          // n-blocks (12544/128)

// ---------------- workspace regions (float offsets) — proven extent ----------------
// R0: part0..part3 (bf16, dead after combine) -> fmap_att at base
// R1: attb [4][49][3136]
// R2: xpad fp32 [4][256][68][68]
// R3: k1 -> c2wb bf16 (after w2-gemm consumed k1)
// R4: xcat bf16 -> part4 (bf16, base) -> attT bf16 (base); x2 fp32 (upper half)
// R5: c1wb bf16 (dead after gemmc1) ; +65536: c2s1,c2s2,atts1,atts2 partial-sum scratch
// R7: xpadT bf16 [4][68][68][256]
// R8: wbf bf16 [128][12544]
#define R0 0u
#define R1 3211264u
#define R2 6422528u
#define R3 11157504u
#define R4 12763136u
#define R5 15974400u
#define R7 17580544u
#define R8 19948032u

typedef __attribute__((ext_vector_type(8))) short bf16x8;
typedef __attribute__((ext_vector_type(8))) short short8v;
typedef __attribute__((ext_vector_type(4))) float f32x4;

__device__ __forceinline__ void gll16(const void* g, void* l) {
    __builtin_amdgcn_global_load_lds((const __attribute__((address_space(1))) void*)g,
                                     (__attribute__((address_space(3))) void*)l, 16, 0, 0);
}

__device__ __forceinline__ float bf2f(short u) {
    return __uint_as_float(((unsigned)(unsigned short)u) << 16);
}

// ---------------- tiled NCHW fp32 -> NHWC bf16 transpose (validated) ----------------
__global__ __launch_bounds__(256) void k_t2nhwc(const float* __restrict__ src,
        __hip_bfloat16* __restrict__ dst, int kstride, int c_off)
{
    __shared__ float t[64][65];
    const int tid = threadIdx.x;
    const int p0 = blockIdx.x * 64;
    const int c0 = blockIdx.y * 64;
    const int b  = blockIdx.z;
    const int pl = tid & 63, cr = tid >> 6;
    #pragma unroll
    for (int i = 0; i < 16; ++i) {
        const int c = c0 + i*4 + cr;
        t[i*4+cr][pl] = src[((size_t)(b*256 + c)) * HW + p0 + pl];
    }
    __syncthreads();
    const int cl = tid & 63, pr = tid >> 6;
    #pragma unroll
    for (int i = 0; i < 16; ++i) {
        const int p = p0 + i*4 + pr;
        dst[((size_t)(b*HW + p)) * kstride + c_off + c0 + cl] = __float2bfloat16(t[cl][i*4+pr]);
    }
}

// ---------------- fused bilinear-upsample + transpose (validated) ----------------
__global__ __launch_bounds__(256) void k_t2up(const float* __restrict__ dec,
        __hip_bfloat16* __restrict__ dst, int kstride, int c_off)
{
    __shared__ float t[64][65];
    const int tid = threadIdx.x;
    const int p0 = blockIdx.x * 64;
    const int c0 = blockIdx.y * 64;
    const int b  = blockIdx.z;
    const int pl = tid & 63, cr = tid >> 6;

    const int p = p0 + pl;
    const int h = p / 56;
    const int w = p - h * 56;
    int ih0; float fh;
    if (h & 1) { ih0 = h >> 1;       fh = 0.25f; }
    else       { ih0 = (h >> 1) - 1; fh = 0.75f; }
    int ih1 = min(ih0 + 1, 27); ih0 = max(ih0, 0);
    int iw0; float fw;
    if (w & 1) { iw0 = w >> 1;       fw = 0.25f; }
    else       { iw0 = (w >> 1) - 1; fw = 0.75f; }
    int iw1 = min(iw0 + 1, 27); iw0 = max(iw0, 0);
    const int o00 = ih0*28 + iw0, o01 = ih0*28 + iw1;
    const int o10 = ih1*28 + iw0, o11 = ih1*28 + iw1;
    const float w00 = (1.f-fh)*(1.f-fw), w01 = (1.f-fh)*fw;
    const float w10 = fh*(1.f-fw),       w11 = fh*fw;

    #pragma unroll
    for (int i = 0; i < 16; ++i) {
        const int c = c0 + i*4 + cr;
        const float* s = dec + (size_t)(b*256 + c) * 784;
        t[i*4+cr][pl] = w00*s[o00] + w01*s[o01] + w10*s[o10] + w11*s[o11];
    }
    __syncthreads();
    const int cl = tid & 63, pr = tid >> 6;
    #pragma unroll
    for (int i = 0; i < 16; ++i) {
        const int pp = p0 + i*4 + pr;
        dst[((size_t)(b*HW + pp)) * kstride + c_off + c0 + cl] = __float2bfloat16(t[cl][i*4+pr]);
    }
}

// ---------------- fp32 -> bf16 straight convert ----------------
__global__ void k_cvt(const float* __restrict__ s, __hip_bfloat16* __restrict__ d)
{
    int j = blockIdx.x * 256 + threadIdx.x;
    d[j] = __float2bfloat16(s[j]);
}

// ---------------- w1 [128][256][49] -> Wbf [oc][k=t*256+c] bf16, LDS transpose (validated) ----------------
__global__ __launch_bounds__(256) void k_w1bf2(const float* __restrict__ w1,
        __hip_bfloat16* __restrict__ wt)
{
    __shared__ float t[NT * 257];
    const int tid = threadIdx.x;
    const int oc  = blockIdx.x;             // 128 blocks
    const float* src = w1 + (size_t)oc * 12544;
    #pragma unroll
    for (int i = 0; i < 49; ++i) {
        const int idx = i * 256 + tid;
        const int c  = idx / 49;
        const int tt = idx - c * 49;
        t[tt * 257 + c] = src[idx];
    }
    __syncthreads();
    __hip_bfloat16* dst = wt + (size_t)oc * 12544;
    #pragma unroll
    for (int i = 0; i < 49; ++i)
        dst[i * 256 + tid] = __float2bfloat16(t[i * 257 + tid]);
}

// ---------------- fp32 8x8 FMA microtile (w2 gemm only) ----------------
__device__ __forceinline__ void tile_fma(const float (*As)[128], const float (*Bs)[128],
                                         float acc[8][8], int tx, int ty)
{
    #pragma unroll
    for (int kk = 0; kk < 16; ++kk) {
        const float4 a0 = *(const float4*)&As[kk][ty*8];
        const float4 a1 = *(const float4*)&As[kk][ty*8+4];
        const float4 b0 = *(const float4*)&Bs[kk][tx*8];
        const float4 b1 = *(const float4*)&Bs[kk][tx*8+4];
        const float av[8] = {a0.x,a0.y,a0.z,a0.w,a1.x,a1.y,a1.z,a1.w};
        const float bv[8] = {b0.x,b0.y,b0.z,b0.w,b1.x,b1.y,b1.z,b1.w};
        #pragma unroll
        for (int e = 0; e < 8; ++e)
            #pragma unroll
            for (int f = 0; f < 8; ++f)
                acc[e][f] = fmaf(av[e], bv[f], acc[e][f]);
    }
}

// ---------------- fp32 1x1 GEMM (w2: M=49, K=128) + per-block BN partial sums ----------------
__global__ __launch_bounds__(256, 2) void k_gemm1x1(
    const float* __restrict__ W, const float* __restrict__ bias,
    const float* __restrict__ X0, int M, int K, float* __restrict__ Y,
    float* __restrict__ ps1, float* __restrict__ ps2)
{
    __shared__ float As[16][128];
    __shared__ float Bs[16][128];
    __shared__ float as1[128], as2[128];
    const int tid = threadIdx.x;
    const int tx = tid & 15, ty = tid >> 4;
    const int n0 = blockIdx.y * 128;

    const int amA = tid >> 2;
    const int kqA = tid & 3;
    const bool av0 = amA < M;
    const bool av1 = (amA + 64) < M;
    const size_t aoff0 = (size_t)amA * K + kqA * 4;
    const size_t aoff1 = (size_t)(amA + 64) * K + kqA * 4;

    const int colB = tid & 127;
    const int kkb  = tid >> 7;
    const int nB = n0 + colB;
    const int bB = nB / HW;
    const int pB = nB - bB * HW;
    const size_t u0 = (size_t)bB * K * HW + pB;

    float acc[8][8] = {};

    for (int k0 = 0; k0 < K; k0 += 16) {
        float4 va = av0 ? *(const float4*)(W + aoff0 + k0) : make_float4(0.f,0.f,0.f,0.f);
        float4 vb = av1 ? *(const float4*)(W + aoff1 + k0) : make_float4(0.f,0.f,0.f,0.f);
        As[kqA*4+0][amA] = va.x; As[kqA*4+1][amA] = va.y;
        As[kqA*4+2][amA] = va.z; As[kqA*4+3][amA] = va.w;
        As[kqA*4+0][amA+64] = vb.x; As[kqA*4+1][amA+64] = vb.y;
        As[kqA*4+2][amA+64] = vb.z; As[kqA*4+3][amA+64] = vb.w;
        #pragma unroll
        for (int e = 0; e < 8; ++e) {
            const int kk = e*2 + kkb;
            Bs[kk][colB] = X0[u0 + (size_t)(k0 + kk) * HW];
        }
        __syncthreads();
        tile_fma(As, Bs, acc, tx, ty);
        __syncthreads();
    }

    float s1v[8] = {}, s2v[8] = {};
    const int nE = n0 + tx*8;
    const int bE0 = nE / HW;
    const int pE0 = nE - bE0 * HW;
    #pragma unroll
    for (int e = 0; e < 8; ++e) {
        const int m = ty*8 + e;
        if (m < M) {
            const float bsv = bias[m];
            int b = bE0, p = pE0;
            #pragma unroll
            for (int f = 0; f < 8; ++f) {
                const float v = acc[e][f] + bsv;
                Y[((size_t)b * M + m) * HW + p] = v;
                s1v[e] += v;
                s2v[e] += v * v;
                if (++p == HW) { p = 0; ++b; }
            }
        }
    }
    // butterfly over tx (low 4 lane bits): per-(block,m) sums
    #pragma unroll
    for (int e = 0; e < 8; ++e) {
        #pragma unroll
        for (int msk = 1; msk <= 8; msk <<= 1) {
            s1v[e] += __shfl_xor(s1v[e], msk);
            s2v[e] += __shfl_xor(s2v[e], msk);
        }
    }
    if (tx == 0) {
        #pragma unroll
        for (int e = 0; e < 8; ++e) {
            const int m = ty*8 + e;
            if (m < 128) { as1[m] = s1v[e]; as2[m] = s2v[e]; }
        }
    }
    __syncthreads();
    if (tid < M) {
        ps1[blockIdx.y * M + tid] = as1[tid];
        ps2[blockIdx.y * M + tid] = as2[tid];
    }
}

// ---------------- c1 MFMA GEMM: epilogue writes xpad (fp32) + xpadT (bf16) — validated ----------------
__global__ __launch_bounds__(256, 2) void k_gemmc1(
    const __hip_bfloat16* __restrict__ A, const __hip_bfloat16* __restrict__ B0,
    const float* __restrict__ bias, float* __restrict__ Xpad,
    __hip_bfloat16* __restrict__ XpadT)
{
    __shared__ __hip_bfloat16 As[8192];
    __shared__ __hip_bfloat16 Bs[8192];
    const int tid  = threadIdx.x;
    const int w    = tid >> 6;
    const int lane = tid & 63;
    const int n0   = blockIdx.x * 128;
    const int m0   = blockIdx.y * 128;

    unsigned aoffs[4], boffs[4];
    void *adst[4], *bdst[4];
    #pragma unroll
    for (int j = 0; j < 4; ++j) {
        const int slot = (w*4 + j)*64 + lane;
        const int row  = slot >> 3;
        const int q    = slot & 7;
        const int lc   = q ^ (row & 7);
        aoffs[j] = (unsigned)(m0 + row) * 512u + (unsigned)lc * 8u;
        adst[j]  = (void*)&As[(w*4 + j) * 512];
        boffs[j] = (unsigned)(n0 + row) * 512u + (unsigned)lc * 8u;
        bdst[j]  = (void*)&Bs[(w*4 + j) * 512];
    }

    const int l15 = lane & 15, lg = lane >> 4;
    const int m_w0 = (w & 1) * 64;
    const int n_w0 = (w >> 1) * 64;
    int rowA[4], rowB[4], chunkoff[2];
    #pragma unroll
    for (int i = 0; i < 4; ++i) {
        rowA[i] = (m_w0 + i*16 + l15) * 128;
        rowB[i] = (n_w0 + i*16 + l15) * 128;
    }
    #pragma unroll
    for (int ks = 0; ks < 2; ++ks)
        chunkoff[ks] = ((4*ks + lg) ^ (lane & 7)) * 16;

    f32x4 acc[4][4];
    #pragma unroll
    for (int i = 0; i < 4; ++i)
        #pragma unroll
        for (int j = 0; j < 4; ++j)
            acc[i][j] = (f32x4){0.f, 0.f, 0.f, 0.f};

    for (int k0 = 0; k0 < 512; k0 += 64) {
        #pragma unroll
        for (int j = 0; j < 4; ++j) gll16(A + aoffs[j] + k0, adst[j]);
        #pragma unroll
        for (int j = 0; j < 4; ++j) gll16(B0 + boffs[j] + k0, bdst[j]);
        __syncthreads();
        #pragma unroll
        for (int ks = 0; ks < 2; ++ks) {
            const int co = chunkoff[ks];
            bf16x8 av[4], bv[4];
            #pragma unroll
            for (int i = 0; i < 4; ++i)
                av[i] = *(const bf16x8*)((const char*)As + rowA[i] + co);
            #pragma unroll
            for (int i = 0; i < 4; ++i)
                bv[i] = *(const bf16x8*)((const char*)Bs + rowB[i] + co);
            #pragma unroll
            for (int i = 0; i < 4; ++i)
                #pragma unroll
                for (int j = 0; j < 4; ++j)
                    acc[i][j] = __builtin_amdgcn_mfma_f32_16x16x32_bf16(av[i], bv[j], acc[i][j], 0, 0, 0);
        }
        __syncthreads();
    }

    #pragma unroll
    for (int j = 0; j < 4; ++j) {
        const int n = n0 + n_w0 + j*16 + l15;
        const int b = n / HW;
        const int p = n - b * HW;
        const int h = p / 56;
        const int ww = p - h * 56;
        #pragma unroll
        for (int i = 0; i < 4; ++i) {
            const int m = m0 + m_w0 + i*16 + lg*4;
            const float4 bs4 = *(const float4*)&bias[m];
            float v0 = fmaxf(acc[i][j][0] + bs4.x, 0.f);
            float v1 = fmaxf(acc[i][j][1] + bs4.y, 0.f);
            float v2 = fmaxf(acc[i][j][2] + bs4.z, 0.f);
            float v3 = fmaxf(acc[i][j][3] + bs4.w, 0.f);
            float* dp = Xpad + ((size_t)(b*256 + m)) * PADA + (h + 6) * 68 + (ww + 6);
            dp[0]      = v0;
            dp[PADA]   = v1;
            dp[2*PADA] = v2;
            dp[3*PADA] = v3;
            ushort4 pk;
            pk.x = __bfloat16_as_ushort(__float2bfloat16(v0));
            pk.y = __bfloat16_as_ushort(__float2bfloat16(v1));
            pk.z = __bfloat16_as_ushort(__float2bfloat16(v2));
            pk.w = __bfloat16_as_ushort(__float2bfloat16(v3));
            *(ushort4*)(XpadT + ((size_t)((b*68 + h + 6)*68 + ww + 6)) * 256 + m) = pk;
        }
    }
}

// ---------------- c2 MFMA GEMM + per-block BN partial sums ----------------
__global__ __launch_bounds__(256, 2) void k_gemmc2(
    const __hip_bfloat16* __restrict__ A, const __hip_bfloat16* __restrict__ XT,
    const __hip_bfloat16* __restrict__ AT, const float* __restrict__ bias,
    float* __restrict__ Y, float* __restrict__ ps1, float* __restrict__ ps2)
{
    __shared__ __hip_bfloat16 As[8192];
    __shared__ __hip_bfloat16 Bs[8192];
    __shared__ float bs1[2][128], bs2[2][128];
    const int tid  = threadIdx.x;
    const int w    = tid >> 6;
    const int lane = tid & 63;
    const int n0   = blockIdx.x * 128;

    unsigned aoffs[4], boffs0[4], boffs1[4];
    void *adst[4], *bdst[4];
    #pragma unroll
    for (int j = 0; j < 4; ++j) {
        const int slot = (w*4 + j)*64 + lane;
        const int row  = slot >> 3;
        const int q    = slot & 7;
        const int lc   = q ^ (row & 7);
        aoffs[j] = (unsigned)row * 512u + (unsigned)lc * 8u;
        adst[j]  = (void*)&As[(w*4 + j) * 512];
        const int n = n0 + row;
        const int b = n / HW;
        const int p = n - b * HW;
        const int h = p / 56;
        const int ww = p - h * 56;
        boffs0[j] = ((unsigned)(b*68 + h + 6)*68 + (unsigned)(ww + 6))*256u + (unsigned)lc * 8u;
        boffs1[j] = (unsigned)n * 256u + (unsigned)lc * 8u;
        bdst[j]  = (void*)&Bs[(w*4 + j) * 512];
    }

    const int l15 = lane & 15, lg = lane >> 4;
    const int m_w0 = (w & 1) * 64;
    const int n_w0 = (w >> 1) * 64;
    int rowA[4], rowB[4], chunkoff[2];
    #pragma unroll
    for (int i = 0; i < 4; ++i) {
        rowA[i] = (m_w0 + i*16 + l15) * 128;
        rowB[i] = (n_w0 + i*16 + l15) * 128;
    }
    #pragma unroll
    for (int ks = 0; ks < 2; ++ks)
        chunkoff[ks] = ((4*ks + lg) ^ (lane & 7)) * 16;

    f32x4 acc[4][4];
    #pragma unroll
    for (int i = 0; i < 4; ++i)
        #pragma unroll
        for (int j = 0; j < 4; ++j)
            acc[i][j] = (f32x4){0.f, 0.f, 0.f, 0.f};

    for (int k0 = 0; k0 < 512; k0 += 64) {
        #pragma unroll
        for (int j = 0; j < 4; ++j) gll16(A + aoffs[j] + k0, adst[j]);
        if (k0 < 256) {
            #pragma unroll
            for (int j = 0; j < 4; ++j) gll16(XT + boffs0[j] + k0, bdst[j]);
        } else {
            #pragma unroll
            for (int j = 0; j < 4; ++j) gll16(AT + boffs1[j] + (k0 - 256), bdst[j]);
        }
        __syncthreads();
        #pragma unroll
        for (int ks = 0; ks < 2; ++ks) {
            const int co = chunkoff[ks];
            bf16x8 av[4], bv[4];
            #pragma unroll
            for (int i = 0; i < 4; ++i)
                av[i] = *(const bf16x8*)((const char*)As + rowA[i] + co);
            #pragma unroll
            for (int i = 0; i < 4; ++i)
                bv[i] = *(const bf16x8*)((const char*)Bs + rowB[i] + co);
            #pragma unroll
            for (int i = 0; i < 4; ++i)
                #pragma unroll
                for (int j = 0; j < 4; ++j)
                    acc[i][j] = __builtin_amdgcn_mfma_f32_16x16x32_bf16(av[i], bv[j], acc[i][j], 0, 0, 0);
        }
        __syncthreads();
    }

    float s1loc[16] = {}, s2loc[16] = {};
    #pragma unroll
    for (int j = 0; j < 4; ++j) {
        const int n = n0 + n_w0 + j*16 + l15;
        const int b = n / HW;
        const int p = n - b * HW;
        #pragma unroll
        for (int i = 0; i < 4; ++i) {
            const int m = m_w0 + i*16 + lg*4;
            const float4 bs4 = *(const float4*)&bias[m];
            float v0 = acc[i][j][0] + bs4.x;
            float v1 = acc[i][j][1] + bs4.y;
            float v2 = acc[i][j][2] + bs4.z;
            float v3 = acc[i][j][3] + bs4.w;
            float* dst = Y + ((size_t)(b*128 + m) * HW + p);
            dst[0]    = v0;
            dst[HW]   = v1;
            dst[2*HW] = v2;
            dst[3*HW] = v3;
            s1loc[i*4+0] += v0; s2loc[i*4+0] += v0*v0;
            s1loc[i*4+1] += v1; s2loc[i*4+1] += v1*v1;
            s1loc[i*4+2] += v2; s2loc[i*4+2] += v2*v2;
            s1loc[i*4+3] += v3; s2loc[i*4+3] += v3*v3;
        }
    }
    // butterfly over l15 (low 4 lane bits): sums across the 16 n-lanes
    #pragma unroll
    for (int k = 0; k < 16; ++k) {
        #pragma unroll
        for (int msk = 1; msk <= 8; msk <<= 1) {
            s1loc[k] += __shfl_xor(s1loc[k], msk);
            s2loc[k] += __shfl_xor(s2loc[k], msk);
        }
    }
    const int qn = w >> 1;     // n-half; waves (0,1)->q0 cover m 0..127, (2,3)->q1
    if (l15 == 0) {
        #pragma unroll
        for (int i = 0; i < 4; ++i)
            #pragma unroll
            for (int r = 0; r < 4; ++r) {
                const int m = m_w0 + i*16 + lg*4 + r;
                bs1[qn][m] = s1loc[i*4+r];
                bs2[qn][m] = s2loc[i*4+r];
            }
    }
    __syncthreads();
    if (tid < 128) {
        ps1[blockIdx.x * 128 + tid] = bs1[0][tid] + bs1[1][tid];
        ps2[blockIdx.x * 128 + tid] = bs2[0][tid] + bs2[1][tid];
    }
}

// ---------------- dilated 7x7 conv: bf16 MFMA implicit GEMM, K-split x5, bf16 partials (validated) ----------------
__global__ __launch_bounds__(256, 2) void k_convmfma(
    const __hip_bfloat16* __restrict__ Wbf, const __hip_bfloat16* __restrict__ XT,
    __hip_bfloat16* __restrict__ o0, __hip_bfloat16* __restrict__ o1,
    __hip_bfloat16* __restrict__ o2, __hip_bfloat16* __restrict__ o3,
    __hip_bfloat16* __restrict__ o4)
{
    __shared__ __hip_bfloat16 As[8192];
    __shared__ __hip_bfloat16 Bs[8192];
    const int tid  = threadIdx.x;
    const int w    = tid >> 6;
    const int lane = tid & 63;
    const int n0   = blockIdx.x * 128;
    const int s    = blockIdx.y;
    const int t_start = (s < 4) ? s * 40 : 158;
    const int cnt     = (s < 3) ? 40 : 38;
    __hip_bfloat16* __restrict__ out = (s==0)?o0:(s==1)?o1:(s==2)?o2:(s==3)?o3:o4;

    unsigned aoffs[4], boffs[4];
    void *adst[4], *bdst[4];
    #pragma unroll
    for (int j = 0; j < 4; ++j) {
        const int slot = (w*4 + j)*64 + lane;
        const int row  = slot >> 3;
        const int q    = slot & 7;
        const int lc   = q ^ (row & 7);
        aoffs[j] = (unsigned)row * 12544u + (unsigned)lc * 8u;
        adst[j]  = (void*)&As[(w*4 + j) * 512];
        const int n = n0 + row;
        const int b = n / HW;
        const int p = n - b * HW;
        const int h = p / 56;
        const int ww = p - h * 56;
        boffs[j] = ((unsigned)(b*68 + h)*68 + (unsigned)ww)*256u + (unsigned)lc * 8u;
        bdst[j]  = (void*)&Bs[(w*4 + j) * 512];
    }

    const int l15 = lane & 15, lg = lane >> 4;
    const int m_w0 = (w & 1) * 64;
    const int n_w0 = (w >> 1) * 64;
    int rowA[4], rowB[4], chunkoff[2];
    #pragma unroll
    for (int i = 0; i < 4; ++i) {
        rowA[i] = (m_w0 + i*16 + l15) * 128;
        rowB[i] = (n_w0 + i*16 + l15) * 128;
    }
    #pragma unroll
    for (int ks = 0; ks < 2; ++ks)
        chunkoff[ks] = ((4*ks + lg) ^ (lane & 7)) * 16;

    f32x4 acc[4][4];
    #pragma unroll
    for (int i = 0; i < 4; ++i)
        #pragma unroll
        for (int j = 0; j < 4; ++j)
            acc[i][j] = (f32x4){0.f, 0.f, 0.f, 0.f};

    for (int it = 0; it < cnt; ++it) {
        const int kt = t_start + it;
        const int k0 = kt << 6;
        const int t  = k0 >> 8;
        const int c0 = k0 & 255;
        const int ti = (t * 37) >> 8;
        const int tj = t - ti * 7;
        const unsigned aof = (unsigned)k0;
        const unsigned bof = (unsigned)(ti*68 + tj) * 512u + (unsigned)c0;

        #pragma unroll
        for (int j = 0; j < 4; ++j) gll16(Wbf + aoffs[j] + aof, adst[j]);
        #pragma unroll
        for (int j = 0; j < 4; ++j) gll16(XT + boffs[j] + bof, bdst[j]);

        __syncthreads();

        #pragma unroll
        for (int ks = 0; ks < 2; ++ks) {
            const int co = chunkoff[ks];
            bf16x8 av[4], bv[4];
            #pragma unroll
            for (int i = 0; i < 4; ++i)
                av[i] = *(const bf16x8*)((const char*)As + rowA[i] + co);
            #pragma unroll
            for (int i = 0; i < 4; ++i)
                bv[i] = *(const bf16x8*)((const char*)Bs + rowB[i] + co);
            #pragma unroll
            for (int i = 0; i < 4; ++i)
                #pragma unroll
                for (int j = 0; j < 4; ++j)
                    acc[i][j] = __builtin_amdgcn_mfma_f32_16x16x32_bf16(av[i], bv[j], acc[i][j], 0, 0, 0);
        }
        __syncthreads();
    }

    #pragma unroll
    for (int j = 0; j < 4; ++j) {
        const int n = n0 + n_w0 + j*16 + l15;
        const int b = n / HW;
        const int p = n - b * HW;
        #pragma unroll
        for (int i = 0; i < 4; ++i) {
            const int m = m_w0 + i*16 + lg*4;
            __hip_bfloat16* dst = out + ((size_t)(b*128 + m) * HW + p);
            dst[0]      = __float2bfloat16(acc[i][j][0]);
            dst[HW]     = __float2bfloat16(acc[i][j][1]);
            dst[2*HW]   = __float2bfloat16(acc[i][j][2]);
            dst[3*HW]   = __float2bfloat16(acc[i][j][3]);
        }
    }
}

// ---------------- combine 5 bf16 partials + bias + relu -> k1 (validated) ----------------
__global__ __launch_bounds__(256) void k_combine5(
    const short8v* __restrict__ p0, const short8v* __restrict__ p1,
    const short8v* __restrict__ p2, const short8v* __restrict__ p3,
    const short8v* __restrict__ p4,
    const float* __restrict__ bias, float* __restrict__ Y)
{
    const int j = blockIdx.x * 256 + threadIdx.x;
    short8v a = p0[j], b = p1[j], c = p2[j], d = p3[j], e5 = p4[j];
    const int oc = ((j * 8) / HW) & 127;
    const float bv = bias[oc];
    float o[8];
    #pragma unroll
    for (int e = 0; e < 8; ++e) {
        float v = bf2f(a[e]) + bf2f(b[e]) + bf2f(c[e]) + bf2f(d[e]) + bf2f(e5[e]) + bv;
        o[e] = fmaxf(v, 0.f);
    }
    float4* dst = (float4*)(Y + (size_t)j * 8);
    dst[0] = *(float4*)&o[0];
    dst[1] = *(float4*)&o[4];
}

// ---------------- fused BN(from partials) + relu + softmax over 49 channels ----------------
__global__ __launch_bounds__(256) void k_bnsoftmax(float* __restrict__ X,
        const float* __restrict__ ps1, const float* __restrict__ ps2,
        const float* __restrict__ gam,  const float* __restrict__ bet)
{
    __shared__ float msh[NT], rsh[NT];
    const int tid = threadIdx.x;
    if (tid < NT) {
        float s1 = 0.f, s2 = 0.f;
        for (int b = 0; b < NBLK; ++b) {
            s1 += ps1[b * NT + tid];
            s2 += ps2[b * NT + tid];
        }
        const float mean = s1 * (1.f / 12544.f);
        const float var  = s2 * (1.f / 12544.f) - mean * mean;
        msh[tid] = mean;
        rsh[tid] = rsqrtf(var + 1e-5f);
    }
    __syncthreads();

    const int gidx = blockIdx.x * 256 + tid;
    const int b = gidx / HW;
    const int p = gidx - b * HW;
    float* base = X + (size_t)b * NT * HW + p;
    float vals[NT];
    float m = -1e30f;
    #pragma unroll
    for (int t = 0; t < NT; ++t) {
        float v = base[(size_t)t * HW];
        v = (v - msh[t]) * rsh[t] * gam[t] + bet[t];
        v = fmaxf(v, 0.f);
        vals[t] = v;
        m = fmaxf(m, v);
    }
    float s = 0.f;
    #pragma unroll
    for (int t = 0; t < NT; ++t) { float e = __expf(vals[t] - m); vals[t] = e; s += e; }
    const float inv = 1.f / s;
    #pragma unroll
    for (int t = 0; t < NT; ++t) base[(size_t)t * HW] = vals[t] * inv;
}

// ---------------- attention apply v2: register-blocked, LDS-free (validated) ----------------
__global__ __launch_bounds__(256) void k_attapply2(const float* __restrict__ Xpad,
        const float* __restrict__ att, float* __restrict__ Y)
{
    const int tid  = threadIdx.x;
    const int wv   = tid >> 6;
    const int lane = tid & 63;
    const int wq   = lane & 15;
    const int rs   = lane >> 4;
    const int rq   = blockIdx.x;
    const int cg   = blockIdx.y;
    const int b    = blockIdx.z;
    const int c    = cg * 4 + wv;
    const int h    = rq * 4 + rs;
    const int w0   = min(wq, 13) * 4;

    const float* xbase = Xpad + ((size_t)(b*256 + c) * 68 + h) * 68 + w0;
    const float* abase = att + (size_t)b * NT * HW + h * 56 + w0;
    float4 acc = {0.f, 0.f, 0.f, 0.f};
    #pragma unroll
    for (int ti = 0; ti < 7; ++ti) {
        const float* xr = xbase + ti * 136;
        float xf[16];
        *(float4*)&xf[0]  = *(const float4*)(xr);
        *(float4*)&xf[4]  = *(const float4*)(xr + 4);
        *(float4*)&xf[8]  = *(const float4*)(xr + 8);
        *(float4*)&xf[12] = *(const float4*)(xr + 12);
        #pragma unroll
        for (int tj = 0; tj < 7; ++tj) {
            const float4 a4 = *(const float4*)(abase + (size_t)(ti*7 + tj) * HW);
            acc.x = fmaf(xf[2*tj + 0], a4.x, acc.x);
            acc.y = fmaf(xf[2*tj + 1], a4.y, acc.y);
            acc.z = fmaf(xf[2*tj + 2], a4.z, acc.z);
            acc.w = fmaf(xf[2*tj + 3], a4.w, acc.w);
        }
    }
    if (wq < 14)
        *(float4*)(Y + (size_t)(b*256 + c) * HW + h * 56 + w0) = acc;
}

// ---------------- fused BN(from partials) + relu -> dec_out, + sigmoid(c3) -> side ----------------
__global__ __launch_bounds__(256) void k_bnside(const float* __restrict__ X,
        const float* __restrict__ ps1, const float* __restrict__ ps2,
        const float* __restrict__ gam,  const float* __restrict__ bet,
        const float* __restrict__ w3,   const float* __restrict__ b3,
        float* __restrict__ dec_out,    float* __restrict__ side)
{
    __shared__ float ms[128], rs[128], gs[128], bs[128], w3s[128];
    const int tid = threadIdx.x;
    if (tid < 128) {
        float s1 = 0.f, s2 = 0.f;
        for (int b = 0; b < NBLK; ++b) {
            s1 += ps1[b * 128 + tid];
            s2 += ps2[b * 128 + tid];
        }
        const float mean = s1 * (1.f / 12544.f);
        const float var  = s2 * (1.f / 12544.f) - mean * mean;
        ms[tid] = mean;
        rs[tid] = rsqrtf(var + 1e-5f);
        gs[tid] = gam[tid];  bs[tid] = bet[tid];
        w3s[tid] = w3[tid];
    }
    __syncthreads();
    const int gidx = blockIdx.x * 256 + tid;
    const int b = gidx / HW;
    const int p = gidx - b * HW;
    const size_t u = (size_t)b * 128 * HW + p;
    float acc = b3[0];
    #pragma unroll 8
    for (int c = 0; c < 128; ++c) {
        const size_t a = u + (size_t)c * HW;
        float v = (X[a] - ms[c]) * rs[c] * gs[c] + bs[c];
        v = fmaxf(v, 0.f);
        dec_out[a] = v;
        acc = fmaf(v, w3s[c], acc);
    }
    side[gidx] = 1.f / (1.f + __expf(-acc));
}

// ---------------- launcher ----------------
extern "C" void kernel_launch(void* const* d_in, const int* in_sizes, int n_in,
                              void* d_out, int out_size, void* d_ws, size_t ws_size,
                              hipStream_t stream)
{
    const float* en  = (const float*)d_in[0];
    const float* dec = (const float*)d_in[1];
    const float* w1  = (const float*)d_in[2];
    const float* b1  = (const float*)d_in[3];
    const float* w2  = (const float*)d_in[4];
    const float* b2  = (const float*)d_in[5];
    const float* bng = (const float*)d_in[6];
    const float* bnb = (const float*)d_in[7];
    const float* c1w = (const float*)d_in[8];
    const float* c1b = (const float*)d_in[9];
    const float* c2w = (const float*)d_in[10];
    const float* c2b = (const float*)d_in[11];
    const float* bfg = (const float*)d_in[12];
    const float* bfb = (const float*)d_in[13];
    const float* c3w = (const float*)d_in[14];
    const float* c3b = (const float*)d_in[15];

    float* ws = (float*)d_ws;                   // 20,750,848 floats (proven extent)
    __hip_bfloat16* part0 = (__hip_bfloat16*)(ws + R0);
    __hip_bfloat16* part1 = (__hip_bfloat16*)(ws + R0 +  802816u);
    __hip_bfloat16* part2 = (__hip_bfloat16*)(ws + R0 + 1605632u);
    __hip_bfloat16* part3 = (__hip_bfloat16*)(ws + R0 + 2408448u);
    float* fmap_att = ws + R0;                  // region base after combine (parts dead)
    float* attb     = ws + R1;
    float* xpad     = ws + R2;
    float* k1       = ws + R3;
    __hip_bfloat16* c2wb = (__hip_bfloat16*)(ws + R3);
    __hip_bfloat16* xcat = (__hip_bfloat16*)(ws + R4);
    __hip_bfloat16* part4 = (__hip_bfloat16*)(ws + R4);
    __hip_bfloat16* attT  = (__hip_bfloat16*)(ws + R4);
    float* x2       = ws + R4 + 1605632u;
    __hip_bfloat16* c1wb = (__hip_bfloat16*)(ws + R5);    // 65536 float-slots; dead after gemmc1
    float* c2s1    = ws + R5 + 131072u;                   // 98*128
    float* c2s2    = ws + R5 + 143616u;                   // 98*128
    float* atts1   = ws + R5 + 156160u;                   // 98*49
    float* atts2   = ws + R5 + 160962u;                   // 98*49
    __hip_bfloat16* xpadT = (__hip_bfloat16*)(ws + R7);
    __hip_bfloat16* wbf   = (__hip_bfloat16*)(ws + R8);

    float* dec_out = (float*)d_out;
    float* side    = (float*)d_out + 1605632u;

    // 0. zero padded buffers (borders must be 0 every call; interiors overwritten by gemmc1)
    hipMemsetAsync(xpad,  0, (size_t)4 * 256 * PADA * sizeof(float), stream);
    hipMemsetAsync(xpadT, 0, (size_t)4 * PADA * 256 * sizeof(__hip_bfloat16), stream);
    // 1. en -> xcat[:, 0:256]; dec -(fused bilinear)-> xcat[:, 256:512]
    k_t2nhwc<<<dim3(49, 4, 4), dim3(256), 0, stream>>>(en, xcat, 512, 0);
    k_t2up<<<dim3(49, 4, 4), dim3(256), 0, stream>>>(dec, xcat, 512, 256);
    // 2. c1 weight -> bf16
    k_cvt<<<dim3(512), dim3(256), 0, stream>>>(c1w, c1wb);
    // 3. relu(c1 x xcat) via MFMA -> xpad (fp32) + xpadT (bf16)
    k_gemmc1<<<dim3(98, 2), dim3(256), 0, stream>>>(c1wb, xcat, c1b, xpad, xpadT);
    // 4. w1 -> bf16 [oc][t*256+c]
    k_w1bf2<<<dim3(128), dim3(256), 0, stream>>>(w1, wbf);
    // 5. big dilated conv (K-split x5, bf16 partials)
    k_convmfma<<<dim3(98, 5), dim3(256), 0, stream>>>(wbf, xpadT, part0, part1, part2, part3, part4);
    // 6. combine -> k1
    k_combine5<<<dim3(784), dim3(256), 0, stream>>>((const short8v*)part0, (const short8v*)part1,
                                                    (const short8v*)part2, (const short8v*)part3,
                                                    (const short8v*)part4, b1, k1);
    // 7. attention logits = w2 * k1 + b2, with fused BN partial sums
    k_gemm1x1<<<dim3(1, 98), dim3(256), 0, stream>>>(w2, b2, k1, 49, 128, attb, atts1, atts2);
    // 8. BN(from partials) + relu + softmax(49) in place
    k_bnsoftmax<<<dim3(49), dim3(256), 0, stream>>>(attb, atts1, atts2, bng, bnb);
    // 9. local attention gather -> fmap_att
    k_attapply2<<<dim3(14, 64, 4), dim3(256), 0, stream>>>(xpad, attb, fmap_att);
    // 10. fmap_att -> attT NHWC bf16
    k_t2nhwc<<<dim3(49, 4, 4), dim3(256), 0, stream>>>(fmap_att, attT, 256, 0);
    // 11. c2 weight -> bf16 (k1 dead after step 7)
    k_cvt<<<dim3(256), dim3(256), 0, stream>>>(c2w, c2wb);
    // 12. x2 = c2 x [xpadT(center) ; attT] via MFMA, with fused BN partial sums
    k_gemmc2<<<dim3(98), dim3(256), 0, stream>>>(c2wb, xpadT, attT, c2b, x2, c2s1, c2s2);
    // 13. fused BN(from partials)/relu -> dec_out + sigmoid side
    k_bnside<<<dim3(49), dim3(256), 0, stream>>>(x2, c2s1, c2s2, bfg, bfb,
                                                 c3w, c3b, dec_out, side);
}

// Round 14
// 184.383 us; speedup vs baseline: 1.2623x; 1.1027x over previous
//
#include <hip/hip_runtime.h>
#include <hip/hip_bf16.h>
#include <math.h>

// ---------------- problem constants ----------------
#define HW    3136        // 56*56
#define PADA  4624        // 68*68 padded plane (fp32 NCHW)
#define NT    49
#define NBLK  98          // n-blocks (12544/128)

// ---------------- workspace regions (float offsets) — proven extent ----------------
// R0: part0..part3 (bf16, dead after combine) -> fmap_att at base
// R1: attb [4][49][3136]
// R2: xpad fp32 [4][256][68][68]
// R3: k1
// R4: xcat bf16 -> part4 (bf16, base) -> attT bf16 (base); x2 fp32 (upper half)
// R5: c1wb bf16 | +65536: c2wb bf16 | +131072: c2s1,c2s2,atts1,atts2 scratch
// R7: xpadT bf16 [4][68][68][256]
// R8: wbf bf16 [128][12544]
#define R0 0u
#define R1 3211264u
#define R2 6422528u
#define R3 11157504u
#define R4 12763136u
#define R5 15974400u
#define R7 17580544u
#define R8 19948032u

typedef __attribute__((ext_vector_type(8))) short bf16x8;
typedef __attribute__((ext_vector_type(8))) short short8v;
typedef __attribute__((ext_vector_type(4))) float f32x4;

__device__ __forceinline__ void gll16(const void* g, void* l) {
    __builtin_amdgcn_global_load_lds((const __attribute__((address_space(1))) void*)g,
                                     (__attribute__((address_space(3))) void*)l, 16, 0, 0);
}

__device__ __forceinline__ float bf2f(short u) {
    return __uint_as_float(((unsigned)(unsigned short)u) << 16);
}

// ---------------- merged prep: en-transpose, dec-upsample-transpose, weight cvts, w1 reshape ----------------
// blocks: [0,784) t2nhwc(en->xcat@0) | [784,1568) t2up(dec->xcat@256) |
//         [1568,2080) cvt c1w | [2080,2336) cvt c2w | [2336,2464) w1bf2
__global__ __launch_bounds__(256) void k_prep(
    const float* __restrict__ en, const float* __restrict__ dec,
    const float* __restrict__ c1w, const float* __restrict__ c2w,
    const float* __restrict__ w1,
    __hip_bfloat16* __restrict__ xcat, __hip_bfloat16* __restrict__ c1wb,
    __hip_bfloat16* __restrict__ c2wb, __hip_bfloat16* __restrict__ wbf)
{
    __shared__ float sm[12593];          // union: w1bf2 needs 49*257; t2* need 64*65
    const int bid = blockIdx.x;
    const int tid = threadIdx.x;

    if (bid < 784) {
        // ---- t2nhwc(en -> xcat, kstride=512, c_off=0) ----
        const int p0 = (bid % 49) * 64;
        const int c0 = ((bid / 49) & 3) * 64;
        const int b  = bid / 196;
        const int pl = tid & 63, cr = tid >> 6;
        #pragma unroll
        for (int i = 0; i < 16; ++i) {
            const int c = c0 + i*4 + cr;
            sm[(i*4+cr)*65 + pl] = en[((size_t)(b*256 + c)) * HW + p0 + pl];
        }
        __syncthreads();
        const int cl = tid & 63, pr = tid >> 6;
        #pragma unroll
        for (int i = 0; i < 16; ++i) {
            const int p = p0 + i*4 + pr;
            xcat[((size_t)(b*HW + p)) * 512 + c0 + cl] = __float2bfloat16(sm[cl*65 + i*4+pr]);
        }
    } else if (bid < 1568) {
        // ---- t2up(dec -> xcat, kstride=512, c_off=256) ----
        const int bb = bid - 784;
        const int p0 = (bb % 49) * 64;
        const int c0 = ((bb / 49) & 3) * 64;
        const int b  = bb / 196;
        const int pl = tid & 63, cr = tid >> 6;

        const int p = p0 + pl;
        const int h = p / 56;
        const int w = p - h * 56;
        int ih0; float fh;
        if (h & 1) { ih0 = h >> 1;       fh = 0.25f; }
        else       { ih0 = (h >> 1) - 1; fh = 0.75f; }
        int ih1 = min(ih0 + 1, 27); ih0 = max(ih0, 0);
        int iw0; float fw;
        if (w & 1) { iw0 = w >> 1;       fw = 0.25f; }
        else       { iw0 = (w >> 1) - 1; fw = 0.75f; }
        int iw1 = min(iw0 + 1, 27); iw0 = max(iw0, 0);
        const int o00 = ih0*28 + iw0, o01 = ih0*28 + iw1;
        const int o10 = ih1*28 + iw0, o11 = ih1*28 + iw1;
        const float w00 = (1.f-fh)*(1.f-fw), w01 = (1.f-fh)*fw;
        const float w10 = fh*(1.f-fw),       w11 = fh*fw;

        #pragma unroll
        for (int i = 0; i < 16; ++i) {
            const int c = c0 + i*4 + cr;
            const float* s = dec + (size_t)(b*256 + c) * 784;
            sm[(i*4+cr)*65 + pl] = w00*s[o00] + w01*s[o01] + w10*s[o10] + w11*s[o11];
        }
        __syncthreads();
        const int cl = tid & 63, pr = tid >> 6;
        #pragma unroll
        for (int i = 0; i < 16; ++i) {
            const int pp = p0 + i*4 + pr;
            xcat[((size_t)(b*HW + pp)) * 512 + 256 + c0 + cl] = __float2bfloat16(sm[cl*65 + i*4+pr]);
        }
    } else if (bid < 2080) {
        // ---- cvt c1w (256*512 = 131072 elements) ----
        const int j = (bid - 1568) * 256 + tid;
        c1wb[j] = __float2bfloat16(c1w[j]);
    } else if (bid < 2336) {
        // ---- cvt c2w (128*512 = 65536 elements) ----
        const int j = (bid - 2080) * 256 + tid;
        c2wb[j] = __float2bfloat16(c2w[j]);
    } else {
        // ---- w1bf2: w1 [128][256][49] -> wbf [oc][k=t*256+c] ----
        const int oc = bid - 2336;
        const float* src = w1 + (size_t)oc * 12544;
        #pragma unroll
        for (int i = 0; i < 49; ++i) {
            const int idx = i * 256 + tid;
            const int c  = idx / 49;
            const int tt = idx - c * 49;
            sm[tt * 257 + c] = src[idx];
        }
        __syncthreads();
        __hip_bfloat16* dst = wbf + (size_t)oc * 12544;
        #pragma unroll
        for (int i = 0; i < 49; ++i)
            dst[i * 256 + tid] = __float2bfloat16(sm[i * 257 + tid]);
    }
}

// ---------------- tiled NCHW fp32 -> NHWC bf16 transpose (validated; used for attT) ----------------
__global__ __launch_bounds__(256) void k_t2nhwc(const float* __restrict__ src,
        __hip_bfloat16* __restrict__ dst, int kstride, int c_off)
{
    __shared__ float t[64][65];
    const int tid = threadIdx.x;
    const int p0 = blockIdx.x * 64;
    const int c0 = blockIdx.y * 64;
    const int b  = blockIdx.z;
    const int pl = tid & 63, cr = tid >> 6;
    #pragma unroll
    for (int i = 0; i < 16; ++i) {
        const int c = c0 + i*4 + cr;
        t[i*4+cr][pl] = src[((size_t)(b*256 + c)) * HW + p0 + pl];
    }
    __syncthreads();
    const int cl = tid & 63, pr = tid >> 6;
    #pragma unroll
    for (int i = 0; i < 16; ++i) {
        const int p = p0 + i*4 + pr;
        dst[((size_t)(b*HW + p)) * kstride + c_off + c0 + cl] = __float2bfloat16(t[cl][i*4+pr]);
    }
}

// ---------------- fp32 8x8 FMA microtile (w2 gemm only) ----------------
__device__ __forceinline__ void tile_fma(const float (*As)[128], const float (*Bs)[128],
                                         float acc[8][8], int tx, int ty)
{
    #pragma unroll
    for (int kk = 0; kk < 16; ++kk) {
        const float4 a0 = *(const float4*)&As[kk][ty*8];
        const float4 a1 = *(const float4*)&As[kk][ty*8+4];
        const float4 b0 = *(const float4*)&Bs[kk][tx*8];
        const float4 b1 = *(const float4*)&Bs[kk][tx*8+4];
        const float av[8] = {a0.x,a0.y,a0.z,a0.w,a1.x,a1.y,a1.z,a1.w};
        const float bv[8] = {b0.x,b0.y,b0.z,b0.w,b1.x,b1.y,b1.z,b1.w};
        #pragma unroll
        for (int e = 0; e < 8; ++e)
            #pragma unroll
            for (int f = 0; f < 8; ++f)
                acc[e][f] = fmaf(av[e], bv[f], acc[e][f]);
    }
}

// ---------------- fp32 1x1 GEMM (w2: M=49, K=128) + per-block BN partial sums (validated) ----------------
__global__ __launch_bounds__(256, 2) void k_gemm1x1(
    const float* __restrict__ W, const float* __restrict__ bias,
    const float* __restrict__ X0, int M, int K, float* __restrict__ Y,
    float* __restrict__ ps1, float* __restrict__ ps2)
{
    __shared__ float As[16][128];
    __shared__ float Bs[16][128];
    __shared__ float as1[128], as2[128];
    const int tid = threadIdx.x;
    const int tx = tid & 15, ty = tid >> 4;
    const int n0 = blockIdx.y * 128;

    const int amA = tid >> 2;
    const int kqA = tid & 3;
    const bool av0 = amA < M;
    const bool av1 = (amA + 64) < M;
    const size_t aoff0 = (size_t)amA * K + kqA * 4;
    const size_t aoff1 = (size_t)(amA + 64) * K + kqA * 4;

    const int colB = tid & 127;
    const int kkb  = tid >> 7;
    const int nB = n0 + colB;
    const int bB = nB / HW;
    const int pB = nB - bB * HW;
    const size_t u0 = (size_t)bB * K * HW + pB;

    float acc[8][8] = {};

    for (int k0 = 0; k0 < K; k0 += 16) {
        float4 va = av0 ? *(const float4*)(W + aoff0 + k0) : make_float4(0.f,0.f,0.f,0.f);
        float4 vb = av1 ? *(const float4*)(W + aoff1 + k0) : make_float4(0.f,0.f,0.f,0.f);
        As[kqA*4+0][amA] = va.x; As[kqA*4+1][amA] = va.y;
        As[kqA*4+2][amA] = va.z; As[kqA*4+3][amA] = va.w;
        As[kqA*4+0][amA+64] = vb.x; As[kqA*4+1][amA+64] = vb.y;
        As[kqA*4+2][amA+64] = vb.z; As[kqA*4+3][amA+64] = vb.w;
        #pragma unroll
        for (int e = 0; e < 8; ++e) {
            const int kk = e*2 + kkb;
            Bs[kk][colB] = X0[u0 + (size_t)(k0 + kk) * HW];
        }
        __syncthreads();
        tile_fma(As, Bs, acc, tx, ty);
        __syncthreads();
    }

    float s1v[8] = {}, s2v[8] = {};
    const int nE = n0 + tx*8;
    const int bE0 = nE / HW;
    const int pE0 = nE - bE0 * HW;
    #pragma unroll
    for (int e = 0; e < 8; ++e) {
        const int m = ty*8 + e;
        if (m < M) {
            const float bsv = bias[m];
            int b = bE0, p = pE0;
            #pragma unroll
            for (int f = 0; f < 8; ++f) {
                const float v = acc[e][f] + bsv;
                Y[((size_t)b * M + m) * HW + p] = v;
                s1v[e] += v;
                s2v[e] += v * v;
                if (++p == HW) { p = 0; ++b; }
            }
        }
    }
    #pragma unroll
    for (int e = 0; e < 8; ++e) {
        #pragma unroll
        for (int msk = 1; msk <= 8; msk <<= 1) {
            s1v[e] += __shfl_xor(s1v[e], msk);
            s2v[e] += __shfl_xor(s2v[e], msk);
        }
    }
    if (tx == 0) {
        #pragma unroll
        for (int e = 0; e < 8; ++e) {
            const int m = ty*8 + e;
            if (m < 128) { as1[m] = s1v[e]; as2[m] = s2v[e]; }
        }
    }
    __syncthreads();
    if (tid < M) {
        ps1[blockIdx.y * M + tid] = as1[tid];
        ps2[blockIdx.y * M + tid] = as2[tid];
    }
}

// ---------------- c1 MFMA GEMM: epilogue writes xpad (fp32) + xpadT (bf16) — validated ----------------
__global__ __launch_bounds__(256, 2) void k_gemmc1(
    const __hip_bfloat16* __restrict__ A, const __hip_bfloat16* __restrict__ B0,
    const float* __restrict__ bias, float* __restrict__ Xpad,
    __hip_bfloat16* __restrict__ XpadT)
{
    __shared__ __hip_bfloat16 As[8192];
    __shared__ __hip_bfloat16 Bs[8192];
    const int tid  = threadIdx.x;
    const int w    = tid >> 6;
    const int lane = tid & 63;
    const int n0   = blockIdx.x * 128;
    const int m0   = blockIdx.y * 128;

    unsigned aoffs[4], boffs[4];
    void *adst[4], *bdst[4];
    #pragma unroll
    for (int j = 0; j < 4; ++j) {
        const int slot = (w*4 + j)*64 + lane;
        const int row  = slot >> 3;
        const int q    = slot & 7;
        const int lc   = q ^ (row & 7);
        aoffs[j] = (unsigned)(m0 + row) * 512u + (unsigned)lc * 8u;
        adst[j]  = (void*)&As[(w*4 + j) * 512];
        boffs[j] = (unsigned)(n0 + row) * 512u + (unsigned)lc * 8u;
        bdst[j]  = (void*)&Bs[(w*4 + j) * 512];
    }

    const int l15 = lane & 15, lg = lane >> 4;
    const int m_w0 = (w & 1) * 64;
    const int n_w0 = (w >> 1) * 64;
    int rowA[4], rowB[4], chunkoff[2];
    #pragma unroll
    for (int i = 0; i < 4; ++i) {
        rowA[i] = (m_w0 + i*16 + l15) * 128;
        rowB[i] = (n_w0 + i*16 + l15) * 128;
    }
    #pragma unroll
    for (int ks = 0; ks < 2; ++ks)
        chunkoff[ks] = ((4*ks + lg) ^ (lane & 7)) * 16;

    f32x4 acc[4][4];
    #pragma unroll
    for (int i = 0; i < 4; ++i)
        #pragma unroll
        for (int j = 0; j < 4; ++j)
            acc[i][j] = (f32x4){0.f, 0.f, 0.f, 0.f};

    for (int k0 = 0; k0 < 512; k0 += 64) {
        #pragma unroll
        for (int j = 0; j < 4; ++j) gll16(A + aoffs[j] + k0, adst[j]);
        #pragma unroll
        for (int j = 0; j < 4; ++j) gll16(B0 + boffs[j] + k0, bdst[j]);
        __syncthreads();
        #pragma unroll
        for (int ks = 0; ks < 2; ++ks) {
            const int co = chunkoff[ks];
            bf16x8 av[4], bv[4];
            #pragma unroll
            for (int i = 0; i < 4; ++i)
                av[i] = *(const bf16x8*)((const char*)As + rowA[i] + co);
            #pragma unroll
            for (int i = 0; i < 4; ++i)
                bv[i] = *(const bf16x8*)((const char*)Bs + rowB[i] + co);
            #pragma unroll
            for (int i = 0; i < 4; ++i)
                #pragma unroll
                for (int j = 0; j < 4; ++j)
                    acc[i][j] = __builtin_amdgcn_mfma_f32_16x16x32_bf16(av[i], bv[j], acc[i][j], 0, 0, 0);
        }
        __syncthreads();
    }

    #pragma unroll
    for (int j = 0; j < 4; ++j) {
        const int n = n0 + n_w0 + j*16 + l15;
        const int b = n / HW;
        const int p = n - b * HW;
        const int h = p / 56;
        const int ww = p - h * 56;
        #pragma unroll
        for (int i = 0; i < 4; ++i) {
            const int m = m0 + m_w0 + i*16 + lg*4;
            const float4 bs4 = *(const float4*)&bias[m];
            float v0 = fmaxf(acc[i][j][0] + bs4.x, 0.f);
            float v1 = fmaxf(acc[i][j][1] + bs4.y, 0.f);
            float v2 = fmaxf(acc[i][j][2] + bs4.z, 0.f);
            float v3 = fmaxf(acc[i][j][3] + bs4.w, 0.f);
            float* dp = Xpad + ((size_t)(b*256 + m)) * PADA + (h + 6) * 68 + (ww + 6);
            dp[0]      = v0;
            dp[PADA]   = v1;
            dp[2*PADA] = v2;
            dp[3*PADA] = v3;
            ushort4 pk;
            pk.x = __bfloat16_as_ushort(__float2bfloat16(v0));
            pk.y = __bfloat16_as_ushort(__float2bfloat16(v1));
            pk.z = __bfloat16_as_ushort(__float2bfloat16(v2));
            pk.w = __bfloat16_as_ushort(__float2bfloat16(v3));
            *(ushort4*)(XpadT + ((size_t)((b*68 + h + 6)*68 + ww + 6)) * 256 + m) = pk;
        }
    }
}

// ---------------- c2 MFMA GEMM + per-block BN partial sums (validated) ----------------
__global__ __launch_bounds__(256, 2) void k_gemmc2(
    const __hip_bfloat16* __restrict__ A, const __hip_bfloat16* __restrict__ XT,
    const __hip_bfloat16* __restrict__ AT, const float* __restrict__ bias,
    float* __restrict__ Y, float* __restrict__ ps1, float* __restrict__ ps2)
{
    __shared__ __hip_bfloat16 As[8192];
    __shared__ __hip_bfloat16 Bs[8192];
    __shared__ float bs1[2][128], bs2[2][128];
    const int tid  = threadIdx.x;
    const int w    = tid >> 6;
    const int lane = tid & 63;
    const int n0   = blockIdx.x * 128;

    unsigned aoffs[4], boffs0[4], boffs1[4];
    void *adst[4], *bdst[4];
    #pragma unroll
    for (int j = 0; j < 4; ++j) {
        const int slot = (w*4 + j)*64 + lane;
        const int row  = slot >> 3;
        const int q    = slot & 7;
        const int lc   = q ^ (row & 7);
        aoffs[j] = (unsigned)row * 512u + (unsigned)lc * 8u;
        adst[j]  = (void*)&As[(w*4 + j) * 512];
        const int n = n0 + row;
        const int b = n / HW;
        const int p = n - b * HW;
        const int h = p / 56;
        const int ww = p - h * 56;
        boffs0[j] = ((unsigned)(b*68 + h + 6)*68 + (unsigned)(ww + 6))*256u + (unsigned)lc * 8u;
        boffs1[j] = (unsigned)n * 256u + (unsigned)lc * 8u;
        bdst[j]  = (void*)&Bs[(w*4 + j) * 512];
    }

    const int l15 = lane & 15, lg = lane >> 4;
    const int m_w0 = (w & 1) * 64;
    const int n_w0 = (w >> 1) * 64;
    int rowA[4], rowB[4], chunkoff[2];
    #pragma unroll
    for (int i = 0; i < 4; ++i) {
        rowA[i] = (m_w0 + i*16 + l15) * 128;
        rowB[i] = (n_w0 + i*16 + l15) * 128;
    }
    #pragma unroll
    for (int ks = 0; ks < 2; ++ks)
        chunkoff[ks] = ((4*ks + lg) ^ (lane & 7)) * 16;

    f32x4 acc[4][4];
    #pragma unroll
    for (int i = 0; i < 4; ++i)
        #pragma unroll
        for (int j = 0; j < 4; ++j)
            acc[i][j] = (f32x4){0.f, 0.f, 0.f, 0.f};

    for (int k0 = 0; k0 < 512; k0 += 64) {
        #pragma unroll
        for (int j = 0; j < 4; ++j) gll16(A + aoffs[j] + k0, adst[j]);
        if (k0 < 256) {
            #pragma unroll
            for (int j = 0; j < 4; ++j) gll16(XT + boffs0[j] + k0, bdst[j]);
        } else {
            #pragma unroll
            for (int j = 0; j < 4; ++j) gll16(AT + boffs1[j] + (k0 - 256), bdst[j]);
        }
        __syncthreads();
        #pragma unroll
        for (int ks = 0; ks < 2; ++ks) {
            const int co = chunkoff[ks];
            bf16x8 av[4], bv[4];
            #pragma unroll
            for (int i = 0; i < 4; ++i)
                av[i] = *(const bf16x8*)((const char*)As + rowA[i] + co);
            #pragma unroll
            for (int i = 0; i < 4; ++i)
                bv[i] = *(const bf16x8*)((const char*)Bs + rowB[i] + co);
            #pragma unroll
            for (int i = 0; i < 4; ++i)
                #pragma unroll
                for (int j = 0; j < 4; ++j)
                    acc[i][j] = __builtin_amdgcn_mfma_f32_16x16x32_bf16(av[i], bv[j], acc[i][j], 0, 0, 0);
        }
        __syncthreads();
    }

    float s1loc[16] = {}, s2loc[16] = {};
    #pragma unroll
    for (int j = 0; j < 4; ++j) {
        const int n = n0 + n_w0 + j*16 + l15;
        const int b = n / HW;
        const int p = n - b * HW;
        #pragma unroll
        for (int i = 0; i < 4; ++i) {
            const int m = m_w0 + i*16 + lg*4;
            const float4 bs4 = *(const float4*)&bias[m];
            float v0 = acc[i][j][0] + bs4.x;
            float v1 = acc[i][j][1] + bs4.y;
            float v2 = acc[i][j][2] + bs4.z;
            float v3 = acc[i][j][3] + bs4.w;
            float* dst = Y + ((size_t)(b*128 + m) * HW + p);
            dst[0]    = v0;
            dst[HW]   = v1;
            dst[2*HW] = v2;
            dst[3*HW] = v3;
            s1loc[i*4+0] += v0; s2loc[i*4+0] += v0*v0;
            s1loc[i*4+1] += v1; s2loc[i*4+1] += v1*v1;
            s1loc[i*4+2] += v2; s2loc[i*4+2] += v2*v2;
            s1loc[i*4+3] += v3; s2loc[i*4+3] += v3*v3;
        }
    }
    #pragma unroll
    for (int k = 0; k < 16; ++k) {
        #pragma unroll
        for (int msk = 1; msk <= 8; msk <<= 1) {
            s1loc[k] += __shfl_xor(s1loc[k], msk);
            s2loc[k] += __shfl_xor(s2loc[k], msk);
        }
    }
    const int qn = w >> 1;
    if (l15 == 0) {
        #pragma unroll
        for (int i = 0; i < 4; ++i)
            #pragma unroll
            for (int r = 0; r < 4; ++r) {
                const int m = m_w0 + i*16 + lg*4 + r;
                bs1[qn][m] = s1loc[i*4+r];
                bs2[qn][m] = s2loc[i*4+r];
            }
    }
    __syncthreads();
    if (tid < 128) {
        ps1[blockIdx.x * 128 + tid] = bs1[0][tid] + bs1[1][tid];
        ps2[blockIdx.x * 128 + tid] = bs2[0][tid] + bs2[1][tid];
    }
}

// ---------------- dilated 7x7 conv: bf16 MFMA implicit GEMM, K-split x5, bf16 partials (validated) ----------------
__global__ __launch_bounds__(256, 2) void k_convmfma(
    const __hip_bfloat16* __restrict__ Wbf, const __hip_bfloat16* __restrict__ XT,
    __hip_bfloat16* __restrict__ o0, __hip_bfloat16* __restrict__ o1,
    __hip_bfloat16* __restrict__ o2, __hip_bfloat16* __restrict__ o3,
    __hip_bfloat16* __restrict__ o4)
{
    __shared__ __hip_bfloat16 As[8192];
    __shared__ __hip_bfloat16 Bs[8192];
    const int tid  = threadIdx.x;
    const int w    = tid >> 6;
    const int lane = tid & 63;
    const int n0   = blockIdx.x * 128;
    const int s    = blockIdx.y;
    const int t_start = (s < 4) ? s * 40 : 158;
    const int cnt     = (s < 3) ? 40 : 38;
    __hip_bfloat16* __restrict__ out = (s==0)?o0:(s==1)?o1:(s==2)?o2:(s==3)?o3:o4;

    unsigned aoffs[4], boffs[4];
    void *adst[4], *bdst[4];
    #pragma unroll
    for (int j = 0; j < 4; ++j) {
        const int slot = (w*4 + j)*64 + lane;
        const int row  = slot >> 3;
        const int q    = slot & 7;
        const int lc   = q ^ (row & 7);
        aoffs[j] = (unsigned)row * 12544u + (unsigned)lc * 8u;
        adst[j]  = (void*)&As[(w*4 + j) * 512];
        const int n = n0 + row;
        const int b = n / HW;
        const int p = n - b * HW;
        const int h = p / 56;
        const int ww = p - h * 56;
        boffs[j] = ((unsigned)(b*68 + h)*68 + (unsigned)ww)*256u + (unsigned)lc * 8u;
        bdst[j]  = (void*)&Bs[(w*4 + j) * 512];
    }

    const int l15 = lane & 15, lg = lane >> 4;
    const int m_w0 = (w & 1) * 64;
    const int n_w0 = (w >> 1) * 64;
    int rowA[4], rowB[4], chunkoff[2];
    #pragma unroll
    for (int i = 0; i < 4; ++i) {
        rowA[i] = (m_w0 + i*16 + l15) * 128;
        rowB[i] = (n_w0 + i*16 + l15) * 128;
    }
    #pragma unroll
    for (int ks = 0; ks < 2; ++ks)
        chunkoff[ks] = ((4*ks + lg) ^ (lane & 7)) * 16;

    f32x4 acc[4][4];
    #pragma unroll
    for (int i = 0; i < 4; ++i)
        #pragma unroll
        for (int j = 0; j < 4; ++j)
            acc[i][j] = (f32x4){0.f, 0.f, 0.f, 0.f};

    for (int it = 0; it < cnt; ++it) {
        const int kt = t_start + it;
        const int k0 = kt << 6;
        const int t  = k0 >> 8;
        const int c0 = k0 & 255;
        const int ti = (t * 37) >> 8;
        const int tj = t - ti * 7;
        const unsigned aof = (unsigned)k0;
        const unsigned bof = (unsigned)(ti*68 + tj) * 512u + (unsigned)c0;

        #pragma unroll
        for (int j = 0; j < 4; ++j) gll16(Wbf + aoffs[j] + aof, adst[j]);
        #pragma unroll
        for (int j = 0; j < 4; ++j) gll16(XT + boffs[j] + bof, bdst[j]);

        __syncthreads();

        #pragma unroll
        for (int ks = 0; ks < 2; ++ks) {
            const int co = chunkoff[ks];
            bf16x8 av[4], bv[4];
            #pragma unroll
            for (int i = 0; i < 4; ++i)
                av[i] = *(const bf16x8*)((const char*)As + rowA[i] + co);
            #pragma unroll
            for (int i = 0; i < 4; ++i)
                bv[i] = *(const bf16x8*)((const char*)Bs + rowB[i] + co);
            #pragma unroll
            for (int i = 0; i < 4; ++i)
                #pragma unroll
                for (int j = 0; j < 4; ++j)
                    acc[i][j] = __builtin_amdgcn_mfma_f32_16x16x32_bf16(av[i], bv[j], acc[i][j], 0, 0, 0);
        }
        __syncthreads();
    }

    #pragma unroll
    for (int j = 0; j < 4; ++j) {
        const int n = n0 + n_w0 + j*16 + l15;
        const int b = n / HW;
        const int p = n - b * HW;
        #pragma unroll
        for (int i = 0; i < 4; ++i) {
            const int m = m_w0 + i*16 + lg*4;
            __hip_bfloat16* dst = out + ((size_t)(b*128 + m) * HW + p);
            dst[0]      = __float2bfloat16(acc[i][j][0]);
            dst[HW]     = __float2bfloat16(acc[i][j][1]);
            dst[2*HW]   = __float2bfloat16(acc[i][j][2]);
            dst[3*HW]   = __float2bfloat16(acc[i][j][3]);
        }
    }
}

// ---------------- combine 5 bf16 partials + bias + relu -> k1 (validated) ----------------
__global__ __launch_bounds__(256) void k_combine5(
    const short8v* __restrict__ p0, const short8v* __restrict__ p1,
    const short8v* __restrict__ p2, const short8v* __restrict__ p3,
    const short8v* __restrict__ p4,
    const float* __restrict__ bias, float* __restrict__ Y)
{
    const int j = blockIdx.x * 256 + threadIdx.x;
    short8v a = p0[j], b = p1[j], c = p2[j], d = p3[j], e5 = p4[j];
    const int oc = ((j * 8) / HW) & 127;
    const float bv = bias[oc];
    float o[8];
    #pragma unroll
    for (int e = 0; e < 8; ++e) {
        float v = bf2f(a[e]) + bf2f(b[e]) + bf2f(c[e]) + bf2f(d[e]) + bf2f(e5[e]) + bv;
        o[e] = fmaxf(v, 0.f);
    }
    float4* dst = (float4*)(Y + (size_t)j * 8);
    dst[0] = *(float4*)&o[0];
    dst[1] = *(float4*)&o[4];
}

// ---------------- fused BN(from partials) + relu + softmax over 49 channels (validated) ----------------
__global__ __launch_bounds__(256) void k_bnsoftmax(float* __restrict__ X,
        const float* __restrict__ ps1, const float* __restrict__ ps2,
        const float* __restrict__ gam,  const float* __restrict__ bet)
{
    __shared__ float msh[NT], rsh[NT];
    const int tid = threadIdx.x;
    if (tid < NT) {
        float s1 = 0.f, s2 = 0.f;
        for (int b = 0; b < NBLK; ++b) {
            s1 += ps1[b * NT + tid];
            s2 += ps2[b * NT + tid];
        }
        const float mean = s1 * (1.f / 12544.f);
        const float var  = s2 * (1.f / 12544.f) - mean * mean;
        msh[tid] = mean;
        rsh[tid] = rsqrtf(var + 1e-5f);
    }
    __syncthreads();

    const int gidx = blockIdx.x * 256 + tid;
    const int b = gidx / HW;
    const int p = gidx - b * HW;
    float* base = X + (size_t)b * NT * HW + p;
    float vals[NT];
    float m = -1e30f;
    #pragma unroll
    for (int t = 0; t < NT; ++t) {
        float v = base[(size_t)t * HW];
        v = (v - msh[t]) * rsh[t] * gam[t] + bet[t];
        v = fmaxf(v, 0.f);
        vals[t] = v;
        m = fmaxf(m, v);
    }
    float s = 0.f;
    #pragma unroll
    for (int t = 0; t < NT; ++t) { float e = __expf(vals[t] - m); vals[t] = e; s += e; }
    const float inv = 1.f / s;
    #pragma unroll
    for (int t = 0; t < NT; ++t) base[(size_t)t * HW] = vals[t] * inv;
}

// ---------------- attention apply v2: register-blocked, LDS-free (validated) ----------------
__global__ __launch_bounds__(256) void k_attapply2(const float* __restrict__ Xpad,
        const float* __restrict__ att, float* __restrict__ Y)
{
    const int tid  = threadIdx.x;
    const int wv   = tid >> 6;
    const int lane = tid & 63;
    const int wq   = lane & 15;
    const int rs   = lane >> 4;
    const int rq   = blockIdx.x;
    const int cg   = blockIdx.y;
    const int b    = blockIdx.z;
    const int c    = cg * 4 + wv;
    const int h    = rq * 4 + rs;
    const int w0   = min(wq, 13) * 4;

    const float* xbase = Xpad + ((size_t)(b*256 + c) * 68 + h) * 68 + w0;
    const float* abase = att + (size_t)b * NT * HW + h * 56 + w0;
    float4 acc = {0.f, 0.f, 0.f, 0.f};
    #pragma unroll
    for (int ti = 0; ti < 7; ++ti) {
        const float* xr = xbase + ti * 136;
        float xf[16];
        *(float4*)&xf[0]  = *(const float4*)(xr);
        *(float4*)&xf[4]  = *(const float4*)(xr + 4);
        *(float4*)&xf[8]  = *(const float4*)(xr + 8);
        *(float4*)&xf[12] = *(const float4*)(xr + 12);
        #pragma unroll
        for (int tj = 0; tj < 7; ++tj) {
            const float4 a4 = *(const float4*)(abase + (size_t)(ti*7 + tj) * HW);
            acc.x = fmaf(xf[2*tj + 0], a4.x, acc.x);
            acc.y = fmaf(xf[2*tj + 1], a4.y, acc.y);
            acc.z = fmaf(xf[2*tj + 2], a4.z, acc.z);
            acc.w = fmaf(xf[2*tj + 3], a4.w, acc.w);
        }
    }
    if (wq < 14)
        *(float4*)(Y + (size_t)(b*256 + c) * HW + h * 56 + w0) = acc;
}

// ---------------- fused BN(from partials) + relu -> dec_out, + sigmoid(c3) -> side (validated) ----------------
__global__ __launch_bounds__(256) void k_bnside(const float* __restrict__ X,
        const float* __restrict__ ps1, const float* __restrict__ ps2,
        const float* __restrict__ gam,  const float* __restrict__ bet,
        const float* __restrict__ w3,   const float* __restrict__ b3,
        float* __restrict__ dec_out,    float* __restrict__ side)
{
    __shared__ float ms[128], rs[128], gs[128], bs[128], w3s[128];
    const int tid = threadIdx.x;
    if (tid < 128) {
        float s1 = 0.f, s2 = 0.f;
        for (int b = 0; b < NBLK; ++b) {
            s1 += ps1[b * 128 + tid];
            s2 += ps2[b * 128 + tid];
        }
        const float mean = s1 * (1.f / 12544.f);
        const float var  = s2 * (1.f / 12544.f) - mean * mean;
        ms[tid] = mean;
        rs[tid] = rsqrtf(var + 1e-5f);
        gs[tid] = gam[tid];  bs[tid] = bet[tid];
        w3s[tid] = w3[tid];
    }
    __syncthreads();
    const int gidx = blockIdx.x * 256 + tid;
    const int b = gidx / HW;
    const int p = gidx - b * HW;
    const size_t u = (size_t)b * 128 * HW + p;
    float acc = b3[0];
    #pragma unroll 8
    for (int c = 0; c < 128; ++c) {
        const size_t a = u + (size_t)c * HW;
        float v = (X[a] - ms[c]) * rs[c] * gs[c] + bs[c];
        v = fmaxf(v, 0.f);
        dec_out[a] = v;
        acc = fmaf(v, w3s[c], acc);
    }
    side[gidx] = 1.f / (1.f + __expf(-acc));
}

// ---------------- launcher ----------------
extern "C" void kernel_launch(void* const* d_in, const int* in_sizes, int n_in,
                              void* d_out, int out_size, void* d_ws, size_t ws_size,
                              hipStream_t stream)
{
    const float* en  = (const float*)d_in[0];
    const float* dec = (const float*)d_in[1];
    const float* w1  = (const float*)d_in[2];
    const float* b1  = (const float*)d_in[3];
    const float* w2  = (const float*)d_in[4];
    const float* b2  = (const float*)d_in[5];
    const float* bng = (const float*)d_in[6];
    const float* bnb = (const float*)d_in[7];
    const float* c1w = (const float*)d_in[8];
    const float* c1b = (const float*)d_in[9];
    const float* c2w = (const float*)d_in[10];
    const float* c2b = (const float*)d_in[11];
    const float* bfg = (const float*)d_in[12];
    const float* bfb = (const float*)d_in[13];
    const float* c3w = (const float*)d_in[14];
    const float* c3b = (const float*)d_in[15];

    float* ws = (float*)d_ws;                   // 20,750,848 floats (proven extent)
    __hip_bfloat16* part0 = (__hip_bfloat16*)(ws + R0);
    __hip_bfloat16* part1 = (__hip_bfloat16*)(ws + R0 +  802816u);
    __hip_bfloat16* part2 = (__hip_bfloat16*)(ws + R0 + 1605632u);
    __hip_bfloat16* part3 = (__hip_bfloat16*)(ws + R0 + 2408448u);
    float* fmap_att = ws + R0;                  // region base after combine (parts dead)
    float* attb     = ws + R1;
    float* xpad     = ws + R2;
    float* k1       = ws + R3;
    __hip_bfloat16* xcat = (__hip_bfloat16*)(ws + R4);
    __hip_bfloat16* part4 = (__hip_bfloat16*)(ws + R4);
    __hip_bfloat16* attT  = (__hip_bfloat16*)(ws + R4);
    float* x2       = ws + R4 + 1605632u;
    __hip_bfloat16* c1wb = (__hip_bfloat16*)(ws + R5);            // 131072 bf16
    __hip_bfloat16* c2wb = (__hip_bfloat16*)(ws + R5 + 65536u);   // 65536 bf16 (own slot now)
    float* c2s1    = ws + R5 + 131072u;                   // 98*128
    float* c2s2    = ws + R5 + 143616u;                   // 98*128
    float* atts1   = ws + R5 + 156160u;                   // 98*49
    float* atts2   = ws + R5 + 160962u;                   // 98*49
    __hip_bfloat16* xpadT = (__hip_bfloat16*)(ws + R7);
    __hip_bfloat16* wbf   = (__hip_bfloat16*)(ws + R8);

    float* dec_out = (float*)d_out;
    float* side    = (float*)d_out + 1605632u;

    // 0. zero padded buffers (borders must be 0 every call; interiors overwritten by gemmc1)
    hipMemsetAsync(xpad,  0, (size_t)4 * 256 * PADA * sizeof(float), stream);
    hipMemsetAsync(xpadT, 0, (size_t)4 * PADA * 256 * sizeof(__hip_bfloat16), stream);
    // 1. merged prep: en/dec -> xcat, c1w/c2w -> bf16, w1 -> wbf (single concurrent dispatch)
    k_prep<<<dim3(2464), dim3(256), 0, stream>>>(en, dec, c1w, c2w, w1, xcat, c1wb, c2wb, wbf);
    // 2. relu(c1 x xcat) via MFMA -> xpad (fp32) + xpadT (bf16)
    k_gemmc1<<<dim3(98, 2), dim3(256), 0, stream>>>(c1wb, xcat, c1b, xpad, xpadT);
    // 3. big dilated conv (K-split x5, bf16 partials)
    k_convmfma<<<dim3(98, 5), dim3(256), 0, stream>>>(wbf, xpadT, part0, part1, part2, part3, part4);
    // 4. combine -> k1
    k_combine5<<<dim3(784), dim3(256), 0, stream>>>((const short8v*)part0, (const short8v*)part1,
                                                    (const short8v*)part2, (const short8v*)part3,
                                                    (const short8v*)part4, b1, k1);
    // 5. attention logits = w2 * k1 + b2, with fused BN partial sums
    k_gemm1x1<<<dim3(1, 98), dim3(256), 0, stream>>>(w2, b2, k1, 49, 128, attb, atts1, atts2);
    // 6. BN(from partials) + relu + softmax(49) in place
    k_bnsoftmax<<<dim3(49), dim3(256), 0, stream>>>(attb, atts1, atts2, bng, bnb);
    // 7. local attention gather -> fmap_att
    k_attapply2<<<dim3(14, 64, 4), dim3(256), 0, stream>>>(xpad, attb, fmap_att);
    // 8. fmap_att -> attT NHWC bf16
    k_t2nhwc<<<dim3(49, 4, 4), dim3(256), 0, stream>>>(fmap_att, attT, 256, 0);
    // 9. x2 = c2 x [xpadT(center) ; attT] via MFMA, with fused BN partial sums
    k_gemmc2<<<dim3(98), dim3(256), 0, stream>>>(c2wb, xpadT, attT, c2b, x2, c2s1, c2s2);
    // 10. fused BN(from partials)/relu -> dec_out + sigmoid side
    k_bnside<<<dim3(49), dim3(256), 0, stream>>>(x2, c2s1, c2s2, bfg, bfb,
                                                 c3w, c3b, dec_out, side);
}

// Round 15
// 181.697 us; speedup vs baseline: 1.2809x; 1.0148x over previous
//
#include <hip/hip_runtime.h>
#include <hip/hip_bf16.h>
#include <math.h>

// ---------------- problem constants ----------------
#define HW    3136        // 56*56
#define PADA  4624        // 68*68 padded plane (fp32 NCHW)
#define NT    49
#define NB_ATT 98         // w2-gemm n-blocks (12544/128)
#define NB_C2  196        // c2-gemm n-blocks (12544/64)

// ---------------- workspace regions (float offsets) — proven extent ----------------
#define R0 0u
#define R1 3211264u
#define R2 6422528u
#define R3 11157504u
#define R4 12763136u
#define R5 15974400u
#define R7 17580544u
#define R8 19948032u

typedef __attribute__((ext_vector_type(8))) short bf16x8;
typedef __attribute__((ext_vector_type(8))) short short8v;
typedef __attribute__((ext_vector_type(4))) float f32x4;

__device__ __forceinline__ void gll16(const void* g, void* l) {
    __builtin_amdgcn_global_load_lds((const __attribute__((address_space(1))) void*)g,
                                     (__attribute__((address_space(3))) void*)l, 16, 0, 0);
}

__device__ __forceinline__ float bf2f(short u) {
    return __uint_as_float(((unsigned)(unsigned short)u) << 16);
}

// ---------------- merged prep (validated R14) ----------------
__global__ __launch_bounds__(256) void k_prep(
    const float* __restrict__ en, const float* __restrict__ dec,
    const float* __restrict__ c1w, const float* __restrict__ c2w,
    const float* __restrict__ w1,
    __hip_bfloat16* __restrict__ xcat, __hip_bfloat16* __restrict__ c1wb,
    __hip_bfloat16* __restrict__ c2wb, __hip_bfloat16* __restrict__ wbf)
{
    __shared__ float sm[12593];
    const int bid = blockIdx.x;
    const int tid = threadIdx.x;

    if (bid < 784) {
        const int p0 = (bid % 49) * 64;
        const int c0 = ((bid / 49) & 3) * 64;
        const int b  = bid / 196;
        const int pl = tid & 63, cr = tid >> 6;
        #pragma unroll
        for (int i = 0; i < 16; ++i) {
            const int c = c0 + i*4 + cr;
            sm[(i*4+cr)*65 + pl] = en[((size_t)(b*256 + c)) * HW + p0 + pl];
        }
        __syncthreads();
        const int cl = tid & 63, pr = tid >> 6;
        #pragma unroll
        for (int i = 0; i < 16; ++i) {
            const int p = p0 + i*4 + pr;
            xcat[((size_t)(b*HW + p)) * 512 + c0 + cl] = __float2bfloat16(sm[cl*65 + i*4+pr]);
        }
    } else if (bid < 1568) {
        const int bb = bid - 784;
        const int p0 = (bb % 49) * 64;
        const int c0 = ((bb / 49) & 3) * 64;
        const int b  = bb / 196;
        const int pl = tid & 63, cr = tid >> 6;

        const int p = p0 + pl;
        const int h = p / 56;
        const int w = p - h * 56;
        int ih0; float fh;
        if (h & 1) { ih0 = h >> 1;       fh = 0.25f; }
        else       { ih0 = (h >> 1) - 1; fh = 0.75f; }
        int ih1 = min(ih0 + 1, 27); ih0 = max(ih0, 0);
        int iw0; float fw;
        if (w & 1) { iw0 = w >> 1;       fw = 0.25f; }
        else       { iw0 = (w >> 1) - 1; fw = 0.75f; }
        int iw1 = min(iw0 + 1, 27); iw0 = max(iw0, 0);
        const int o00 = ih0*28 + iw0, o01 = ih0*28 + iw1;
        const int o10 = ih1*28 + iw0, o11 = ih1*28 + iw1;
        const float w00 = (1.f-fh)*(1.f-fw), w01 = (1.f-fh)*fw;
        const float w10 = fh*(1.f-fw),       w11 = fh*fw;

        #pragma unroll
        for (int i = 0; i < 16; ++i) {
            const int c = c0 + i*4 + cr;
            const float* s = dec + (size_t)(b*256 + c) * 784;
            sm[(i*4+cr)*65 + pl] = w00*s[o00] + w01*s[o01] + w10*s[o10] + w11*s[o11];
        }
        __syncthreads();
        const int cl = tid & 63, pr = tid >> 6;
        #pragma unroll
        for (int i = 0; i < 16; ++i) {
            const int pp = p0 + i*4 + pr;
            xcat[((size_t)(b*HW + pp)) * 512 + 256 + c0 + cl] = __float2bfloat16(sm[cl*65 + i*4+pr]);
        }
    } else if (bid < 2080) {
        const int j = (bid - 1568) * 256 + tid;
        c1wb[j] = __float2bfloat16(c1w[j]);
    } else if (bid < 2336) {
        const int j = (bid - 2080) * 256 + tid;
        c2wb[j] = __float2bfloat16(c2w[j]);
    } else {
        const int oc = bid - 2336;
        const float* src = w1 + (size_t)oc * 12544;
        #pragma unroll
        for (int i = 0; i < 49; ++i) {
            const int idx = i * 256 + tid;
            const int c  = idx / 49;
            const int tt = idx - c * 49;
            sm[tt * 257 + c] = src[idx];
        }
        __syncthreads();
        __hip_bfloat16* dst = wbf + (size_t)oc * 12544;
        #pragma unroll
        for (int i = 0; i < 49; ++i)
            dst[i * 256 + tid] = __float2bfloat16(sm[i * 257 + tid]);
    }
}

// ---------------- tiled NCHW fp32 -> NHWC bf16 transpose (validated; attT) ----------------
__global__ __launch_bounds__(256) void k_t2nhwc(const float* __restrict__ src,
        __hip_bfloat16* __restrict__ dst, int kstride, int c_off)
{
    __shared__ float t[64][65];
    const int tid = threadIdx.x;
    const int p0 = blockIdx.x * 64;
    const int c0 = blockIdx.y * 64;
    const int b  = blockIdx.z;
    const int pl = tid & 63, cr = tid >> 6;
    #pragma unroll
    for (int i = 0; i < 16; ++i) {
        const int c = c0 + i*4 + cr;
        t[i*4+cr][pl] = src[((size_t)(b*256 + c)) * HW + p0 + pl];
    }
    __syncthreads();
    const int cl = tid & 63, pr = tid >> 6;
    #pragma unroll
    for (int i = 0; i < 16; ++i) {
        const int p = p0 + i*4 + pr;
        dst[((size_t)(b*HW + p)) * kstride + c_off + c0 + cl] = __float2bfloat16(t[cl][i*4+pr]);
    }
}

// ---------------- fp32 8x8 FMA microtile (w2 gemm only) ----------------
__device__ __forceinline__ void tile_fma(const float (*As)[128], const float (*Bs)[128],
                                         float acc[8][8], int tx, int ty)
{
    #pragma unroll
    for (int kk = 0; kk < 16; ++kk) {
        const float4 a0 = *(const float4*)&As[kk][ty*8];
        const float4 a1 = *(const float4*)&As[kk][ty*8+4];
        const float4 b0 = *(const float4*)&Bs[kk][tx*8];
        const float4 b1 = *(const float4*)&Bs[kk][tx*8+4];
        const float av[8] = {a0.x,a0.y,a0.z,a0.w,a1.x,a1.y,a1.z,a1.w};
        const float bv[8] = {b0.x,b0.y,b0.z,b0.w,b1.x,b1.y,b1.z,b1.w};
        #pragma unroll
        for (int e = 0; e < 8; ++e)
            #pragma unroll
            for (int f = 0; f < 8; ++f)
                acc[e][f] = fmaf(av[e], bv[f], acc[e][f]);
    }
}

// ---------------- fp32 1x1 GEMM (w2: M=49, K=128) + BN partial sums (validated) ----------------
__global__ __launch_bounds__(256, 2) void k_gemm1x1(
    const float* __restrict__ W, const float* __restrict__ bias,
    const float* __restrict__ X0, int M, int K, float* __restrict__ Y,
    float* __restrict__ ps1, float* __restrict__ ps2)
{
    __shared__ float As[16][128];
    __shared__ float Bs[16][128];
    __shared__ float as1[128], as2[128];
    const int tid = threadIdx.x;
    const int tx = tid & 15, ty = tid >> 4;
    const int n0 = blockIdx.y * 128;

    const int amA = tid >> 2;
    const int kqA = tid & 3;
    const bool av0 = amA < M;
    const bool av1 = (amA + 64) < M;
    const size_t aoff0 = (size_t)amA * K + kqA * 4;
    const size_t aoff1 = (size_t)(amA + 64) * K + kqA * 4;

    const int colB = tid & 127;
    const int kkb  = tid >> 7;
    const int nB = n0 + colB;
    const int bB = nB / HW;
    const int pB = nB - bB * HW;
    const size_t u0 = (size_t)bB * K * HW + pB;

    float acc[8][8] = {};

    for (int k0 = 0; k0 < K; k0 += 16) {
        float4 va = av0 ? *(const float4*)(W + aoff0 + k0) : make_float4(0.f,0.f,0.f,0.f);
        float4 vb = av1 ? *(const float4*)(W + aoff1 + k0) : make_float4(0.f,0.f,0.f,0.f);
        As[kqA*4+0][amA] = va.x; As[kqA*4+1][amA] = va.y;
        As[kqA*4+2][amA] = va.z; As[kqA*4+3][amA] = va.w;
        As[kqA*4+0][amA+64] = vb.x; As[kqA*4+1][amA+64] = vb.y;
        As[kqA*4+2][amA+64] = vb.z; As[kqA*4+3][amA+64] = vb.w;
        #pragma unroll
        for (int e = 0; e < 8; ++e) {
            const int kk = e*2 + kkb;
            Bs[kk][colB] = X0[u0 + (size_t)(k0 + kk) * HW];
        }
        __syncthreads();
        tile_fma(As, Bs, acc, tx, ty);
        __syncthreads();
    }

    float s1v[8] = {}, s2v[8] = {};
    const int nE = n0 + tx*8;
    const int bE0 = nE / HW;
    const int pE0 = nE - bE0 * HW;
    #pragma unroll
    for (int e = 0; e < 8; ++e) {
        const int m = ty*8 + e;
        if (m < M) {
            const float bsv = bias[m];
            int b = bE0, p = pE0;
            #pragma unroll
            for (int f = 0; f < 8; ++f) {
                const float v = acc[e][f] + bsv;
                Y[((size_t)b * M + m) * HW + p] = v;
                s1v[e] += v;
                s2v[e] += v * v;
                if (++p == HW) { p = 0; ++b; }
            }
        }
    }
    #pragma unroll
    for (int e = 0; e < 8; ++e) {
        #pragma unroll
        for (int msk = 1; msk <= 8; msk <<= 1) {
            s1v[e] += __shfl_xor(s1v[e], msk);
            s2v[e] += __shfl_xor(s2v[e], msk);
        }
    }
    if (tx == 0) {
        #pragma unroll
        for (int e = 0; e < 8; ++e) {
            const int m = ty*8 + e;
            if (m < 128) { as1[m] = s1v[e]; as2[m] = s2v[e]; }
        }
    }
    __syncthreads();
    if (tid < M) {
        ps1[blockIdx.y * M + tid] = as1[tid];
        ps2[blockIdx.y * M + tid] = as2[tid];
    }
}

// ---------------- c1 MFMA GEMM, BM=128 x BN=64 (4 m-slice waves of 32x64) ----------------
// grid (196, 2): 392 blocks. Epilogue writes xpad (fp32) + xpadT (bf16).
__global__ __launch_bounds__(256, 2) void k_gemmc1(
    const __hip_bfloat16* __restrict__ A, const __hip_bfloat16* __restrict__ B0,
    const float* __restrict__ bias, float* __restrict__ Xpad,
    __hip_bfloat16* __restrict__ XpadT)
{
    __shared__ __hip_bfloat16 As[8192];   // [128][64]
    __shared__ __hip_bfloat16 Bs[4096];   // [64][64]
    const int tid  = threadIdx.x;
    const int w    = tid >> 6;
    const int lane = tid & 63;
    const int n0   = blockIdx.x * 64;
    const int m0   = blockIdx.y * 128;

    // A staging: 1024 slots, 4/thread
    unsigned aoffs[4];
    void* adst[4];
    #pragma unroll
    for (int j = 0; j < 4; ++j) {
        const int slot = (w*4 + j)*64 + lane;
        const int row  = slot >> 3;
        const int q    = slot & 7;
        const int lc   = q ^ (row & 7);
        aoffs[j] = (unsigned)(m0 + row) * 512u + (unsigned)lc * 8u;
        adst[j]  = (void*)&As[(w*4 + j) * 512];
    }
    // B staging: 512 slots, 2/thread
    unsigned boffs[2];
    void* bdst[2];
    #pragma unroll
    for (int j = 0; j < 2; ++j) {
        const int slot = (w*2 + j)*64 + lane;
        const int row  = slot >> 3;
        const int q    = slot & 7;
        const int lc   = q ^ (row & 7);
        boffs[j] = (unsigned)(n0 + row) * 512u + (unsigned)lc * 8u;
        bdst[j]  = (void*)&Bs[(w*2 + j) * 512];
    }

    const int l15 = lane & 15, lg = lane >> 4;
    const int m_w0 = w * 32;
    int rowA[2], rowB[4], chunkoff[2];
    #pragma unroll
    for (int i = 0; i < 2; ++i)
        rowA[i] = (m_w0 + i*16 + l15) * 128;     // byte offsets (row stride 128B)
    #pragma unroll
    for (int j = 0; j < 4; ++j)
        rowB[j] = (j*16 + l15) * 128;
    #pragma unroll
    for (int ks = 0; ks < 2; ++ks)
        chunkoff[ks] = ((4*ks + lg) ^ (lane & 7)) * 16;

    f32x4 acc[2][4];
    #pragma unroll
    for (int i = 0; i < 2; ++i)
        #pragma unroll
        for (int j = 0; j < 4; ++j)
            acc[i][j] = (f32x4){0.f, 0.f, 0.f, 0.f};

    for (int k0 = 0; k0 < 512; k0 += 64) {
        #pragma unroll
        for (int j = 0; j < 4; ++j) gll16(A + aoffs[j] + k0, adst[j]);
        #pragma unroll
        for (int j = 0; j < 2; ++j) gll16(B0 + boffs[j] + k0, bdst[j]);
        __syncthreads();
        #pragma unroll
        for (int ks = 0; ks < 2; ++ks) {
            const int co = chunkoff[ks];
            bf16x8 av[2], bv[4];
            #pragma unroll
            for (int i = 0; i < 2; ++i)
                av[i] = *(const bf16x8*)((const char*)As + rowA[i] + co);
            #pragma unroll
            for (int j = 0; j < 4; ++j)
                bv[j] = *(const bf16x8*)((const char*)Bs + rowB[j] + co);
            #pragma unroll
            for (int i = 0; i < 2; ++i)
                #pragma unroll
                for (int j = 0; j < 4; ++j)
                    acc[i][j] = __builtin_amdgcn_mfma_f32_16x16x32_bf16(av[i], bv[j], acc[i][j], 0, 0, 0);
        }
        __syncthreads();
    }

    #pragma unroll
    for (int j = 0; j < 4; ++j) {
        const int n = n0 + j*16 + l15;
        const int b = n / HW;
        const int p = n - b * HW;
        const int h = p / 56;
        const int ww = p - h * 56;
        #pragma unroll
        for (int i = 0; i < 2; ++i) {
            const int m = m0 + m_w0 + i*16 + lg*4;
            const float4 bs4 = *(const float4*)&bias[m];
            float v0 = fmaxf(acc[i][j][0] + bs4.x, 0.f);
            float v1 = fmaxf(acc[i][j][1] + bs4.y, 0.f);
            float v2 = fmaxf(acc[i][j][2] + bs4.z, 0.f);
            float v3 = fmaxf(acc[i][j][3] + bs4.w, 0.f);
            float* dp = Xpad + ((size_t)(b*256 + m)) * PADA + (h + 6) * 68 + (ww + 6);
            dp[0]      = v0;
            dp[PADA]   = v1;
            dp[2*PADA] = v2;
            dp[3*PADA] = v3;
            ushort4 pk;
            pk.x = __bfloat16_as_ushort(__float2bfloat16(v0));
            pk.y = __bfloat16_as_ushort(__float2bfloat16(v1));
            pk.z = __bfloat16_as_ushort(__float2bfloat16(v2));
            pk.w = __bfloat16_as_ushort(__float2bfloat16(v3));
            *(ushort4*)(XpadT + ((size_t)((b*68 + h + 6)*68 + ww + 6)) * 256 + m) = pk;
        }
    }
}

// ---------------- c2 MFMA GEMM, BM=128 x BN=64 + BN partial sums ----------------
// grid (196): waves own disjoint 32-row m-slices -> direct bs1[128] writes.
__global__ __launch_bounds__(256, 2) void k_gemmc2(
    const __hip_bfloat16* __restrict__ A, const __hip_bfloat16* __restrict__ XT,
    const __hip_bfloat16* __restrict__ AT, const float* __restrict__ bias,
    float* __restrict__ Y, float* __restrict__ ps1, float* __restrict__ ps2)
{
    __shared__ __hip_bfloat16 As[8192];   // [128][64]
    __shared__ __hip_bfloat16 Bs[4096];   // [64][64]
    __shared__ float bs1[128], bs2[128];
    const int tid  = threadIdx.x;
    const int w    = tid >> 6;
    const int lane = tid & 63;
    const int n0   = blockIdx.x * 64;

    unsigned aoffs[4];
    void* adst[4];
    #pragma unroll
    for (int j = 0; j < 4; ++j) {
        const int slot = (w*4 + j)*64 + lane;
        const int row  = slot >> 3;
        const int q    = slot & 7;
        const int lc   = q ^ (row & 7);
        aoffs[j] = (unsigned)row * 512u + (unsigned)lc * 8u;
        adst[j]  = (void*)&As[(w*4 + j) * 512];
    }
    unsigned boffs0[2], boffs1[2];
    void* bdst[2];
    #pragma unroll
    for (int j = 0; j < 2; ++j) {
        const int slot = (w*2 + j)*64 + lane;
        const int row  = slot >> 3;
        const int q    = slot & 7;
        const int lc   = q ^ (row & 7);
        const int n = n0 + row;
        const int b = n / HW;
        const int p = n - b * HW;
        const int h = p / 56;
        const int ww = p - h * 56;
        boffs0[j] = ((unsigned)(b*68 + h + 6)*68 + (unsigned)(ww + 6))*256u + (unsigned)lc * 8u;
        boffs1[j] = (unsigned)n * 256u + (unsigned)lc * 8u;
        bdst[j]  = (void*)&Bs[(w*2 + j) * 512];
    }

    const int l15 = lane & 15, lg = lane >> 4;
    const int m_w0 = w * 32;
    int rowA[2], rowB[4], chunkoff[2];
    #pragma unroll
    for (int i = 0; i < 2; ++i)
        rowA[i] = (m_w0 + i*16 + l15) * 128;
    #pragma unroll
    for (int j = 0; j < 4; ++j)
        rowB[j] = (j*16 + l15) * 128;
    #pragma unroll
    for (int ks = 0; ks < 2; ++ks)
        chunkoff[ks] = ((4*ks + lg) ^ (lane & 7)) * 16;

    f32x4 acc[2][4];
    #pragma unroll
    for (int i = 0; i < 2; ++i)
        #pragma unroll
        for (int j = 0; j < 4; ++j)
            acc[i][j] = (f32x4){0.f, 0.f, 0.f, 0.f};

    for (int k0 = 0; k0 < 512; k0 += 64) {
        #pragma unroll
        for (int j = 0; j < 4; ++j) gll16(A + aoffs[j] + k0, adst[j]);
        if (k0 < 256) {
            #pragma unroll
            for (int j = 0; j < 2; ++j) gll16(XT + boffs0[j] + k0, bdst[j]);
        } else {
            #pragma unroll
            for (int j = 0; j < 2; ++j) gll16(AT + boffs1[j] + (k0 - 256), bdst[j]);
        }
        __syncthreads();
        #pragma unroll
        for (int ks = 0; ks < 2; ++ks) {
            const int co = chunkoff[ks];
            bf16x8 av[2], bv[4];
            #pragma unroll
            for (int i = 0; i < 2; ++i)
                av[i] = *(const bf16x8*)((const char*)As + rowA[i] + co);
            #pragma unroll
            for (int j = 0; j < 4; ++j)
                bv[j] = *(const bf16x8*)((const char*)Bs + rowB[j] + co);
            #pragma unroll
            for (int i = 0; i < 2; ++i)
                #pragma unroll
                for (int j = 0; j < 4; ++j)
                    acc[i][j] = __builtin_amdgcn_mfma_f32_16x16x32_bf16(av[i], bv[j], acc[i][j], 0, 0, 0);
        }
        __syncthreads();
    }

    float s1loc[8] = {}, s2loc[8] = {};
    #pragma unroll
    for (int j = 0; j < 4; ++j) {
        const int n = n0 + j*16 + l15;
        const int b = n / HW;
        const int p = n - b * HW;
        #pragma unroll
        for (int i = 0; i < 2; ++i) {
            const int m = m_w0 + i*16 + lg*4;
            const float4 bs4 = *(const float4*)&bias[m];
            float v0 = acc[i][j][0] + bs4.x;
            float v1 = acc[i][j][1] + bs4.y;
            float v2 = acc[i][j][2] + bs4.z;
            float v3 = acc[i][j][3] + bs4.w;
            float* dst = Y + ((size_t)(b*128 + m) * HW + p);
            dst[0]    = v0;
            dst[HW]   = v1;
            dst[2*HW] = v2;
            dst[3*HW] = v3;
            s1loc[i*4+0] += v0; s2loc[i*4+0] += v0*v0;
            s1loc[i*4+1] += v1; s2loc[i*4+1] += v1*v1;
            s1loc[i*4+2] += v2; s2loc[i*4+2] += v2*v2;
            s1loc[i*4+3] += v3; s2loc[i*4+3] += v3*v3;
        }
    }
    #pragma unroll
    for (int k = 0; k < 8; ++k) {
        #pragma unroll
        for (int msk = 1; msk <= 8; msk <<= 1) {
            s1loc[k] += __shfl_xor(s1loc[k], msk);
            s2loc[k] += __shfl_xor(s2loc[k], msk);
        }
    }
    if (l15 == 0) {
        #pragma unroll
        for (int i = 0; i < 2; ++i)
            #pragma unroll
            for (int r = 0; r < 4; ++r) {
                const int m = m_w0 + i*16 + lg*4 + r;
                bs1[m] = s1loc[i*4+r];
                bs2[m] = s2loc[i*4+r];
            }
    }
    __syncthreads();
    if (tid < 128) {
        ps1[blockIdx.x * 128 + tid] = bs1[tid];
        ps2[blockIdx.x * 128 + tid] = bs2[tid];
    }
}

// ---------------- dilated 7x7 conv: bf16 MFMA implicit GEMM, K-split x5, bf16 partials (validated) ----------------
__global__ __launch_bounds__(256, 2) void k_convmfma(
    const __hip_bfloat16* __restrict__ Wbf, const __hip_bfloat16* __restrict__ XT,
    __hip_bfloat16* __restrict__ o0, __hip_bfloat16* __restrict__ o1,
    __hip_bfloat16* __restrict__ o2, __hip_bfloat16* __restrict__ o3,
    __hip_bfloat16* __restrict__ o4)
{
    __shared__ __hip_bfloat16 As[8192];
    __shared__ __hip_bfloat16 Bs[8192];
    const int tid  = threadIdx.x;
    const int w    = tid >> 6;
    const int lane = tid & 63;
    const int n0   = blockIdx.x * 128;
    const int s    = blockIdx.y;
    const int t_start = (s < 4) ? s * 40 : 158;
    const int cnt     = (s < 3) ? 40 : 38;
    __hip_bfloat16* __restrict__ out = (s==0)?o0:(s==1)?o1:(s==2)?o2:(s==3)?o3:o4;

    unsigned aoffs[4], boffs[4];
    void *adst[4], *bdst[4];
    #pragma unroll
    for (int j = 0; j < 4; ++j) {
        const int slot = (w*4 + j)*64 + lane;
        const int row  = slot >> 3;
        const int q    = slot & 7;
        const int lc   = q ^ (row & 7);
        aoffs[j] = (unsigned)row * 12544u + (unsigned)lc * 8u;
        adst[j]  = (void*)&As[(w*4 + j) * 512];
        const int n = n0 + row;
        const int b = n / HW;
        const int p = n - b * HW;
        const int h = p / 56;
        const int ww = p - h * 56;
        boffs[j] = ((unsigned)(b*68 + h)*68 + (unsigned)ww)*256u + (unsigned)lc * 8u;
        bdst[j]  = (void*)&Bs[(w*4 + j) * 512];
    }

    const int l15 = lane & 15, lg = lane >> 4;
    const int m_w0 = (w & 1) * 64;
    const int n_w0 = (w >> 1) * 64;
    int rowA[4], rowB[4], chunkoff[2];
    #pragma unroll
    for (int i = 0; i < 4; ++i) {
        rowA[i] = (m_w0 + i*16 + l15) * 128;
        rowB[i] = (n_w0 + i*16 + l15) * 128;
    }
    #pragma unroll
    for (int ks = 0; ks < 2; ++ks)
        chunkoff[ks] = ((4*ks + lg) ^ (lane & 7)) * 16;

    f32x4 acc[4][4];
    #pragma unroll
    for (int i = 0; i < 4; ++i)
        #pragma unroll
        for (int j = 0; j < 4; ++j)
            acc[i][j] = (f32x4){0.f, 0.f, 0.f, 0.f};

    for (int it = 0; it < cnt; ++it) {
        const int kt = t_start + it;
        const int k0 = kt << 6;
        const int t  = k0 >> 8;
        const int c0 = k0 & 255;
        const int ti = (t * 37) >> 8;
        const int tj = t - ti * 7;
        const unsigned aof = (unsigned)k0;
        const unsigned bof = (unsigned)(ti*68 + tj) * 512u + (unsigned)c0;

        #pragma unroll
        for (int j = 0; j < 4; ++j) gll16(Wbf + aoffs[j] + aof, adst[j]);
        #pragma unroll
        for (int j = 0; j < 4; ++j) gll16(XT + boffs[j] + bof, bdst[j]);

        __syncthreads();

        #pragma unroll
        for (int ks = 0; ks < 2; ++ks) {
            const int co = chunkoff[ks];
            bf16x8 av[4], bv[4];
            #pragma unroll
            for (int i = 0; i < 4; ++i)
                av[i] = *(const bf16x8*)((const char*)As + rowA[i] + co);
            #pragma unroll
            for (int i = 0; i < 4; ++i)
                bv[i] = *(const bf16x8*)((const char*)Bs + rowB[i] + co);
            #pragma unroll
            for (int i = 0; i < 4; ++i)
                #pragma unroll
                for (int j = 0; j < 4; ++j)
                    acc[i][j] = __builtin_amdgcn_mfma_f32_16x16x32_bf16(av[i], bv[j], acc[i][j], 0, 0, 0);
        }
        __syncthreads();
    }

    #pragma unroll
    for (int j = 0; j < 4; ++j) {
        const int n = n0 + n_w0 + j*16 + l15;
        const int b = n / HW;
        const int p = n - b * HW;
        #pragma unroll
        for (int i = 0; i < 4; ++i) {
            const int m = m_w0 + i*16 + lg*4;
            __hip_bfloat16* dst = out + ((size_t)(b*128 + m) * HW + p);
            dst[0]      = __float2bfloat16(acc[i][j][0]);
            dst[HW]     = __float2bfloat16(acc[i][j][1]);
            dst[2*HW]   = __float2bfloat16(acc[i][j][2]);
            dst[3*HW]   = __float2bfloat16(acc[i][j][3]);
        }
    }
}

// ---------------- combine 5 bf16 partials + bias + relu -> k1 (validated) ----------------
__global__ __launch_bounds__(256) void k_combine5(
    const short8v* __restrict__ p0, const short8v* __restrict__ p1,
    const short8v* __restrict__ p2, const short8v* __restrict__ p3,
    const short8v* __restrict__ p4,
    const float* __restrict__ bias, float* __restrict__ Y)
{
    const int j = blockIdx.x * 256 + threadIdx.x;
    short8v a = p0[j], b = p1[j], c = p2[j], d = p3[j], e5 = p4[j];
    const int oc = ((j * 8) / HW) & 127;
    const float bv = bias[oc];
    float o[8];
    #pragma unroll
    for (int e = 0; e < 8; ++e) {
        float v = bf2f(a[e]) + bf2f(b[e]) + bf2f(c[e]) + bf2f(d[e]) + bf2f(e5[e]) + bv;
        o[e] = fmaxf(v, 0.f);
    }
    float4* dst = (float4*)(Y + (size_t)j * 8);
    dst[0] = *(float4*)&o[0];
    dst[1] = *(float4*)&o[4];
}

// ---------------- fused BN(from partials) + relu + softmax over 49 channels (validated) ----------------
__global__ __launch_bounds__(256) void k_bnsoftmax(float* __restrict__ X,
        const float* __restrict__ ps1, const float* __restrict__ ps2,
        const float* __restrict__ gam,  const float* __restrict__ bet)
{
    __shared__ float msh[NT], rsh[NT];
    const int tid = threadIdx.x;
    if (tid < NT) {
        float s1 = 0.f, s2 = 0.f;
        for (int b = 0; b < NB_ATT; ++b) {
            s1 += ps1[b * NT + tid];
            s2 += ps2[b * NT + tid];
        }
        const float mean = s1 * (1.f / 12544.f);
        const float var  = s2 * (1.f / 12544.f) - mean * mean;
        msh[tid] = mean;
        rsh[tid] = rsqrtf(var + 1e-5f);
    }
    __syncthreads();

    const int gidx = blockIdx.x * 256 + tid;
    const int b = gidx / HW;
    const int p = gidx - b * HW;
    float* base = X + (size_t)b * NT * HW + p;
    float vals[NT];
    float m = -1e30f;
    #pragma unroll
    for (int t = 0; t < NT; ++t) {
        float v = base[(size_t)t * HW];
        v = (v - msh[t]) * rsh[t] * gam[t] + bet[t];
        v = fmaxf(v, 0.f);
        vals[t] = v;
        m = fmaxf(m, v);
    }
    float s = 0.f;
    #pragma unroll
    for (int t = 0; t < NT; ++t) { float e = __expf(vals[t] - m); vals[t] = e; s += e; }
    const float inv = 1.f / s;
    #pragma unroll
    for (int t = 0; t < NT; ++t) base[(size_t)t * HW] = vals[t] * inv;
}

// ---------------- attention apply v2: register-blocked, LDS-free (validated) ----------------
__global__ __launch_bounds__(256) void k_attapply2(const float* __restrict__ Xpad,
        const float* __restrict__ att, float* __restrict__ Y)
{
    const int tid  = threadIdx.x;
    const int wv   = tid >> 6;
    const int lane = tid & 63;
    const int wq   = lane & 15;
    const int rs   = lane >> 4;
    const int rq   = blockIdx.x;
    const int cg   = blockIdx.y;
    const int b    = blockIdx.z;
    const int c    = cg * 4 + wv;
    const int h    = rq * 4 + rs;
    const int w0   = min(wq, 13) * 4;

    const float* xbase = Xpad + ((size_t)(b*256 + c) * 68 + h) * 68 + w0;
    const float* abase = att + (size_t)b * NT * HW + h * 56 + w0;
    float4 acc = {0.f, 0.f, 0.f, 0.f};
    #pragma unroll
    for (int ti = 0; ti < 7; ++ti) {
        const float* xr = xbase + ti * 136;
        float xf[16];
        *(float4*)&xf[0]  = *(const float4*)(xr);
        *(float4*)&xf[4]  = *(const float4*)(xr + 4);
        *(float4*)&xf[8]  = *(const float4*)(xr + 8);
        *(float4*)&xf[12] = *(const float4*)(xr + 12);
        #pragma unroll
        for (int tj = 0; tj < 7; ++tj) {
            const float4 a4 = *(const float4*)(abase + (size_t)(ti*7 + tj) * HW);
            acc.x = fmaf(xf[2*tj + 0], a4.x, acc.x);
            acc.y = fmaf(xf[2*tj + 1], a4.y, acc.y);
            acc.z = fmaf(xf[2*tj + 2], a4.z, acc.z);
            acc.w = fmaf(xf[2*tj + 3], a4.w, acc.w);
        }
    }
    if (wq < 14)
        *(float4*)(Y + (size_t)(b*256 + c) * HW + h * 56 + w0) = acc;
}

// ---------------- fused BN(from partials) + relu -> dec_out, + sigmoid(c3) -> side ----------------
__global__ __launch_bounds__(256) void k_bnside(const float* __restrict__ X,
        const float* __restrict__ ps1, const float* __restrict__ ps2,
        const float* __restrict__ gam,  const float* __restrict__ bet,
        const float* __restrict__ w3,   const float* __restrict__ b3,
        float* __restrict__ dec_out,    float* __restrict__ side)
{
    __shared__ float ms[128], rs[128], gs[128], bs[128], w3s[128];
    const int tid = threadIdx.x;
    if (tid < 128) {
        float s1 = 0.f, s2 = 0.f;
        for (int b = 0; b < NB_C2; ++b) {
            s1 += ps1[b * 128 + tid];
            s2 += ps2[b * 128 + tid];
        }
        const float mean = s1 * (1.f / 12544.f);
        const float var  = s2 * (1.f / 12544.f) - mean * mean;
        ms[tid] = mean;
        rs[tid] = rsqrtf(var + 1e-5f);
        gs[tid] = gam[tid];  bs[tid] = bet[tid];
        w3s[tid] = w3[tid];
    }
    __syncthreads();
    const int gidx = blockIdx.x * 256 + tid;
    const int b = gidx / HW;
    const int p = gidx - b * HW;
    const size_t u = (size_t)b * 128 * HW + p;
    float acc = b3[0];
    #pragma unroll 8
    for (int c = 0; c < 128; ++c) {
        const size_t a = u + (size_t)c * HW;
        float v = (X[a] - ms[c]) * rs[c] * gs[c] + bs[c];
        v = fmaxf(v, 0.f);
        dec_out[a] = v;
        acc = fmaf(v, w3s[c], acc);
    }
    side[gidx] = 1.f / (1.f + __expf(-acc));
}

// ---------------- launcher ----------------
extern "C" void kernel_launch(void* const* d_in, const int* in_sizes, int n_in,
                              void* d_out, int out_size, void* d_ws, size_t ws_size,
                              hipStream_t stream)
{
    const float* en  = (const float*)d_in[0];
    const float* dec = (const float*)d_in[1];
    const float* w1  = (const float*)d_in[2];
    const float* b1  = (const float*)d_in[3];
    const float* w2  = (const float*)d_in[4];
    const float* b2  = (const float*)d_in[5];
    const float* bng = (const float*)d_in[6];
    const float* bnb = (const float*)d_in[7];
    const float* c1w = (const float*)d_in[8];
    const float* c1b = (const float*)d_in[9];
    const float* c2w = (const float*)d_in[10];
    const float* c2b = (const float*)d_in[11];
    const float* bfg = (const float*)d_in[12];
    const float* bfb = (const float*)d_in[13];
    const float* c3w = (const float*)d_in[14];
    const float* c3b = (const float*)d_in[15];

    float* ws = (float*)d_ws;                   // 20,750,848 floats (proven extent)
    __hip_bfloat16* part0 = (__hip_bfloat16*)(ws + R0);
    __hip_bfloat16* part1 = (__hip_bfloat16*)(ws + R0 +  802816u);
    __hip_bfloat16* part2 = (__hip_bfloat16*)(ws + R0 + 1605632u);
    __hip_bfloat16* part3 = (__hip_bfloat16*)(ws + R0 + 2408448u);
    float* fmap_att = ws + R0;                  // region base after combine (parts dead)
    float* attb     = ws + R1;
    float* xpad     = ws + R2;
    float* k1       = ws + R3;
    __hip_bfloat16* xcat = (__hip_bfloat16*)(ws + R4);
    __hip_bfloat16* part4 = (__hip_bfloat16*)(ws + R4);
    __hip_bfloat16* attT  = (__hip_bfloat16*)(ws + R4);
    float* x2       = ws + R4 + 1605632u;
    __hip_bfloat16* c1wb = (__hip_bfloat16*)(ws + R5);            // 131072 bf16
    __hip_bfloat16* c2wb = (__hip_bfloat16*)(ws + R5 + 65536u);   // 65536 bf16
    float* c2s1    = ws + R5 + 131072u;                   // 196*128 = 25088
    float* c2s2    = ws + R5 + 156160u;                   // 196*128 = 25088
    float* atts1   = ws + R5 + 181248u;                   // 98*49
    float* atts2   = ws + R5 + 186050u;                   // 98*49
    __hip_bfloat16* xpadT = (__hip_bfloat16*)(ws + R7);
    __hip_bfloat16* wbf   = (__hip_bfloat16*)(ws + R8);

    float* dec_out = (float*)d_out;
    float* side    = (float*)d_out + 1605632u;

    // 0. zero padded buffers (borders must be 0 every call; interiors overwritten by gemmc1)
    hipMemsetAsync(xpad,  0, (size_t)4 * 256 * PADA * sizeof(float), stream);
    hipMemsetAsync(xpadT, 0, (size_t)4 * PADA * 256 * sizeof(__hip_bfloat16), stream);
    // 1. merged prep
    k_prep<<<dim3(2464), dim3(256), 0, stream>>>(en, dec, c1w, c2w, w1, xcat, c1wb, c2wb, wbf);
    // 2. relu(c1 x xcat) via MFMA -> xpad + xpadT  (BN=64 tiles, 392 blocks)
    k_gemmc1<<<dim3(196, 2), dim3(256), 0, stream>>>(c1wb, xcat, c1b, xpad, xpadT);
    // 3. big dilated conv (K-split x5, bf16 partials)
    k_convmfma<<<dim3(98, 5), dim3(256), 0, stream>>>(wbf, xpadT, part0, part1, part2, part3, part4);
    // 4. combine -> k1
    k_combine5<<<dim3(784), dim3(256), 0, stream>>>((const short8v*)part0, (const short8v*)part1,
                                                    (const short8v*)part2, (const short8v*)part3,
                                                    (const short8v*)part4, b1, k1);
    // 5. attention logits = w2 * k1 + b2, with fused BN partial sums
    k_gemm1x1<<<dim3(1, 98), dim3(256), 0, stream>>>(w2, b2, k1, 49, 128, attb, atts1, atts2);
    // 6. BN(from partials) + relu + softmax(49) in place
    k_bnsoftmax<<<dim3(49), dim3(256), 0, stream>>>(attb, atts1, atts2, bng, bnb);
    // 7. local attention gather -> fmap_att
    k_attapply2<<<dim3(14, 64, 4), dim3(256), 0, stream>>>(xpad, attb, fmap_att);
    // 8. fmap_att -> attT NHWC bf16
    k_t2nhwc<<<dim3(49, 4, 4), dim3(256), 0, stream>>>(fmap_att, attT, 256, 0);
    // 9. x2 = c2 x [xpadT(center) ; attT] via MFMA (BN=64 tiles, 196 blocks) + BN partials
    k_gemmc2<<<dim3(196), dim3(256), 0, stream>>>(c2wb, xpadT, attT, c2b, x2, c2s1, c2s2);
    // 10. fused BN(from partials)/relu -> dec_out + sigmoid side
    k_bnside<<<dim3(49), dim3(256), 0, stream>>>(x2, c2s1, c2s2, bfg, bfb,
                                                 c3w, c3b, dec_out, side);
}

// Round 16
// 173.990 us; speedup vs baseline: 1.3377x; 1.0443x over previous
//
#include <hip/hip_runtime.h>
#include <hip/hip_bf16.h>
#include <math.h>

// ---------------- problem constants ----------------
#define HW    3136        // 56*56
#define PADA  4624        // 68*68 padded plane (fp32 NCHW)
#define NT    49
#define NB_ATT 98         // w2-gemm n-blocks (12544/128)
#define NB_C2  196        // c2-gemm n-blocks (12544/64)

// ---------------- workspace regions (float offsets) — proven extent ----------------
#define R0 0u
#define R1 3211264u
#define R2 6422528u
#define R3 11157504u
#define R4 12763136u
#define R5 15974400u
#define R7 17580544u
#define R8 19948032u

typedef __attribute__((ext_vector_type(8))) short bf16x8;
typedef __attribute__((ext_vector_type(8))) short short8v;
typedef __attribute__((ext_vector_type(4))) float f32x4;

__device__ __forceinline__ void gll16(const void* g, void* l) {
    __builtin_amdgcn_global_load_lds((const __attribute__((address_space(1))) void*)g,
                                     (__attribute__((address_space(3))) void*)l, 16, 0, 0);
}

__device__ __forceinline__ float bf2f(short u) {
    return __uint_as_float(((unsigned)(unsigned short)u) << 16);
}

// ---------------- merged prep (validated R14) ----------------
__global__ __launch_bounds__(256) void k_prep(
    const float* __restrict__ en, const float* __restrict__ dec,
    const float* __restrict__ c1w, const float* __restrict__ c2w,
    const float* __restrict__ w1,
    __hip_bfloat16* __restrict__ xcat, __hip_bfloat16* __restrict__ c1wb,
    __hip_bfloat16* __restrict__ c2wb, __hip_bfloat16* __restrict__ wbf)
{
    __shared__ float sm[12593];
    const int bid = blockIdx.x;
    const int tid = threadIdx.x;

    if (bid < 784) {
        const int p0 = (bid % 49) * 64;
        const int c0 = ((bid / 49) & 3) * 64;
        const int b  = bid / 196;
        const int pl = tid & 63, cr = tid >> 6;
        #pragma unroll
        for (int i = 0; i < 16; ++i) {
            const int c = c0 + i*4 + cr;
            sm[(i*4+cr)*65 + pl] = en[((size_t)(b*256 + c)) * HW + p0 + pl];
        }
        __syncthreads();
        const int cl = tid & 63, pr = tid >> 6;
        #pragma unroll
        for (int i = 0; i < 16; ++i) {
            const int p = p0 + i*4 + pr;
            xcat[((size_t)(b*HW + p)) * 512 + c0 + cl] = __float2bfloat16(sm[cl*65 + i*4+pr]);
        }
    } else if (bid < 1568) {
        const int bb = bid - 784;
        const int p0 = (bb % 49) * 64;
        const int c0 = ((bb / 49) & 3) * 64;
        const int b  = bb / 196;
        const int pl = tid & 63, cr = tid >> 6;

        const int p = p0 + pl;
        const int h = p / 56;
        const int w = p - h * 56;
        int ih0; float fh;
        if (h & 1) { ih0 = h >> 1;       fh = 0.25f; }
        else       { ih0 = (h >> 1) - 1; fh = 0.75f; }
        int ih1 = min(ih0 + 1, 27); ih0 = max(ih0, 0);
        int iw0; float fw;
        if (w & 1) { iw0 = w >> 1;       fw = 0.25f; }
        else       { iw0 = (w >> 1) - 1; fw = 0.75f; }
        int iw1 = min(iw0 + 1, 27); iw0 = max(iw0, 0);
        const int o00 = ih0*28 + iw0, o01 = ih0*28 + iw1;
        const int o10 = ih1*28 + iw0, o11 = ih1*28 + iw1;
        const float w00 = (1.f-fh)*(1.f-fw), w01 = (1.f-fh)*fw;
        const float w10 = fh*(1.f-fw),       w11 = fh*fw;

        #pragma unroll
        for (int i = 0; i < 16; ++i) {
            const int c = c0 + i*4 + cr;
            const float* s = dec + (size_t)(b*256 + c) * 784;
            sm[(i*4+cr)*65 + pl] = w00*s[o00] + w01*s[o01] + w10*s[o10] + w11*s[o11];
        }
        __syncthreads();
        const int cl = tid & 63, pr = tid >> 6;
        #pragma unroll
        for (int i = 0; i < 16; ++i) {
            const int pp = p0 + i*4 + pr;
            xcat[((size_t)(b*HW + pp)) * 512 + 256 + c0 + cl] = __float2bfloat16(sm[cl*65 + i*4+pr]);
        }
    } else if (bid < 2080) {
        const int j = (bid - 1568) * 256 + tid;
        c1wb[j] = __float2bfloat16(c1w[j]);
    } else if (bid < 2336) {
        const int j = (bid - 2080) * 256 + tid;
        c2wb[j] = __float2bfloat16(c2w[j]);
    } else {
        const int oc = bid - 2336;
        const float* src = w1 + (size_t)oc * 12544;
        #pragma unroll
        for (int i = 0; i < 49; ++i) {
            const int idx = i * 256 + tid;
            const int c  = idx / 49;
            const int tt = idx - c * 49;
            sm[tt * 257 + c] = src[idx];
        }
        __syncthreads();
        __hip_bfloat16* dst = wbf + (size_t)oc * 12544;
        #pragma unroll
        for (int i = 0; i < 49; ++i)
            dst[i * 256 + tid] = __float2bfloat16(sm[i * 257 + tid]);
    }
}

// ---------------- tiled NCHW fp32 -> NHWC bf16 transpose (validated; attT) ----------------
__global__ __launch_bounds__(256) void k_t2nhwc(const float* __restrict__ src,
        __hip_bfloat16* __restrict__ dst, int kstride, int c_off)
{
    __shared__ float t[64][65];
    const int tid = threadIdx.x;
    const int p0 = blockIdx.x * 64;
    const int c0 = blockIdx.y * 64;
    const int b  = blockIdx.z;
    const int pl = tid & 63, cr = tid >> 6;
    #pragma unroll
    for (int i = 0; i < 16; ++i) {
        const int c = c0 + i*4 + cr;
        t[i*4+cr][pl] = src[((size_t)(b*256 + c)) * HW + p0 + pl];
    }
    __syncthreads();
    const int cl = tid & 63, pr = tid >> 6;
    #pragma unroll
    for (int i = 0; i < 16; ++i) {
        const int p = p0 + i*4 + pr;
        dst[((size_t)(b*HW + p)) * kstride + c_off + c0 + cl] = __float2bfloat16(t[cl][i*4+pr]);
    }
}

// ---------------- fp32 8x8 FMA microtile (w2 gemm only) ----------------
__device__ __forceinline__ void tile_fma(const float (*As)[128], const float (*Bs)[128],
                                         float acc[8][8], int tx, int ty)
{
    #pragma unroll
    for (int kk = 0; kk < 16; ++kk) {
        const float4 a0 = *(const float4*)&As[kk][ty*8];
        const float4 a1 = *(const float4*)&As[kk][ty*8+4];
        const float4 b0 = *(const float4*)&Bs[kk][tx*8];
        const float4 b1 = *(const float4*)&Bs[kk][tx*8+4];
        const float av[8] = {a0.x,a0.y,a0.z,a0.w,a1.x,a1.y,a1.z,a1.w};
        const float bv[8] = {b0.x,b0.y,b0.z,b0.w,b1.x,b1.y,b1.z,b1.w};
        #pragma unroll
        for (int e = 0; e < 8; ++e)
            #pragma unroll
            for (int f = 0; f < 8; ++f)
                acc[e][f] = fmaf(av[e], bv[f], acc[e][f]);
    }
}

// ---------------- fp32 1x1 GEMM (w2: M=49, K=128) + BN partial sums (validated) ----------------
__global__ __launch_bounds__(256, 2) void k_gemm1x1(
    const float* __restrict__ W, const float* __restrict__ bias,
    const float* __restrict__ X0, int M, int K, float* __restrict__ Y,
    float* __restrict__ ps1, float* __restrict__ ps2)
{
    __shared__ float As[16][128];
    __shared__ float Bs[16][128];
    __shared__ float as1[128], as2[128];
    const int tid = threadIdx.x;
    const int tx = tid & 15, ty = tid >> 4;
    const int n0 = blockIdx.y * 128;

    const int amA = tid >> 2;
    const int kqA = tid & 3;
    const bool av0 = amA < M;
    const bool av1 = (amA + 64) < M;
    const size_t aoff0 = (size_t)amA * K + kqA * 4;
    const size_t aoff1 = (size_t)(amA + 64) * K + kqA * 4;

    const int colB = tid & 127;
    const int kkb  = tid >> 7;
    const int nB = n0 + colB;
    const int bB = nB / HW;
    const int pB = nB - bB * HW;
    const size_t u0 = (size_t)bB * K * HW + pB;

    float acc[8][8] = {};

    for (int k0 = 0; k0 < K; k0 += 16) {
        float4 va = av0 ? *(const float4*)(W + aoff0 + k0) : make_float4(0.f,0.f,0.f,0.f);
        float4 vb = av1 ? *(const float4*)(W + aoff1 + k0) : make_float4(0.f,0.f,0.f,0.f);
        As[kqA*4+0][amA] = va.x; As[kqA*4+1][amA] = va.y;
        As[kqA*4+2][amA] = va.z; As[kqA*4+3][amA] = va.w;
        As[kqA*4+0][amA+64] = vb.x; As[kqA*4+1][amA+64] = vb.y;
        As[kqA*4+2][amA+64] = vb.z; As[kqA*4+3][amA+64] = vb.w;
        #pragma unroll
        for (int e = 0; e < 8; ++e) {
            const int kk = e*2 + kkb;
            Bs[kk][colB] = X0[u0 + (size_t)(k0 + kk) * HW];
        }
        __syncthreads();
        tile_fma(As, Bs, acc, tx, ty);
        __syncthreads();
    }

    float s1v[8] = {}, s2v[8] = {};
    const int nE = n0 + tx*8;
    const int bE0 = nE / HW;
    const int pE0 = nE - bE0 * HW;
    #pragma unroll
    for (int e = 0; e < 8; ++e) {
        const int m = ty*8 + e;
        if (m < M) {
            const float bsv = bias[m];
            int b = bE0, p = pE0;
            #pragma unroll
            for (int f = 0; f < 8; ++f) {
                const float v = acc[e][f] + bsv;
                Y[((size_t)b * M + m) * HW + p] = v;
                s1v[e] += v;
                s2v[e] += v * v;
                if (++p == HW) { p = 0; ++b; }
            }
        }
    }
    #pragma unroll
    for (int e = 0; e < 8; ++e) {
        #pragma unroll
        for (int msk = 1; msk <= 8; msk <<= 1) {
            s1v[e] += __shfl_xor(s1v[e], msk);
            s2v[e] += __shfl_xor(s2v[e], msk);
        }
    }
    if (tx == 0) {
        #pragma unroll
        for (int e = 0; e < 8; ++e) {
            const int m = ty*8 + e;
            if (m < 128) { as1[m] = s1v[e]; as2[m] = s2v[e]; }
        }
    }
    __syncthreads();
    if (tid < M) {
        ps1[blockIdx.y * M + tid] = as1[tid];
        ps2[blockIdx.y * M + tid] = as2[tid];
    }
}

// ---------------- c1 MFMA GEMM, BM=128 x BN=64 (validated R15) ----------------
__global__ __launch_bounds__(256, 2) void k_gemmc1(
    const __hip_bfloat16* __restrict__ A, const __hip_bfloat16* __restrict__ B0,
    const float* __restrict__ bias, float* __restrict__ Xpad,
    __hip_bfloat16* __restrict__ XpadT)
{
    __shared__ __hip_bfloat16 As[8192];   // [128][64]
    __shared__ __hip_bfloat16 Bs[4096];   // [64][64]
    const int tid  = threadIdx.x;
    const int w    = tid >> 6;
    const int lane = tid & 63;
    const int n0   = blockIdx.x * 64;
    const int m0   = blockIdx.y * 128;

    unsigned aoffs[4];
    void* adst[4];
    #pragma unroll
    for (int j = 0; j < 4; ++j) {
        const int slot = (w*4 + j)*64 + lane;
        const int row  = slot >> 3;
        const int q    = slot & 7;
        const int lc   = q ^ (row & 7);
        aoffs[j] = (unsigned)(m0 + row) * 512u + (unsigned)lc * 8u;
        adst[j]  = (void*)&As[(w*4 + j) * 512];
    }
    unsigned boffs[2];
    void* bdst[2];
    #pragma unroll
    for (int j = 0; j < 2; ++j) {
        const int slot = (w*2 + j)*64 + lane;
        const int row  = slot >> 3;
        const int q    = slot & 7;
        const int lc   = q ^ (row & 7);
        boffs[j] = (unsigned)(n0 + row) * 512u + (unsigned)lc * 8u;
        bdst[j]  = (void*)&Bs[(w*2 + j) * 512];
    }

    const int l15 = lane & 15, lg = lane >> 4;
    const int m_w0 = w * 32;
    int rowA[2], rowB[4], chunkoff[2];
    #pragma unroll
    for (int i = 0; i < 2; ++i)
        rowA[i] = (m_w0 + i*16 + l15) * 128;
    #pragma unroll
    for (int j = 0; j < 4; ++j)
        rowB[j] = (j*16 + l15) * 128;
    #pragma unroll
    for (int ks = 0; ks < 2; ++ks)
        chunkoff[ks] = ((4*ks + lg) ^ (lane & 7)) * 16;

    f32x4 acc[2][4];
    #pragma unroll
    for (int i = 0; i < 2; ++i)
        #pragma unroll
        for (int j = 0; j < 4; ++j)
            acc[i][j] = (f32x4){0.f, 0.f, 0.f, 0.f};

    for (int k0 = 0; k0 < 512; k0 += 64) {
        #pragma unroll
        for (int j = 0; j < 4; ++j) gll16(A + aoffs[j] + k0, adst[j]);
        #pragma unroll
        for (int j = 0; j < 2; ++j) gll16(B0 + boffs[j] + k0, bdst[j]);
        __syncthreads();
        #pragma unroll
        for (int ks = 0; ks < 2; ++ks) {
            const int co = chunkoff[ks];
            bf16x8 av[2], bv[4];
            #pragma unroll
            for (int i = 0; i < 2; ++i)
                av[i] = *(const bf16x8*)((const char*)As + rowA[i] + co);
            #pragma unroll
            for (int j = 0; j < 4; ++j)
                bv[j] = *(const bf16x8*)((const char*)Bs + rowB[j] + co);
            #pragma unroll
            for (int i = 0; i < 2; ++i)
                #pragma unroll
                for (int j = 0; j < 4; ++j)
                    acc[i][j] = __builtin_amdgcn_mfma_f32_16x16x32_bf16(av[i], bv[j], acc[i][j], 0, 0, 0);
        }
        __syncthreads();
    }

    #pragma unroll
    for (int j = 0; j < 4; ++j) {
        const int n = n0 + j*16 + l15;
        const int b = n / HW;
        const int p = n - b * HW;
        const int h = p / 56;
        const int ww = p - h * 56;
        #pragma unroll
        for (int i = 0; i < 2; ++i) {
            const int m = m0 + m_w0 + i*16 + lg*4;
            const float4 bs4 = *(const float4*)&bias[m];
            float v0 = fmaxf(acc[i][j][0] + bs4.x, 0.f);
            float v1 = fmaxf(acc[i][j][1] + bs4.y, 0.f);
            float v2 = fmaxf(acc[i][j][2] + bs4.z, 0.f);
            float v3 = fmaxf(acc[i][j][3] + bs4.w, 0.f);
            float* dp = Xpad + ((size_t)(b*256 + m)) * PADA + (h + 6) * 68 + (ww + 6);
            dp[0]      = v0;
            dp[PADA]   = v1;
            dp[2*PADA] = v2;
            dp[3*PADA] = v3;
            ushort4 pk;
            pk.x = __bfloat16_as_ushort(__float2bfloat16(v0));
            pk.y = __bfloat16_as_ushort(__float2bfloat16(v1));
            pk.z = __bfloat16_as_ushort(__float2bfloat16(v2));
            pk.w = __bfloat16_as_ushort(__float2bfloat16(v3));
            *(ushort4*)(XpadT + ((size_t)((b*68 + h + 6)*68 + ww + 6)) * 256 + m) = pk;
        }
    }
}

// ---------------- c2 MFMA GEMM, BM=128 x BN=64 + BN partial sums (validated R15) ----------------
__global__ __launch_bounds__(256, 2) void k_gemmc2(
    const __hip_bfloat16* __restrict__ A, const __hip_bfloat16* __restrict__ XT,
    const __hip_bfloat16* __restrict__ AT, const float* __restrict__ bias,
    float* __restrict__ Y, float* __restrict__ ps1, float* __restrict__ ps2)
{
    __shared__ __hip_bfloat16 As[8192];
    __shared__ __hip_bfloat16 Bs[4096];
    __shared__ float bs1[128], bs2[128];
    const int tid  = threadIdx.x;
    const int w    = tid >> 6;
    const int lane = tid & 63;
    const int n0   = blockIdx.x * 64;

    unsigned aoffs[4];
    void* adst[4];
    #pragma unroll
    for (int j = 0; j < 4; ++j) {
        const int slot = (w*4 + j)*64 + lane;
        const int row  = slot >> 3;
        const int q    = slot & 7;
        const int lc   = q ^ (row & 7);
        aoffs[j] = (unsigned)row * 512u + (unsigned)lc * 8u;
        adst[j]  = (void*)&As[(w*4 + j) * 512];
    }
    unsigned boffs0[2], boffs1[2];
    void* bdst[2];
    #pragma unroll
    for (int j = 0; j < 2; ++j) {
        const int slot = (w*2 + j)*64 + lane;
        const int row  = slot >> 3;
        const int q    = slot & 7;
        const int lc   = q ^ (row & 7);
        const int n = n0 + row;
        const int b = n / HW;
        const int p = n - b * HW;
        const int h = p / 56;
        const int ww = p - h * 56;
        boffs0[j] = ((unsigned)(b*68 + h + 6)*68 + (unsigned)(ww + 6))*256u + (unsigned)lc * 8u;
        boffs1[j] = (unsigned)n * 256u + (unsigned)lc * 8u;
        bdst[j]  = (void*)&Bs[(w*2 + j) * 512];
    }

    const int l15 = lane & 15, lg = lane >> 4;
    const int m_w0 = w * 32;
    int rowA[2], rowB[4], chunkoff[2];
    #pragma unroll
    for (int i = 0; i < 2; ++i)
        rowA[i] = (m_w0 + i*16 + l15) * 128;
    #pragma unroll
    for (int j = 0; j < 4; ++j)
        rowB[j] = (j*16 + l15) * 128;
    #pragma unroll
    for (int ks = 0; ks < 2; ++ks)
        chunkoff[ks] = ((4*ks + lg) ^ (lane & 7)) * 16;

    f32x4 acc[2][4];
    #pragma unroll
    for (int i = 0; i < 2; ++i)
        #pragma unroll
        for (int j = 0; j < 4; ++j)
            acc[i][j] = (f32x4){0.f, 0.f, 0.f, 0.f};

    for (int k0 = 0; k0 < 512; k0 += 64) {
        #pragma unroll
        for (int j = 0; j < 4; ++j) gll16(A + aoffs[j] + k0, adst[j]);
        if (k0 < 256) {
            #pragma unroll
            for (int j = 0; j < 2; ++j) gll16(XT + boffs0[j] + k0, bdst[j]);
        } else {
            #pragma unroll
            for (int j = 0; j < 2; ++j) gll16(AT + boffs1[j] + (k0 - 256), bdst[j]);
        }
        __syncthreads();
        #pragma unroll
        for (int ks = 0; ks < 2; ++ks) {
            const int co = chunkoff[ks];
            bf16x8 av[2], bv[4];
            #pragma unroll
            for (int i = 0; i < 2; ++i)
                av[i] = *(const bf16x8*)((const char*)As + rowA[i] + co);
            #pragma unroll
            for (int j = 0; j < 4; ++j)
                bv[j] = *(const bf16x8*)((const char*)Bs + rowB[j] + co);
            #pragma unroll
            for (int i = 0; i < 2; ++i)
                #pragma unroll
                for (int j = 0; j < 4; ++j)
                    acc[i][j] = __builtin_amdgcn_mfma_f32_16x16x32_bf16(av[i], bv[j], acc[i][j], 0, 0, 0);
        }
        __syncthreads();
    }

    float s1loc[8] = {}, s2loc[8] = {};
    #pragma unroll
    for (int j = 0; j < 4; ++j) {
        const int n = n0 + j*16 + l15;
        const int b = n / HW;
        const int p = n - b * HW;
        #pragma unroll
        for (int i = 0; i < 2; ++i) {
            const int m = m_w0 + i*16 + lg*4;
            const float4 bs4 = *(const float4*)&bias[m];
            float v0 = acc[i][j][0] + bs4.x;
            float v1 = acc[i][j][1] + bs4.y;
            float v2 = acc[i][j][2] + bs4.z;
            float v3 = acc[i][j][3] + bs4.w;
            float* dst = Y + ((size_t)(b*128 + m) * HW + p);
            dst[0]    = v0;
            dst[HW]   = v1;
            dst[2*HW] = v2;
            dst[3*HW] = v3;
            s1loc[i*4+0] += v0; s2loc[i*4+0] += v0*v0;
            s1loc[i*4+1] += v1; s2loc[i*4+1] += v1*v1;
            s1loc[i*4+2] += v2; s2loc[i*4+2] += v2*v2;
            s1loc[i*4+3] += v3; s2loc[i*4+3] += v3*v3;
        }
    }
    #pragma unroll
    for (int k = 0; k < 8; ++k) {
        #pragma unroll
        for (int msk = 1; msk <= 8; msk <<= 1) {
            s1loc[k] += __shfl_xor(s1loc[k], msk);
            s2loc[k] += __shfl_xor(s2loc[k], msk);
        }
    }
    if (l15 == 0) {
        #pragma unroll
        for (int i = 0; i < 2; ++i)
            #pragma unroll
            for (int r = 0; r < 4; ++r) {
                const int m = m_w0 + i*16 + lg*4 + r;
                bs1[m] = s1loc[i*4+r];
                bs2[m] = s2loc[i*4+r];
            }
    }
    __syncthreads();
    if (tid < 128) {
        ps1[blockIdx.x * 128 + tid] = bs1[tid];
        ps2[blockIdx.x * 128 + tid] = bs2[tid];
    }
}

// ---------------- dilated 7x7 conv: bf16 MFMA implicit GEMM, K-split x5, bf16 partials (validated) ----------------
__global__ __launch_bounds__(256, 2) void k_convmfma(
    const __hip_bfloat16* __restrict__ Wbf, const __hip_bfloat16* __restrict__ XT,
    __hip_bfloat16* __restrict__ o0, __hip_bfloat16* __restrict__ o1,
    __hip_bfloat16* __restrict__ o2, __hip_bfloat16* __restrict__ o3,
    __hip_bfloat16* __restrict__ o4)
{
    __shared__ __hip_bfloat16 As[8192];
    __shared__ __hip_bfloat16 Bs[8192];
    const int tid  = threadIdx.x;
    const int w    = tid >> 6;
    const int lane = tid & 63;
    const int n0   = blockIdx.x * 128;
    const int s    = blockIdx.y;
    const int t_start = (s < 4) ? s * 40 : 158;
    const int cnt     = (s < 3) ? 40 : 38;
    __hip_bfloat16* __restrict__ out = (s==0)?o0:(s==1)?o1:(s==2)?o2:(s==3)?o3:o4;

    unsigned aoffs[4], boffs[4];
    void *adst[4], *bdst[4];
    #pragma unroll
    for (int j = 0; j < 4; ++j) {
        const int slot = (w*4 + j)*64 + lane;
        const int row  = slot >> 3;
        const int q    = slot & 7;
        const int lc   = q ^ (row & 7);
        aoffs[j] = (unsigned)row * 12544u + (unsigned)lc * 8u;
        adst[j]  = (void*)&As[(w*4 + j) * 512];
        const int n = n0 + row;
        const int b = n / HW;
        const int p = n - b * HW;
        const int h = p / 56;
        const int ww = p - h * 56;
        boffs[j] = ((unsigned)(b*68 + h)*68 + (unsigned)ww)*256u + (unsigned)lc * 8u;
        bdst[j]  = (void*)&Bs[(w*4 + j) * 512];
    }

    const int l15 = lane & 15, lg = lane >> 4;
    const int m_w0 = (w & 1) * 64;
    const int n_w0 = (w >> 1) * 64;
    int rowA[4], rowB[4], chunkoff[2];
    #pragma unroll
    for (int i = 0; i < 4; ++i) {
        rowA[i] = (m_w0 + i*16 + l15) * 128;
        rowB[i] = (n_w0 + i*16 + l15) * 128;
    }
    #pragma unroll
    for (int ks = 0; ks < 2; ++ks)
        chunkoff[ks] = ((4*ks + lg) ^ (lane & 7)) * 16;

    f32x4 acc[4][4];
    #pragma unroll
    for (int i = 0; i < 4; ++i)
        #pragma unroll
        for (int j = 0; j < 4; ++j)
            acc[i][j] = (f32x4){0.f, 0.f, 0.f, 0.f};

    for (int it = 0; it < cnt; ++it) {
        const int kt = t_start + it;
        const int k0 = kt << 6;
        const int t  = k0 >> 8;
        const int c0 = k0 & 255;
        const int ti = (t * 37) >> 8;
        const int tj = t - ti * 7;
        const unsigned aof = (unsigned)k0;
        const unsigned bof = (unsigned)(ti*68 + tj) * 512u + (unsigned)c0;

        #pragma unroll
        for (int j = 0; j < 4; ++j) gll16(Wbf + aoffs[j] + aof, adst[j]);
        #pragma unroll
        for (int j = 0; j < 4; ++j) gll16(XT + boffs[j] + bof, bdst[j]);

        __syncthreads();

        #pragma unroll
        for (int ks = 0; ks < 2; ++ks) {
            const int co = chunkoff[ks];
            bf16x8 av[4], bv[4];
            #pragma unroll
            for (int i = 0; i < 4; ++i)
                av[i] = *(const bf16x8*)((const char*)As + rowA[i] + co);
            #pragma unroll
            for (int i = 0; i < 4; ++i)
                bv[i] = *(const bf16x8*)((const char*)Bs + rowB[i] + co);
            #pragma unroll
            for (int i = 0; i < 4; ++i)
                #pragma unroll
                for (int j = 0; j < 4; ++j)
                    acc[i][j] = __builtin_amdgcn_mfma_f32_16x16x32_bf16(av[i], bv[j], acc[i][j], 0, 0, 0);
        }
        __syncthreads();
    }

    #pragma unroll
    for (int j = 0; j < 4; ++j) {
        const int n = n0 + n_w0 + j*16 + l15;
        const int b = n / HW;
        const int p = n - b * HW;
        #pragma unroll
        for (int i = 0; i < 4; ++i) {
            const int m = m_w0 + i*16 + lg*4;
            __hip_bfloat16* dst = out + ((size_t)(b*128 + m) * HW + p);
            dst[0]      = __float2bfloat16(acc[i][j][0]);
            dst[HW]     = __float2bfloat16(acc[i][j][1]);
            dst[2*HW]   = __float2bfloat16(acc[i][j][2]);
            dst[3*HW]   = __float2bfloat16(acc[i][j][3]);
        }
    }
}

// ---------------- combine 5 bf16 partials + bias + relu -> k1 (validated) ----------------
__global__ __launch_bounds__(256) void k_combine5(
    const short8v* __restrict__ p0, const short8v* __restrict__ p1,
    const short8v* __restrict__ p2, const short8v* __restrict__ p3,
    const short8v* __restrict__ p4,
    const float* __restrict__ bias, float* __restrict__ Y)
{
    const int j = blockIdx.x * 256 + threadIdx.x;
    short8v a = p0[j], b = p1[j], c = p2[j], d = p3[j], e5 = p4[j];
    const int oc = ((j * 8) / HW) & 127;
    const float bv = bias[oc];
    float o[8];
    #pragma unroll
    for (int e = 0; e < 8; ++e) {
        float v = bf2f(a[e]) + bf2f(b[e]) + bf2f(c[e]) + bf2f(d[e]) + bf2f(e5[e]) + bv;
        o[e] = fmaxf(v, 0.f);
    }
    float4* dst = (float4*)(Y + (size_t)j * 8);
    dst[0] = *(float4*)&o[0];
    dst[1] = *(float4*)&o[4];
}

// ---------------- fused BN(from partials) + relu + softmax over 49 channels (validated) ----------------
__global__ __launch_bounds__(256) void k_bnsoftmax(float* __restrict__ X,
        const float* __restrict__ ps1, const float* __restrict__ ps2,
        const float* __restrict__ gam,  const float* __restrict__ bet)
{
    __shared__ float msh[NT], rsh[NT];
    const int tid = threadIdx.x;
    if (tid < NT) {
        float s1 = 0.f, s2 = 0.f;
        for (int b = 0; b < NB_ATT; ++b) {
            s1 += ps1[b * NT + tid];
            s2 += ps2[b * NT + tid];
        }
        const float mean = s1 * (1.f / 12544.f);
        const float var  = s2 * (1.f / 12544.f) - mean * mean;
        msh[tid] = mean;
        rsh[tid] = rsqrtf(var + 1e-5f);
    }
    __syncthreads();

    const int gidx = blockIdx.x * 256 + tid;
    const int b = gidx / HW;
    const int p = gidx - b * HW;
    float* base = X + (size_t)b * NT * HW + p;
    float vals[NT];
    float m = -1e30f;
    #pragma unroll
    for (int t = 0; t < NT; ++t) {
        float v = base[(size_t)t * HW];
        v = (v - msh[t]) * rsh[t] * gam[t] + bet[t];
        v = fmaxf(v, 0.f);
        vals[t] = v;
        m = fmaxf(m, v);
    }
    float s = 0.f;
    #pragma unroll
    for (int t = 0; t < NT; ++t) { float e = __expf(vals[t] - m); vals[t] = e; s += e; }
    const float inv = 1.f / s;
    #pragma unroll
    for (int t = 0; t < NT; ++t) base[(size_t)t * HW] = vals[t] * inv;
}

// ---------------- attention apply v3: 4 channels per wave (att loads amortized x4) ----------------
// wave = 4 channels; lane: wq (w-quad, active<14), rs (row-slice). Grid (14, 16, 4).
__global__ __launch_bounds__(256) void k_attapply3(const float* __restrict__ Xpad,
        const float* __restrict__ att, float* __restrict__ Y)
{
    const int tid  = threadIdx.x;
    const int wv   = tid >> 6;
    const int lane = tid & 63;
    const int wq   = lane & 15;          // active < 14
    const int rs   = lane >> 4;
    const int rq   = blockIdx.x;         // 0..13
    const int cg   = blockIdx.y;         // 0..15
    const int b    = blockIdx.z;         // 0..3
    const int cb   = cg * 16 + wv * 4;   // base channel (4 per wave)
    const int h    = rq * 4 + rs;
    const int w0   = min(wq, 13) * 4;

    const float* xbase = Xpad + ((size_t)(b*256 + cb) * 68 + h) * 68 + w0;
    const float* abase = att + (size_t)b * NT * HW + h * 56 + w0;
    float4 acc[4];
    #pragma unroll
    for (int ci = 0; ci < 4; ++ci) acc[ci] = (float4){0.f, 0.f, 0.f, 0.f};

    #pragma unroll
    for (int ti = 0; ti < 7; ++ti) {
        float xf[4][16];
        #pragma unroll
        for (int ci = 0; ci < 4; ++ci) {
            const float* xr = xbase + (size_t)ci * 68 * 68 + ti * 136;   // row h + 2*ti, channel cb+ci
            *(float4*)&xf[ci][0]  = *(const float4*)(xr);
            *(float4*)&xf[ci][4]  = *(const float4*)(xr + 4);
            *(float4*)&xf[ci][8]  = *(const float4*)(xr + 8);
            *(float4*)&xf[ci][12] = *(const float4*)(xr + 12);
        }
        #pragma unroll
        for (int tj = 0; tj < 7; ++tj) {
            const float4 a4 = *(const float4*)(abase + (size_t)(ti*7 + tj) * HW);
            #pragma unroll
            for (int ci = 0; ci < 4; ++ci) {
                acc[ci].x = fmaf(xf[ci][2*tj + 0], a4.x, acc[ci].x);
                acc[ci].y = fmaf(xf[ci][2*tj + 1], a4.y, acc[ci].y);
                acc[ci].z = fmaf(xf[ci][2*tj + 2], a4.z, acc[ci].z);
                acc[ci].w = fmaf(xf[ci][2*tj + 3], a4.w, acc[ci].w);
            }
        }
    }
    if (wq < 14) {
        #pragma unroll
        for (int ci = 0; ci < 4; ++ci)
            *(float4*)(Y + (size_t)(b*256 + cb + ci) * HW + h * 56 + w0) = acc[ci];
    }
}

// ---------------- fused BN(from partials) + relu -> dec_out, + sigmoid(c3) -> side (validated) ----------------
__global__ __launch_bounds__(256) void k_bnside(const float* __restrict__ X,
        const float* __restrict__ ps1, const float* __restrict__ ps2,
        const float* __restrict__ gam,  const float* __restrict__ bet,
        const float* __restrict__ w3,   const float* __restrict__ b3,
        float* __restrict__ dec_out,    float* __restrict__ side)
{
    __shared__ float ms[128], rs[128], gs[128], bs[128], w3s[128];
    const int tid = threadIdx.x;
    if (tid < 128) {
        float s1 = 0.f, s2 = 0.f;
        for (int b = 0; b < NB_C2; ++b) {
            s1 += ps1[b * 128 + tid];
            s2 += ps2[b * 128 + tid];
        }
        const float mean = s1 * (1.f / 12544.f);
        const float var  = s2 * (1.f / 12544.f) - mean * mean;
        ms[tid] = mean;
        rs[tid] = rsqrtf(var + 1e-5f);
        gs[tid] = gam[tid];  bs[tid] = bet[tid];
        w3s[tid] = w3[tid];
    }
    __syncthreads();
    const int gidx = blockIdx.x * 256 + tid;
    const int b = gidx / HW;
    const int p = gidx - b * HW;
    const size_t u = (size_t)b * 128 * HW + p;
    float acc = b3[0];
    #pragma unroll 8
    for (int c = 0; c < 128; ++c) {
        const size_t a = u + (size_t)c * HW;
        float v = (X[a] - ms[c]) * rs[c] * gs[c] + bs[c];
        v = fmaxf(v, 0.f);
        dec_out[a] = v;
        acc = fmaf(v, w3s[c], acc);
    }
    side[gidx] = 1.f / (1.f + __expf(-acc));
}

// ---------------- launcher ----------------
extern "C" void kernel_launch(void* const* d_in, const int* in_sizes, int n_in,
                              void* d_out, int out_size, void* d_ws, size_t ws_size,
                              hipStream_t stream)
{
    const float* en  = (const float*)d_in[0];
    const float* dec = (const float*)d_in[1];
    const float* w1  = (const float*)d_in[2];
    const float* b1  = (const float*)d_in[3];
    const float* w2  = (const float*)d_in[4];
    const float* b2  = (const float*)d_in[5];
    const float* bng = (const float*)d_in[6];
    const float* bnb = (const float*)d_in[7];
    const float* c1w = (const float*)d_in[8];
    const float* c1b = (const float*)d_in[9];
    const float* c2w = (const float*)d_in[10];
    const float* c2b = (const float*)d_in[11];
    const float* bfg = (const float*)d_in[12];
    const float* bfb = (const float*)d_in[13];
    const float* c3w = (const float*)d_in[14];
    const float* c3b = (const float*)d_in[15];

    float* ws = (float*)d_ws;                   // 20,750,848 floats (proven extent)
    __hip_bfloat16* part0 = (__hip_bfloat16*)(ws + R0);
    __hip_bfloat16* part1 = (__hip_bfloat16*)(ws + R0 +  802816u);
    __hip_bfloat16* part2 = (__hip_bfloat16*)(ws + R0 + 1605632u);
    __hip_bfloat16* part3 = (__hip_bfloat16*)(ws + R0 + 2408448u);
    float* fmap_att = ws + R0;                  // region base after combine (parts dead)
    float* attb     = ws + R1;
    float* xpad     = ws + R2;
    float* k1       = ws + R3;
    __hip_bfloat16* xcat = (__hip_bfloat16*)(ws + R4);
    __hip_bfloat16* part4 = (__hip_bfloat16*)(ws + R4);
    __hip_bfloat16* attT  = (__hip_bfloat16*)(ws + R4);
    float* x2       = ws + R4 + 1605632u;
    __hip_bfloat16* c1wb = (__hip_bfloat16*)(ws + R5);            // 131072 bf16
    __hip_bfloat16* c2wb = (__hip_bfloat16*)(ws + R5 + 65536u);   // 65536 bf16
    float* c2s1    = ws + R5 + 131072u;                   // 196*128
    float* c2s2    = ws + R5 + 156160u;                   // 196*128
    float* atts1   = ws + R5 + 181248u;                   // 98*49
    float* atts2   = ws + R5 + 186050u;                   // 98*49
    __hip_bfloat16* xpadT = (__hip_bfloat16*)(ws + R7);
    __hip_bfloat16* wbf   = (__hip_bfloat16*)(ws + R8);

    float* dec_out = (float*)d_out;
    float* side    = (float*)d_out + 1605632u;

    // 0. zero padded buffers
    hipMemsetAsync(xpad,  0, (size_t)4 * 256 * PADA * sizeof(float), stream);
    hipMemsetAsync(xpadT, 0, (size_t)4 * PADA * 256 * sizeof(__hip_bfloat16), stream);
    // 1. merged prep
    k_prep<<<dim3(2464), dim3(256), 0, stream>>>(en, dec, c1w, c2w, w1, xcat, c1wb, c2wb, wbf);
    // 2. relu(c1 x xcat) via MFMA -> xpad + xpadT
    k_gemmc1<<<dim3(196, 2), dim3(256), 0, stream>>>(c1wb, xcat, c1b, xpad, xpadT);
    // 3. big dilated conv (K-split x5, bf16 partials)
    k_convmfma<<<dim3(98, 5), dim3(256), 0, stream>>>(wbf, xpadT, part0, part1, part2, part3, part4);
    // 4. combine -> k1
    k_combine5<<<dim3(784), dim3(256), 0, stream>>>((const short8v*)part0, (const short8v*)part1,
                                                    (const short8v*)part2, (const short8v*)part3,
                                                    (const short8v*)part4, b1, k1);
    // 5. attention logits = w2 * k1 + b2, with fused BN partial sums
    k_gemm1x1<<<dim3(1, 98), dim3(256), 0, stream>>>(w2, b2, k1, 49, 128, attb, atts1, atts2);
    // 6. BN(from partials) + relu + softmax(49) in place
    k_bnsoftmax<<<dim3(49), dim3(256), 0, stream>>>(attb, atts1, atts2, bng, bnb);
    // 7. local attention gather -> fmap_att (4 channels/wave)
    k_attapply3<<<dim3(14, 16, 4), dim3(256), 0, stream>>>(xpad, attb, fmap_att);
    // 8. fmap_att -> attT NHWC bf16
    k_t2nhwc<<<dim3(49, 4, 4), dim3(256), 0, stream>>>(fmap_att, attT, 256, 0);
    // 9. x2 = c2 x [xpadT(center) ; attT] via MFMA + BN partials
    k_gemmc2<<<dim3(196), dim3(256), 0, stream>>>(c2wb, xpadT, attT, c2b, x2, c2s1, c2s2);
    // 10. fused BN(from partials)/relu -> dec_out + sigmoid side
    k_bnside<<<dim3(49), dim3(256), 0, stream>>>(x2, c2s1, c2s2, bfg, bfb,
                                                 c3w, c3b, dec_out, side);
}